// Round 4
// baseline (906.707 us; speedup 1.0000x reference)
//
#include <hip/hip_runtime.h>
#include <math.h>

typedef __bf16 bf16;
typedef __bf16 bf16x8 __attribute__((ext_vector_type(8)));
typedef float f32x4 __attribute__((ext_vector_type(4)));

#define NPTS 8192
#define MTOT 16384

static __device__ __forceinline__ float b2f(bf16 x) { return (float)x; }
static __device__ __forceinline__ bf16  f2b(float x) { return (bf16)x; }

// ------------------------------------------------------------ diagnostics --
__global__ void diag_k(float* out, float code)
{
    if (threadIdx.x == 0 && blockIdx.x == 0) out[0] = code;
}

// ---------------------------------------------------------------- KNN ------
// partial top-9 per (query, candidate-chunk of 2048), f32 coords.
// d2 = (sq_n + sq_m) - 2*dot (reference formula); lexicographic (d, idx)
// tie-break = top_k first-occurrence. ii init {0..8}: fault-proof.
__global__ __launch_bounds__(256) void knn_partial(const float* __restrict__ xyz,
                                                   float2* __restrict__ part)
{
    __shared__ float4 pts[2048];               // 32 KB
    const int t  = threadIdx.x;
    const int b  = blockIdx.z;
    const int nb = blockIdx.x * 256;
    const int cb = blockIdx.y * 2048;
    const float* X = xyz + b * 3 * NPTS;
    for (int i = t; i < 2048; i += 256) {
        float x = X[cb + i];
        float y = X[NPTS + cb + i];
        float z = X[2 * NPTS + cb + i];
        pts[i] = make_float4(x, y, z, x * x + y * y + z * z);
    }
    __syncthreads();
    const int n = nb + t;
    float qx = X[n], qy = X[NPTS + n], qz = X[2 * NPTS + n];
    float qsq = qx * qx + qy * qy + qz * qz;
    float dd[9]; int ii[9];
#pragma unroll
    for (int k = 0; k < 9; ++k) { dd[k] = __builtin_inff(); ii[k] = k; }
    for (int i = 0; i < 2048; ++i) {
        float4 c = pts[i];
        float d = (qsq + c.w) - 2.0f * (qx * c.x + qy * c.y + qz * c.z);
        int m = cb + i;
        if (d < dd[8] || (d == dd[8] && m < ii[8])) {
            dd[8] = d; ii[8] = m;
#pragma unroll
            for (int k = 8; k > 0; --k) {
                float a0 = dd[k - 1], a1 = dd[k];
                int   b0v = ii[k - 1], b1v = ii[k];
                bool sw = (a1 < a0) || (a1 == a0 && b1v < b0v);
                dd[k - 1] = sw ? a1 : a0;  dd[k] = sw ? a0 : a1;
                ii[k - 1] = sw ? b1v : b0v; ii[k] = sw ? b0v : b1v;
            }
        }
    }
    float2* pp = part + (size_t)(b * NPTS + n) * 36 + blockIdx.y * 9;
#pragma unroll
    for (int k = 0; k < 9; ++k) pp[k] = make_float2(dd[k], __int_as_float(ii[k]));
}

// merge 4 chunk-partials -> final 9 neighbor row-indices (b*8192+m)
__global__ __launch_bounds__(256) void knn_merge(const float2* __restrict__ part,
                                                 int* __restrict__ idxg)
{
    const int j = blockIdx.x * 256 + threadIdx.x;
    float dd[9]; int ii[9];
#pragma unroll
    for (int k = 0; k < 9; ++k) { dd[k] = __builtin_inff(); ii[k] = k; }
    const float2* pp = part + (size_t)j * 36;
    for (int c = 0; c < 36; ++c) {
        float2 e = pp[c];
        float d = e.x; int m = __float_as_int(e.y);
        if (d < dd[8] || (d == dd[8] && m < ii[8])) {
            dd[8] = d; ii[8] = m;
#pragma unroll
            for (int k = 8; k > 0; --k) {
                float a0 = dd[k - 1], a1 = dd[k];
                int   b0v = ii[k - 1], b1v = ii[k];
                bool sw = (a1 < a0) || (a1 == a0 && b1v < b0v);
                dd[k - 1] = sw ? a1 : a0;  dd[k] = sw ? a0 : a1;
                ii[k - 1] = sw ? b1v : b0v; ii[k] = sw ? b0v : b1v;
            }
        }
    }
    const int base = (j >> 13) * NPTS;
#pragma unroll
    for (int k = 0; k < 9; ++k) {
        int m = ii[k];
        m = ((unsigned)m < (unsigned)NPTS) ? m : 0;   // fault-proof
        idxg[j * 9 + k] = base + m;
    }
}

// --------------------------------------------------------------- pack ------
// f32 [B][C][N] channel-major -> bf16 point-major [M][ldd] at column offset,
// zero-pad c>=Csrc.
__global__ __launch_bounds__(256) void pack_t(const float* __restrict__ src, int Csrc,
                                              bf16* __restrict__ dst, int ldd, int colOfs)
{
    __shared__ bf16 tile[32][68];
    const int t  = threadIdx.x;
    const int nb = blockIdx.x * 64;
    const int cb = blockIdx.y * 32;
    const int b  = blockIdx.z;
#pragma unroll
    for (int i = 0; i < 8; ++i) {
        int id = t + i * 256;
        int c = id >> 6, n = id & 63;
        int cc = cb + c;
        bf16 v = (bf16)0.0f;
        if (cc < Csrc) v = f2b(src[(size_t)(b * Csrc + cc) * NPTS + nb + n]);
        tile[c][n] = v;
    }
    __syncthreads();
#pragma unroll
    for (int i = 0; i < 8; ++i) {
        int id = t + i * 256;
        int n = id >> 5, c = id & 31;
        dst[(size_t)(b * NPTS + nb + n) * ldd + colOfs + cb + c] = tile[c][n];
    }
}

// pad w0 f32 [128][67] -> bf16 [128][96] zeros beyond 67
__global__ __launch_bounds__(256) void w0_pad(const float* __restrict__ w0,
                                              bf16* __restrict__ w0p)
{
    int id = blockIdx.x * 256 + threadIdx.x;
    if (id < 128 * 96) {
        int o = id / 96, c = id - o * 96;
        w0p[id] = (c < 67) ? f2b(w0[o * 67 + c]) : (bf16)0.0f;
    }
}

// stage all dense GEMM weights f32 -> bf16 contiguous in ws
__global__ __launch_bounds__(256) void cvt_weights(
    const float* __restrict__ w1, const float* __restrict__ wz,
    const float* __restrict__ wr, const float* __restrict__ wq,
    const float* __restrict__ w2a, const float* __restrict__ w2b,
    const float* __restrict__ rw0, const float* __restrict__ rw1,
    const float* __restrict__ cw0, const float* __restrict__ cw1,
    bf16* __restrict__ dst)
{
    int id = blockIdx.x * 256 + threadIdx.x;
    if (id >= 163840) return;
    const float* s; int off;
    if (id < 16384)       { s = w1;  off = 0; }
    else if (id < 49152)  { s = wz;  off = 16384; }
    else if (id < 81920)  { s = wr;  off = 49152; }
    else if (id < 114688) { s = wq;  off = 81920; }
    else if (id < 139264) { s = w2a; off = 114688; }
    else if (id < 147456) { s = w2b; off = 139264; }
    else if (id < 151552) { s = rw0; off = 147456; }
    else if (id < 155648) { s = rw1; off = 151552; }
    else if (id < 159744) { s = cw0; off = 155648; }
    else                  { s = cw1; off = 159744; }
    dst[id] = f2b(s[id - off]);
}

// --------------------------------------------------------------- GEMM ------
// out[j][o] = epi( sum_c A[j][c] * W[o][c] ). A bf16 point-major [M][lda],
// W bf16 [O][ldw] (staged). MFMA 16x16x32 bf16 NT:
// A-frag lane(q=lane>>4,r=lane&15): A[pt=r][k=q*8+j]; B-frag: W[o=r][k=q*8+j];
// C/D: col(lane&15)=o, row=q*4+reg=pt (m89 mapping).
// Wave tile 64pt x 32o; block = 2x2 waves = 128pt x 64o.
template <int EPI>
__global__ __launch_bounds__(256) void gemm_k(
    const bf16* __restrict__ A, int lda,
    const bf16* __restrict__ W, int ldw, int K, int Otot,
    const float* __restrict__ bias, const float* __restrict__ bnp,
    const bf16* __restrict__ aux1, const bf16* __restrict__ aux2,
    bf16* __restrict__ dst, int ldo, int dofs,
    float* __restrict__ out2)
{
    const int w = threadIdx.x >> 6, lane = threadIdx.x & 63;
    const int q = lane >> 4, r = lane & 15;
    const int ptb = blockIdx.x * 128 + (w & 1) * 64;
    const int ob  = blockIdx.y * 64 + (w >> 1) * 32;
    const bf16* Ap = A + (size_t)(ptb + r) * lda + q * 8;
    const bf16* Wp = W + (size_t)(ob + r) * ldw + q * 8;
    f32x4 zero = {0.f, 0.f, 0.f, 0.f};
    f32x4 acc[4][2];
#pragma unroll
    for (int i = 0; i < 4; ++i) { acc[i][0] = zero; acc[i][1] = zero; }
    for (int k = 0; k < K; k += 32) {
        bf16x8 bv0 = *(const bf16x8*)(Wp + k);
        bf16x8 bv1 = *(const bf16x8*)(Wp + 16 * ldw + k);
        bf16x8 a0 = *(const bf16x8*)(Ap + k);
        bf16x8 a1 = *(const bf16x8*)(Ap + 16 * lda + k);
        bf16x8 a2 = *(const bf16x8*)(Ap + 32 * lda + k);
        bf16x8 a3 = *(const bf16x8*)(Ap + 48 * lda + k);
        acc[0][0] = __builtin_amdgcn_mfma_f32_16x16x32_bf16(a0, bv0, acc[0][0], 0, 0, 0);
        acc[1][0] = __builtin_amdgcn_mfma_f32_16x16x32_bf16(a1, bv0, acc[1][0], 0, 0, 0);
        acc[2][0] = __builtin_amdgcn_mfma_f32_16x16x32_bf16(a2, bv0, acc[2][0], 0, 0, 0);
        acc[3][0] = __builtin_amdgcn_mfma_f32_16x16x32_bf16(a3, bv0, acc[3][0], 0, 0, 0);
        acc[0][1] = __builtin_amdgcn_mfma_f32_16x16x32_bf16(a0, bv1, acc[0][1], 0, 0, 0);
        acc[1][1] = __builtin_amdgcn_mfma_f32_16x16x32_bf16(a1, bv1, acc[1][1], 0, 0, 0);
        acc[2][1] = __builtin_amdgcn_mfma_f32_16x16x32_bf16(a2, bv1, acc[2][1], 0, 0, 0);
        acc[3][1] = __builtin_amdgcn_mfma_f32_16x16x32_bf16(a3, bv1, acc[3][1], 0, 0, 0);
    }
#pragma unroll
    for (int to = 0; to < 2; ++to) {
        const int o = ob + to * 16 + r;
        float bs = 0.f, gg = 0.f, be = 0.f, mm = 0.f, rs = 0.f;
        if (EPI != 5) bs = bias[o];
        if (EPI == 1 || EPI == 5) {
            gg = bnp[o]; be = bnp[Otot + o]; mm = bnp[2 * Otot + o];
            float vv = bnp[3 * Otot + o];
            rs = 1.0f / sqrtf(vv + 1e-5f);
        }
#pragma unroll
        for (int tm = 0; tm < 4; ++tm) {
#pragma unroll
            for (int rr = 0; rr < 4; ++rr) {
                const int j = ptb + tm * 16 + q * 4 + rr;
                float v = acc[tm][to][rr];
                if (EPI == 0) { v += bs; v = v > 0.f ? v : 0.1f * v; }
                else if (EPI == 1) { v += bs; v = (v - mm) * rs * gg + be; v = v > 0.f ? v : 0.1f * v; }
                else if (EPI == 2) { v += bs; v = 1.0f / (1.0f + expf(-v)); }
                else if (EPI == 3) { v += bs; v = 1.0f / (1.0f + expf(-v));
                                     v *= b2f(aux1[(size_t)j * 256 + o]); }
                else if (EPI == 4) {
                    v += bs; float qv = tanhf(v);
                    float z = b2f(aux2[(size_t)j * 128 + o]);
                    float h = b2f(aux1[(size_t)j * 256 + o]);
                    v = (1.0f - z) * h + z * qv;
                }
                else if (EPI == 5) { v = (v - mm) * rs * gg + be; v = fmaxf(v, 0.f); }
                else if (EPI == 6) { v += bs; v = v > 0.f ? v : 0.1f * v; }
                dst[(size_t)j * ldo + dofs + o] = f2b(v);
                if (EPI == 6) {
                    int bb = j >> 13, n = j & (NPTS - 1);
                    out2[(size_t)bb * 64 * NPTS + (size_t)o * NPTS + n] = v;
                }
            }
        }
    }
}

// ---------------------------------------------------------- gather-max -----
__global__ __launch_bounds__(256) void gather_max(const int* __restrict__ idxg,
                                                  const bf16* __restrict__ P2,
                                                  bf16* __restrict__ HF)
{
    const int id = blockIdx.x * 256 + threadIdx.x;
    const int j = id >> 7, o = id & 127;
    const int* ip = idxg + j * 9;
    float v = -__builtin_inff();
#pragma unroll
    for (int k = 0; k < 9; ++k) {
        int m = ip[k];
        m = ((unsigned)m < (unsigned)MTOT) ? m : 0;   // fault-proof
        v = fmaxf(v, b2f(P2[(size_t)m * 128 + o]));
    }
    HF[(size_t)j * 256 + o] = f2b(v);
}

// --------------------------------------------------------------- head ------
__global__ __launch_bounds__(256) void head_k(
    const bf16* __restrict__ X2, const bf16* __restrict__ R2v, const bf16* __restrict__ C2v,
    const float* __restrict__ rw2, const float* __restrict__ rbn2,
    const float* __restrict__ cw2, const float* __restrict__ cbn2,
    const float* __restrict__ wfc, const float* __restrict__ bfc,
    const float* __restrict__ flow, float* __restrict__ out)
{
    const int j = blockIdx.x * 256 + threadIdx.x;
    const int b = j >> 13, n = j & (NPTS - 1);
    const bf16x8* xr = (const bf16x8*)(X2 + (size_t)j * 64);
    const bf16x8* rr = (const bf16x8*)(R2v + (size_t)j * 64);
    const bf16x8* cr = (const bf16x8*)(C2v + (size_t)j * 64);
    float dr = 0.f, dc = 0.f, p0 = 0.f, p1 = 0.f, p2 = 0.f;
#pragma unroll
    for (int bk = 0; bk < 8; ++bk) {
        bf16x8 xv = xr[bk], rv = rr[bk], cv = cr[bk];
#pragma unroll
        for (int i = 0; i < 8; ++i) {
            const int c = bk * 8 + i;
            float x = (float)xv[i];
            dr += rw2[c] * (float)rv[i];
            dc += cw2[c] * (float)cv[i];
            p0 += wfc[c] * x;
            p1 += wfc[64 + c] * x;
            p2 += wfc[128 + c] * x;
        }
    }
    float refine = (dr - rbn2[2]) / sqrtf(rbn2[3] + 1e-5f) * rbn2[0] + rbn2[1];
    refine = fmaxf(refine, 0.f);
    float coarse = (dc - cbn2[2]) / sqrtf(cbn2[3] + 1e-5f) * cbn2[0] + cbn2[1];
    coarse = fmaxf(coarse, 0.f);
    p0 += bfc[0]; p1 += bfc[1]; p2 += bfc[2];
    const float f0 = flow[(size_t)b * 3 * NPTS + n];
    const float f1 = flow[(size_t)b * 3 * NPTS + NPTS + n];
    const float f2v = flow[(size_t)b * 3 * NPTS + 2 * NPTS + n];
    float o0 = fminf(fmaxf(coarse * f0 + refine * p0, -20.f), 20.f);
    float o1 = fminf(fmaxf(coarse * f1 + refine * p1, -20.f), 20.f);
    float o2 = fminf(fmaxf(coarse * f2v + refine * p2, -20.f), 20.f);
    float* ro = out + 1048576; // x section = 2*64*8192 f32 elements
    ro[(size_t)b * 3 * NPTS + n] = o0;
    ro[(size_t)b * 3 * NPTS + NPTS + n] = o1;
    ro[(size_t)b * 3 * NPTS + 2 * NPTS + n] = o2;
}

// -------------------------------------------------------------- launch -----
// Workspace (27,590,656 B), lifetime-aliased; steps = launch order.
//   region XA  @0          6,291,456  XA [14->15]
//     A0 @0 3,145,728 [4->7] | idxg @3,145,728 589,824 [2->9] | W0p @3,735,552 [3->7]
//   region HF  @6,291,456  8,388,608  HF [6->14]
//     part @6,291,456 4,718,592 [1->2]
//     X1 @6,291,456 [15->16] | X2 @10,485,760 [16->22] | R1 @12,582,912 [17->18]
//   region QIN @14,680,064 8,388,608  QIN [11->14]
//     P1 @14,680,064 [7->8] | P2 @18,874,368 [8->9]
//     C1 @14,680,064 [20->21] | C2 @16,777,216 [21->22]
//   region Z   @23,068,672 4,194,304  Z [12->14]
//     R2 @23,068,672 [18->22] | CV @25,165,824 [19->20]
//   region WTS @27,262,976 327,680  staged bf16 weights [3c->21]
extern "C" void kernel_launch(void* const* d_in, const int* in_sizes, int n_in,
                              void* d_out, int out_size, void* d_ws, size_t ws_size,
                              hipStream_t stream)
{
    static const int EXP[35] = {
        49152, 1048576, 1048576, 2097152, 49152,
        8576, 128, 512, 16384, 128, 512,
        32768, 128, 32768, 128, 32768, 128,
        24576, 128, 8192, 64, 192, 3,
        4096, 256, 4096, 256, 64, 4,
        4096, 256, 4096, 256, 64, 4 };
    float code = 0.f;
    if (n_in != 35) code = 900.f;
    else if (out_size != 1097728) code = 950.f;
    else if (ws_size < 27590656u) code = 980.f;
    else { for (int i = 0; i < 35; ++i) if (in_sizes[i] != EXP[i]) { code = 1000.f + 4.f * i; break; } }
    if (code != 0.f) { diag_k<<<dim3(1), dim3(64), 0, stream>>>((float*)d_out, code); return; }

    const float* xyz    = (const float*)d_in[0];
    const float* points = (const float*)d_in[1];
    const float* cost   = (const float*)d_in[2];
    const float* feats  = (const float*)d_in[3];
    const float* flow   = (const float*)d_in[4];
    const float* w0     = (const float*)d_in[5];
    const float* b0     = (const float*)d_in[6];
    const float* bn0    = (const float*)d_in[7];
    const float* w1     = (const float*)d_in[8];
    const float* b1     = (const float*)d_in[9];
    const float* bn1    = (const float*)d_in[10];
    const float* wz     = (const float*)d_in[11];
    const float* bz     = (const float*)d_in[12];
    const float* wr     = (const float*)d_in[13];
    const float* br     = (const float*)d_in[14];
    const float* wq     = (const float*)d_in[15];
    const float* bq     = (const float*)d_in[16];
    const float* w2a    = (const float*)d_in[17];
    const float* b2a    = (const float*)d_in[18];
    const float* w2b    = (const float*)d_in[19];
    const float* b2b    = (const float*)d_in[20];
    const float* wfc    = (const float*)d_in[21];
    const float* bfc    = (const float*)d_in[22];
    const float* rw0    = (const float*)d_in[23];
    const float* rbn0   = (const float*)d_in[24];
    const float* rw1    = (const float*)d_in[25];
    const float* rbn1   = (const float*)d_in[26];
    const float* rw2    = (const float*)d_in[27];
    const float* rbn2   = (const float*)d_in[28];
    const float* cw0    = (const float*)d_in[29];
    const float* cbn0   = (const float*)d_in[30];
    const float* cw1    = (const float*)d_in[31];
    const float* cbn1   = (const float*)d_in[32];
    const float* cw2    = (const float*)d_in[33];
    const float* cbn2   = (const float*)d_in[34];

    char* ws = (char*)d_ws;
    bf16*   XA   = (bf16*)  (ws + 0);
    bf16*   A0   = (bf16*)  (ws + 0);
    int*    idxg = (int*)   (ws + 3145728);
    bf16*   W0p  = (bf16*)  (ws + 3735552);
    bf16*   HF   = (bf16*)  (ws + 6291456);
    float2* part = (float2*)(ws + 6291456);
    bf16*   X1   = (bf16*)  (ws + 6291456);
    bf16*   X2   = (bf16*)  (ws + 10485760);
    bf16*   R1   = (bf16*)  (ws + 12582912);
    bf16*   QIN  = (bf16*)  (ws + 14680064);
    bf16*   P1   = (bf16*)  (ws + 14680064);
    bf16*   P2   = (bf16*)  (ws + 18874368);
    bf16*   C1   = (bf16*)  (ws + 14680064);
    bf16*   C2   = (bf16*)  (ws + 16777216);
    bf16*   Z    = (bf16*)  (ws + 23068672);
    bf16*   R2   = (bf16*)  (ws + 23068672);
    bf16*   CV   = (bf16*)  (ws + 25165824);
    bf16*   WTS  = (bf16*)  (ws + 27262976);  // staged bf16 weights

    bf16* W1  = WTS;
    bf16* WZ  = WTS + 16384;
    bf16* WR  = WTS + 49152;
    bf16* WQ  = WTS + 81920;
    bf16* W2A = WTS + 114688;
    bf16* W2B = WTS + 139264;
    bf16* RW0 = WTS + 147456;
    bf16* RW1 = WTS + 151552;
    bf16* CW0 = WTS + 155648;
    bf16* CW1 = WTS + 159744;

    float* out = (float*)d_out;
    dim3 blk(256);

    /*1*/  knn_partial<<<dim3(32, 4, 2), blk, 0, stream>>>(xyz, part);
    /*2*/  knn_merge<<<dim3(64), blk, 0, stream>>>(part, idxg);
    /*3*/  w0_pad<<<dim3(48), blk, 0, stream>>>(w0, W0p);
    /*3c*/ cvt_weights<<<dim3(640), blk, 0, stream>>>(w1, wz, wr, wq, w2a, w2b, rw0, rw1, cw0, cw1, WTS);
    /*4*/  pack_t<<<dim3(128, 2, 2), blk, 0, stream>>>(cost,   64, A0,  96,   0);
    /*5*/  pack_t<<<dim3(128, 1, 2), blk, 0, stream>>>(flow,    3, A0,  96,  64);
    /*6*/  pack_t<<<dim3(128, 4, 2), blk, 0, stream>>>(feats, 128, HF,  256, 128);
    /*7*/  gemm_k<1><<<dim3(128, 2), blk, 0, stream>>>(A0,  96, W0p, 96,  96, 128, b0, bn0, nullptr, nullptr, P1, 128, 0, nullptr);
    /*8*/  gemm_k<1><<<dim3(128, 2), blk, 0, stream>>>(P1, 128, W1, 128, 128, 128, b1, bn1, nullptr, nullptr, P2, 128, 0, nullptr);
    /*9*/  gather_max<<<dim3(8192), blk, 0, stream>>>(idxg, P2, HF);
    /*10*/ pack_t<<<dim3(128, 2, 2), blk, 0, stream>>>(points, 64, XA,  192,   0);
    /*11*/ pack_t<<<dim3(128, 4, 2), blk, 0, stream>>>(feats, 128, QIN, 256, 128);
    /*12*/ gemm_k<2><<<dim3(128, 2), blk, 0, stream>>>(HF, 256, WZ, 256, 256, 128, bz, nullptr, nullptr, nullptr, Z,   128, 0, nullptr);
    /*13*/ gemm_k<3><<<dim3(128, 2), blk, 0, stream>>>(HF, 256, WR, 256, 256, 128, br, nullptr, HF,      nullptr, QIN, 256, 0, nullptr);
    /*14*/ gemm_k<4><<<dim3(128, 2), blk, 0, stream>>>(QIN,256, WQ, 256, 256, 128, bq, nullptr, HF,      Z,       XA,  192, 64, nullptr);
    /*15*/ gemm_k<0><<<dim3(128, 2), blk, 0, stream>>>(XA, 192, W2A,192, 192, 128, b2a, nullptr, nullptr, nullptr, X1, 128, 0, nullptr);
    /*16*/ gemm_k<6><<<dim3(128, 1), blk, 0, stream>>>(X1, 128, W2B,128, 128,  64, b2b, nullptr, nullptr, nullptr, X2,  64, 0, out);
    /*17*/ gemm_k<5><<<dim3(128, 1), blk, 0, stream>>>(X2,  64, RW0, 64,  64,  64, nullptr, rbn0, nullptr, nullptr, R1, 64, 0, nullptr);
    /*18*/ gemm_k<5><<<dim3(128, 1), blk, 0, stream>>>(R1,  64, RW1, 64,  64,  64, nullptr, rbn1, nullptr, nullptr, R2, 64, 0, nullptr);
    /*19*/ pack_t<<<dim3(128, 2, 2), blk, 0, stream>>>(cost,   64, CV,  64,   0);
    /*20*/ gemm_k<5><<<dim3(128, 1), blk, 0, stream>>>(CV,  64, CW0, 64,  64,  64, nullptr, cbn0, nullptr, nullptr, C1, 64, 0, nullptr);
    /*21*/ gemm_k<5><<<dim3(128, 1), blk, 0, stream>>>(C1,  64, CW1, 64,  64,  64, nullptr, cbn1, nullptr, nullptr, C2, 64, 0, nullptr);
    /*22*/ head_k<<<dim3(64), blk, 0, stream>>>(X2, R2, C2, rw2, rbn2, cw2, cbn2, wfc, bfc, flow, out);

    (void)n_in;
}

// Round 5
// 737.848 us; speedup vs baseline: 1.2289x; 1.2289x over previous
//
#include <hip/hip_runtime.h>
#include <math.h>

typedef __bf16 bf16;
typedef __bf16 bf16x8 __attribute__((ext_vector_type(8)));
typedef float f32x4 __attribute__((ext_vector_type(4)));

#define NPTS 8192
#define MTOT 16384
#define NCHUNK 16
#define CHUNK 512

static __device__ __forceinline__ float b2f(bf16 x) { return (float)x; }
static __device__ __forceinline__ bf16  f2b(float x) { return (bf16)x; }

// ------------------------------------------------------------ diagnostics --
__global__ void diag_k(float* out, float code)
{
    if (threadIdx.x == 0 && blockIdx.x == 0) out[0] = code;
}

// ---------------------------------------------------------------- KNN ------
// partial top-9 per (query, candidate-chunk of 512), f32 coords.
// d2 = (qsq + c.w) - 2*dot — bit-identical formula to the round-4 passing code.
// Selection = unsorted set of 9 with tracked lexicographic max (d, idx):
// equivalent to top_k first-occurrence semantics; order-invariant downstream
// (indices only feed max-over-k). Batch of 8 distances for ILP; insert path
// guarded by a conservative any(d<=mx) test (rare after warm-up).
__global__ __launch_bounds__(256) void knn_partial(const float* __restrict__ xyz,
                                                   float2* __restrict__ part)
{
    __shared__ float4 pts[CHUNK];              // 8 KB
    const int t  = threadIdx.x;
    const int b  = blockIdx.z;
    const int nb = blockIdx.x * 256;
    const int cb = blockIdx.y * CHUNK;
    const float* X = xyz + b * 3 * NPTS;
    for (int i = t; i < CHUNK; i += 256) {
        float x = X[cb + i];
        float y = X[NPTS + cb + i];
        float z = X[2 * NPTS + cb + i];
        pts[i] = make_float4(x, y, z, x * x + y * y + z * z);
    }
    __syncthreads();
    const int n = nb + t;
    float qx = X[n], qy = X[NPTS + n], qz = X[2 * NPTS + n];
    float qsq = qx * qx + qy * qy + qz * qz;

    float dd[9]; int ii[9];
#pragma unroll
    for (int k = 0; k < 9; ++k) { dd[k] = __builtin_inff(); ii[k] = k; }
    float mx = __builtin_inff(); int mxi = 8, ms = 8;

    for (int i = 0; i < CHUNK; i += 8) {
        float d[8];
#pragma unroll
        for (int u = 0; u < 8; ++u) {
            float4 c = pts[i + u];
            d[u] = (qsq + c.w) - 2.0f * (qx * c.x + qy * c.y + qz * c.z);
        }
        bool any = false;
#pragma unroll
        for (int u = 0; u < 8; ++u) any = any || (d[u] <= mx);
        if (any) {
#pragma unroll
            for (int u = 0; u < 8; ++u) {
                const int m = cb + i + u;
                if (d[u] < mx || (d[u] == mx && m < mxi)) {
                    // replace current lex-max slot (unrolled: no dynamic index)
#pragma unroll
                    for (int k = 0; k < 9; ++k)
                        if (k == ms) { dd[k] = d[u]; ii[k] = m; }
                    // rescan for new lex-max
                    mx = dd[0]; mxi = ii[0]; ms = 0;
#pragma unroll
                    for (int k = 1; k < 9; ++k) {
                        bool g = (dd[k] > mx) || (dd[k] == mx && ii[k] > mxi);
                        if (g) { mx = dd[k]; mxi = ii[k]; ms = k; }
                    }
                }
            }
        }
    }
    // transposed layout: part[(chunk*9+k)*MTOT + j] -> coalesced write & read
    const int j = b * NPTS + n;
#pragma unroll
    for (int k = 0; k < 9; ++k)
        part[(size_t)(blockIdx.y * 9 + k) * MTOT + j] =
            make_float2(dd[k], __int_as_float(ii[k]));
}

// merge 16 chunk-partials (144 entries) -> final 9 neighbor row-indices
__global__ __launch_bounds__(256) void knn_merge(const float2* __restrict__ part,
                                                 int* __restrict__ idxg)
{
    const int j = blockIdx.x * 256 + threadIdx.x;
    float dd[9]; int ii[9];
#pragma unroll
    for (int k = 0; k < 9; ++k) { dd[k] = __builtin_inff(); ii[k] = k; }
    float mx = __builtin_inff(); int mxi = 8, ms = 8;

    for (int c = 0; c < 9 * NCHUNK; c += 4) {
        float2 e[4];
#pragma unroll
        for (int u = 0; u < 4; ++u) e[u] = part[(size_t)(c + u) * MTOT + j];
        bool any = false;
#pragma unroll
        for (int u = 0; u < 4; ++u) any = any || (e[u].x <= mx);
        if (any) {
#pragma unroll
            for (int u = 0; u < 4; ++u) {
                float d = e[u].x; int m = __float_as_int(e[u].y);
                if (d < mx || (d == mx && m < mxi)) {
#pragma unroll
                    for (int k = 0; k < 9; ++k)
                        if (k == ms) { dd[k] = d; ii[k] = m; }
                    mx = dd[0]; mxi = ii[0]; ms = 0;
#pragma unroll
                    for (int k = 1; k < 9; ++k) {
                        bool g = (dd[k] > mx) || (dd[k] == mx && ii[k] > mxi);
                        if (g) { mx = dd[k]; mxi = ii[k]; ms = k; }
                    }
                }
            }
        }
    }
    const int base = (j >> 13) * NPTS;
#pragma unroll
    for (int k = 0; k < 9; ++k) {
        int m = ii[k];
        m = ((unsigned)m < (unsigned)NPTS) ? m : 0;   // fault-proof
        idxg[j * 9 + k] = base + m;
    }
}

// --------------------------------------------------------------- pack ------
// f32 [B][C][N] channel-major -> bf16 point-major [M][ldd] at column offset,
// zero-pad c>=Csrc.
__global__ __launch_bounds__(256) void pack_t(const float* __restrict__ src, int Csrc,
                                              bf16* __restrict__ dst, int ldd, int colOfs)
{
    __shared__ bf16 tile[32][68];
    const int t  = threadIdx.x;
    const int nb = blockIdx.x * 64;
    const int cb = blockIdx.y * 32;
    const int b  = blockIdx.z;
#pragma unroll
    for (int i = 0; i < 8; ++i) {
        int id = t + i * 256;
        int c = id >> 6, n = id & 63;
        int cc = cb + c;
        bf16 v = (bf16)0.0f;
        if (cc < Csrc) v = f2b(src[(size_t)(b * Csrc + cc) * NPTS + nb + n]);
        tile[c][n] = v;
    }
    __syncthreads();
#pragma unroll
    for (int i = 0; i < 8; ++i) {
        int id = t + i * 256;
        int n = id >> 5, c = id & 31;
        dst[(size_t)(b * NPTS + nb + n) * ldd + colOfs + cb + c] = tile[c][n];
    }
}

// pad w0 f32 [128][67] -> bf16 [128][96] zeros beyond 67
__global__ __launch_bounds__(256) void w0_pad(const float* __restrict__ w0,
                                              bf16* __restrict__ w0p)
{
    int id = blockIdx.x * 256 + threadIdx.x;
    if (id < 128 * 96) {
        int o = id / 96, c = id - o * 96;
        w0p[id] = (c < 67) ? f2b(w0[o * 67 + c]) : (bf16)0.0f;
    }
}

// stage all dense GEMM weights f32 -> bf16 contiguous in ws
__global__ __launch_bounds__(256) void cvt_weights(
    const float* __restrict__ w1, const float* __restrict__ wz,
    const float* __restrict__ wr, const float* __restrict__ wq,
    const float* __restrict__ w2a, const float* __restrict__ w2b,
    const float* __restrict__ rw0, const float* __restrict__ rw1,
    const float* __restrict__ cw0, const float* __restrict__ cw1,
    bf16* __restrict__ dst)
{
    int id = blockIdx.x * 256 + threadIdx.x;
    if (id >= 163840) return;
    const float* s; int off;
    if (id < 16384)       { s = w1;  off = 0; }
    else if (id < 49152)  { s = wz;  off = 16384; }
    else if (id < 81920)  { s = wr;  off = 49152; }
    else if (id < 114688) { s = wq;  off = 81920; }
    else if (id < 139264) { s = w2a; off = 114688; }
    else if (id < 147456) { s = w2b; off = 139264; }
    else if (id < 151552) { s = rw0; off = 147456; }
    else if (id < 155648) { s = rw1; off = 151552; }
    else if (id < 159744) { s = cw0; off = 155648; }
    else                  { s = cw1; off = 159744; }
    dst[id] = f2b(s[id - off]);
}

// --------------------------------------------------------------- GEMM ------
// out[j][o] = epi( sum_c A[j][c] * W[o][c] ). A bf16 point-major [M][lda],
// W bf16 [O][ldw] (staged). MFMA 16x16x32 bf16 NT:
// A-frag lane(q=lane>>4,r=lane&15): A[pt=r][k=q*8+j]; B-frag: W[o=r][k=q*8+j];
// C/D: col(lane&15)=o, row=q*4+reg=pt (m89 mapping).
// Wave tile 64pt x 32o; block = 2x2 waves = 128pt x 64o.
template <int EPI>
__global__ __launch_bounds__(256) void gemm_k(
    const bf16* __restrict__ A, int lda,
    const bf16* __restrict__ W, int ldw, int K, int Otot,
    const float* __restrict__ bias, const float* __restrict__ bnp,
    const bf16* __restrict__ aux1, const bf16* __restrict__ aux2,
    bf16* __restrict__ dst, int ldo, int dofs,
    float* __restrict__ out2)
{
    const int w = threadIdx.x >> 6, lane = threadIdx.x & 63;
    const int q = lane >> 4, r = lane & 15;
    const int ptb = blockIdx.x * 128 + (w & 1) * 64;
    const int ob  = blockIdx.y * 64 + (w >> 1) * 32;
    const bf16* Ap = A + (size_t)(ptb + r) * lda + q * 8;
    const bf16* Wp = W + (size_t)(ob + r) * ldw + q * 8;
    f32x4 zero = {0.f, 0.f, 0.f, 0.f};
    f32x4 acc[4][2];
#pragma unroll
    for (int i = 0; i < 4; ++i) { acc[i][0] = zero; acc[i][1] = zero; }
    for (int k = 0; k < K; k += 32) {
        bf16x8 bv0 = *(const bf16x8*)(Wp + k);
        bf16x8 bv1 = *(const bf16x8*)(Wp + 16 * ldw + k);
        bf16x8 a0 = *(const bf16x8*)(Ap + k);
        bf16x8 a1 = *(const bf16x8*)(Ap + 16 * lda + k);
        bf16x8 a2 = *(const bf16x8*)(Ap + 32 * lda + k);
        bf16x8 a3 = *(const bf16x8*)(Ap + 48 * lda + k);
        acc[0][0] = __builtin_amdgcn_mfma_f32_16x16x32_bf16(a0, bv0, acc[0][0], 0, 0, 0);
        acc[1][0] = __builtin_amdgcn_mfma_f32_16x16x32_bf16(a1, bv0, acc[1][0], 0, 0, 0);
        acc[2][0] = __builtin_amdgcn_mfma_f32_16x16x32_bf16(a2, bv0, acc[2][0], 0, 0, 0);
        acc[3][0] = __builtin_amdgcn_mfma_f32_16x16x32_bf16(a3, bv0, acc[3][0], 0, 0, 0);
        acc[0][1] = __builtin_amdgcn_mfma_f32_16x16x32_bf16(a0, bv1, acc[0][1], 0, 0, 0);
        acc[1][1] = __builtin_amdgcn_mfma_f32_16x16x32_bf16(a1, bv1, acc[1][1], 0, 0, 0);
        acc[2][1] = __builtin_amdgcn_mfma_f32_16x16x32_bf16(a2, bv1, acc[2][1], 0, 0, 0);
        acc[3][1] = __builtin_amdgcn_mfma_f32_16x16x32_bf16(a3, bv1, acc[3][1], 0, 0, 0);
    }
#pragma unroll
    for (int to = 0; to < 2; ++to) {
        const int o = ob + to * 16 + r;
        float bs = 0.f, gg = 0.f, be = 0.f, mm = 0.f, rs = 0.f;
        if (EPI != 5) bs = bias[o];
        if (EPI == 1 || EPI == 5) {
            gg = bnp[o]; be = bnp[Otot + o]; mm = bnp[2 * Otot + o];
            float vv = bnp[3 * Otot + o];
            rs = 1.0f / sqrtf(vv + 1e-5f);
        }
#pragma unroll
        for (int tm = 0; tm < 4; ++tm) {
#pragma unroll
            for (int rr = 0; rr < 4; ++rr) {
                const int j = ptb + tm * 16 + q * 4 + rr;
                float v = acc[tm][to][rr];
                if (EPI == 0) { v += bs; v = v > 0.f ? v : 0.1f * v; }
                else if (EPI == 1) { v += bs; v = (v - mm) * rs * gg + be; v = v > 0.f ? v : 0.1f * v; }
                else if (EPI == 2) { v += bs; v = 1.0f / (1.0f + expf(-v)); }
                else if (EPI == 3) { v += bs; v = 1.0f / (1.0f + expf(-v));
                                     v *= b2f(aux1[(size_t)j * 256 + o]); }
                else if (EPI == 4) {
                    v += bs; float qv = tanhf(v);
                    float z = b2f(aux2[(size_t)j * 128 + o]);
                    float h = b2f(aux1[(size_t)j * 256 + o]);
                    v = (1.0f - z) * h + z * qv;
                }
                else if (EPI == 5) { v = (v - mm) * rs * gg + be; v = fmaxf(v, 0.f); }
                else if (EPI == 6) { v += bs; v = v > 0.f ? v : 0.1f * v; }
                dst[(size_t)j * ldo + dofs + o] = f2b(v);
                if (EPI == 6) {
                    int bb = j >> 13, n = j & (NPTS - 1);
                    out2[(size_t)bb * 64 * NPTS + (size_t)o * NPTS + n] = v;
                }
            }
        }
    }
}

// ---------------------------------------------------------- gather-max -----
__global__ __launch_bounds__(256) void gather_max(const int* __restrict__ idxg,
                                                  const bf16* __restrict__ P2,
                                                  bf16* __restrict__ HF)
{
    const int id = blockIdx.x * 256 + threadIdx.x;
    const int j = id >> 7, o = id & 127;
    const int* ip = idxg + j * 9;
    float v = -__builtin_inff();
#pragma unroll
    for (int k = 0; k < 9; ++k) {
        int m = ip[k];
        m = ((unsigned)m < (unsigned)MTOT) ? m : 0;   // fault-proof
        v = fmaxf(v, b2f(P2[(size_t)m * 128 + o]));
    }
    HF[(size_t)j * 256 + o] = f2b(v);
}

// --------------------------------------------------------------- head ------
__global__ __launch_bounds__(256) void head_k(
    const bf16* __restrict__ X2, const bf16* __restrict__ R2v, const bf16* __restrict__ C2v,
    const float* __restrict__ rw2, const float* __restrict__ rbn2,
    const float* __restrict__ cw2, const float* __restrict__ cbn2,
    const float* __restrict__ wfc, const float* __restrict__ bfc,
    const float* __restrict__ flow, float* __restrict__ out)
{
    const int j = blockIdx.x * 256 + threadIdx.x;
    const int b = j >> 13, n = j & (NPTS - 1);
    const bf16x8* xr = (const bf16x8*)(X2 + (size_t)j * 64);
    const bf16x8* rr = (const bf16x8*)(R2v + (size_t)j * 64);
    const bf16x8* cr = (const bf16x8*)(C2v + (size_t)j * 64);
    float dr = 0.f, dc = 0.f, p0 = 0.f, p1 = 0.f, p2 = 0.f;
#pragma unroll
    for (int bk = 0; bk < 8; ++bk) {
        bf16x8 xv = xr[bk], rv = rr[bk], cv = cr[bk];
#pragma unroll
        for (int i = 0; i < 8; ++i) {
            const int c = bk * 8 + i;
            float x = (float)xv[i];
            dr += rw2[c] * (float)rv[i];
            dc += cw2[c] * (float)cv[i];
            p0 += wfc[c] * x;
            p1 += wfc[64 + c] * x;
            p2 += wfc[128 + c] * x;
        }
    }
    float refine = (dr - rbn2[2]) / sqrtf(rbn2[3] + 1e-5f) * rbn2[0] + rbn2[1];
    refine = fmaxf(refine, 0.f);
    float coarse = (dc - cbn2[2]) / sqrtf(cbn2[3] + 1e-5f) * cbn2[0] + cbn2[1];
    coarse = fmaxf(coarse, 0.f);
    p0 += bfc[0]; p1 += bfc[1]; p2 += bfc[2];
    const float f0 = flow[(size_t)b * 3 * NPTS + n];
    const float f1 = flow[(size_t)b * 3 * NPTS + NPTS + n];
    const float f2v = flow[(size_t)b * 3 * NPTS + 2 * NPTS + n];
    float o0 = fminf(fmaxf(coarse * f0 + refine * p0, -20.f), 20.f);
    float o1 = fminf(fmaxf(coarse * f1 + refine * p1, -20.f), 20.f);
    float o2 = fminf(fmaxf(coarse * f2v + refine * p2, -20.f), 20.f);
    float* ro = out + 1048576; // x section = 2*64*8192 f32 elements
    ro[(size_t)b * 3 * NPTS + n] = o0;
    ro[(size_t)b * 3 * NPTS + NPTS + n] = o1;
    ro[(size_t)b * 3 * NPTS + 2 * NPTS + n] = o2;
}

// -------------------------------------------------------------- launch -----
// Workspace (27,590,656 B), lifetime-aliased; steps = launch order.
//   part @3,735,552 18,874,368 [1->2]   (16 chunks x 9 x MTOT float2, transposed)
//   region XA  @0          6,291,456  XA [14->15]
//     A0 @0 3,145,728 [4->7] | idxg @3,145,728 589,824 [2->9] | W0p @3,735,552 [3->7]
//   region HF  @6,291,456  8,388,608  HF [6->14]
//     X1 @6,291,456 [15->16] | X2 @10,485,760 [16->22] | R1 @12,582,912 [17->18]
//   region QIN @14,680,064 8,388,608  QIN [11->14]
//     P1 @14,680,064 [7->8] | P2 @18,874,368 [8->9]
//     C1 @14,680,064 [20->21] | C2 @16,777,216 [21->22]
//   region Z   @23,068,672 4,194,304  Z [12->14]
//     R2 @23,068,672 [18->22] | CV @25,165,824 [19->20]
//   region WTS @27,262,976 327,680  staged bf16 weights [3c->21]
// part [1->2] overlaps only W0p/HF/QIN/Z regions, all first written >= step 3. OK.
extern "C" void kernel_launch(void* const* d_in, const int* in_sizes, int n_in,
                              void* d_out, int out_size, void* d_ws, size_t ws_size,
                              hipStream_t stream)
{
    static const int EXP[35] = {
        49152, 1048576, 1048576, 2097152, 49152,
        8576, 128, 512, 16384, 128, 512,
        32768, 128, 32768, 128, 32768, 128,
        24576, 128, 8192, 64, 192, 3,
        4096, 256, 4096, 256, 64, 4,
        4096, 256, 4096, 256, 64, 4 };
    float code = 0.f;
    if (n_in != 35) code = 900.f;
    else if (out_size != 1097728) code = 950.f;
    else if (ws_size < 27590656u) code = 980.f;
    else { for (int i = 0; i < 35; ++i) if (in_sizes[i] != EXP[i]) { code = 1000.f + 4.f * i; break; } }
    if (code != 0.f) { diag_k<<<dim3(1), dim3(64), 0, stream>>>((float*)d_out, code); return; }

    const float* xyz    = (const float*)d_in[0];
    const float* points = (const float*)d_in[1];
    const float* cost   = (const float*)d_in[2];
    const float* feats  = (const float*)d_in[3];
    const float* flow   = (const float*)d_in[4];
    const float* w0     = (const float*)d_in[5];
    const float* b0     = (const float*)d_in[6];
    const float* bn0    = (const float*)d_in[7];
    const float* w1     = (const float*)d_in[8];
    const float* b1     = (const float*)d_in[9];
    const float* bn1    = (const float*)d_in[10];
    const float* wz     = (const float*)d_in[11];
    const float* bz     = (const float*)d_in[12];
    const float* wr     = (const float*)d_in[13];
    const float* br     = (const float*)d_in[14];
    const float* wq     = (const float*)d_in[15];
    const float* bq     = (const float*)d_in[16];
    const float* w2a    = (const float*)d_in[17];
    const float* b2a    = (const float*)d_in[18];
    const float* w2b    = (const float*)d_in[19];
    const float* b2b    = (const float*)d_in[20];
    const float* wfc    = (const float*)d_in[21];
    const float* bfc    = (const float*)d_in[22];
    const float* rw0    = (const float*)d_in[23];
    const float* rbn0   = (const float*)d_in[24];
    const float* rw1    = (const float*)d_in[25];
    const float* rbn1   = (const float*)d_in[26];
    const float* rw2    = (const float*)d_in[27];
    const float* rbn2   = (const float*)d_in[28];
    const float* cw0    = (const float*)d_in[29];
    const float* cbn0   = (const float*)d_in[30];
    const float* cw1    = (const float*)d_in[31];
    const float* cbn1   = (const float*)d_in[32];
    const float* cw2    = (const float*)d_in[33];
    const float* cbn2   = (const float*)d_in[34];

    char* ws = (char*)d_ws;
    bf16*   XA   = (bf16*)  (ws + 0);
    bf16*   A0   = (bf16*)  (ws + 0);
    int*    idxg = (int*)   (ws + 3145728);
    bf16*   W0p  = (bf16*)  (ws + 3735552);
    float2* part = (float2*)(ws + 3735552);
    bf16*   HF   = (bf16*)  (ws + 6291456);
    bf16*   X1   = (bf16*)  (ws + 6291456);
    bf16*   X2   = (bf16*)  (ws + 10485760);
    bf16*   R1   = (bf16*)  (ws + 12582912);
    bf16*   QIN  = (bf16*)  (ws + 14680064);
    bf16*   P1   = (bf16*)  (ws + 14680064);
    bf16*   P2   = (bf16*)  (ws + 18874368);
    bf16*   C1   = (bf16*)  (ws + 14680064);
    bf16*   C2   = (bf16*)  (ws + 16777216);
    bf16*   Z    = (bf16*)  (ws + 23068672);
    bf16*   R2   = (bf16*)  (ws + 23068672);
    bf16*   CV   = (bf16*)  (ws + 25165824);
    bf16*   WTS  = (bf16*)  (ws + 27262976);  // staged bf16 weights

    bf16* W1  = WTS;
    bf16* WZ  = WTS + 16384;
    bf16* WR  = WTS + 49152;
    bf16* WQ  = WTS + 81920;
    bf16* W2A = WTS + 114688;
    bf16* W2B = WTS + 139264;
    bf16* RW0 = WTS + 147456;
    bf16* RW1 = WTS + 151552;
    bf16* CW0 = WTS + 155648;
    bf16* CW1 = WTS + 159744;

    float* out = (float*)d_out;
    dim3 blk(256);

    /*1*/  knn_partial<<<dim3(32, NCHUNK, 2), blk, 0, stream>>>(xyz, part);
    /*2*/  knn_merge<<<dim3(64), blk, 0, stream>>>(part, idxg);
    /*3*/  w0_pad<<<dim3(48), blk, 0, stream>>>(w0, W0p);
    /*3c*/ cvt_weights<<<dim3(640), blk, 0, stream>>>(w1, wz, wr, wq, w2a, w2b, rw0, rw1, cw0, cw1, WTS);
    /*4*/  pack_t<<<dim3(128, 2, 2), blk, 0, stream>>>(cost,   64, A0,  96,   0);
    /*5*/  pack_t<<<dim3(128, 1, 2), blk, 0, stream>>>(flow,    3, A0,  96,  64);
    /*6*/  pack_t<<<dim3(128, 4, 2), blk, 0, stream>>>(feats, 128, HF,  256, 128);
    /*7*/  gemm_k<1><<<dim3(128, 2), blk, 0, stream>>>(A0,  96, W0p, 96,  96, 128, b0, bn0, nullptr, nullptr, P1, 128, 0, nullptr);
    /*8*/  gemm_k<1><<<dim3(128, 2), blk, 0, stream>>>(P1, 128, W1, 128, 128, 128, b1, bn1, nullptr, nullptr, P2, 128, 0, nullptr);
    /*9*/  gather_max<<<dim3(8192), blk, 0, stream>>>(idxg, P2, HF);
    /*10*/ pack_t<<<dim3(128, 2, 2), blk, 0, stream>>>(points, 64, XA,  192,   0);
    /*11*/ pack_t<<<dim3(128, 4, 2), blk, 0, stream>>>(feats, 128, QIN, 256, 128);
    /*12*/ gemm_k<2><<<dim3(128, 2), blk, 0, stream>>>(HF, 256, WZ, 256, 256, 128, bz, nullptr, nullptr, nullptr, Z,   128, 0, nullptr);
    /*13*/ gemm_k<3><<<dim3(128, 2), blk, 0, stream>>>(HF, 256, WR, 256, 256, 128, br, nullptr, HF,      nullptr, QIN, 256, 0, nullptr);
    /*14*/ gemm_k<4><<<dim3(128, 2), blk, 0, stream>>>(QIN,256, WQ, 256, 256, 128, bq, nullptr, HF,      Z,       XA,  192, 64, nullptr);
    /*15*/ gemm_k<0><<<dim3(128, 2), blk, 0, stream>>>(XA, 192, W2A,192, 192, 128, b2a, nullptr, nullptr, nullptr, X1, 128, 0, nullptr);
    /*16*/ gemm_k<6><<<dim3(128, 1), blk, 0, stream>>>(X1, 128, W2B,128, 128,  64, b2b, nullptr, nullptr, nullptr, X2,  64, 0, out);
    /*17*/ gemm_k<5><<<dim3(128, 1), blk, 0, stream>>>(X2,  64, RW0, 64,  64,  64, nullptr, rbn0, nullptr, nullptr, R1, 64, 0, nullptr);
    /*18*/ gemm_k<5><<<dim3(128, 1), blk, 0, stream>>>(R1,  64, RW1, 64,  64,  64, nullptr, rbn1, nullptr, nullptr, R2, 64, 0, nullptr);
    /*19*/ pack_t<<<dim3(128, 2, 2), blk, 0, stream>>>(cost,   64, CV,  64,   0);
    /*20*/ gemm_k<5><<<dim3(128, 1), blk, 0, stream>>>(CV,  64, CW0, 64,  64,  64, nullptr, cbn0, nullptr, nullptr, C1, 64, 0, nullptr);
    /*21*/ gemm_k<5><<<dim3(128, 1), blk, 0, stream>>>(C1,  64, CW1, 64,  64,  64, nullptr, cbn1, nullptr, nullptr, C2, 64, 0, nullptr);
    /*22*/ head_k<<<dim3(64), blk, 0, stream>>>(X2, R2, C2, rw2, rbn2, cw2, cbn2, wfc, bfc, flow, out);

    (void)n_in;
}

// Round 6
// 510.395 us; speedup vs baseline: 1.7765x; 1.4456x over previous
//
#include <hip/hip_runtime.h>
#include <math.h>

typedef __bf16 bf16;
typedef __bf16 bf16x8 __attribute__((ext_vector_type(8)));
typedef float f32x4 __attribute__((ext_vector_type(4)));

#define NPTS 8192
#define MTOT 16384

static __device__ __forceinline__ float b2f(bf16 x) { return (float)x; }
static __device__ __forceinline__ bf16  f2b(float x) { return (bf16)x; }

// ------------------------------------------------------------ diagnostics --
__global__ void diag_k(float* out, float code)
{
    if (threadIdx.x == 0 && blockIdx.x == 0) out[0] = code;
}

// ---------------------------------------------------------------- KNN ------
// prep: P4[j] = (x, y, z, x^2+y^2+z^2) for all 16384 points
__global__ __launch_bounds__(256) void knn_prep(const float* __restrict__ xyz,
                                                float4* __restrict__ P4)
{
    const int id = blockIdx.x * 256 + threadIdx.x;   // 0..16383
    const int b = id >> 13, n = id & (NPTS - 1);
    const float* X = xyz + b * 3 * NPTS;
    float x = X[n], y = X[NPTS + n], z = X[2 * NPTS + n];
    P4[id] = make_float4(x, y, z, x * x + y * y + z * z);
}

// one WAVE per query: 64 lanes compute 64 candidate distances/iter; the
// wave-uniform ballot(d <= tau) gates the (rare) insert path, so there is
// no exec-mask divergence at all. Single continuous scan over all 8192
// candidates (no chunk restarts, no merge pass). Lex (d, idx) selection =
// jax.lax.top_k first-occurrence semantics; d2 = (qsq + csq) - 2*dot in f32
// (formula identical to the passing round-4/5 kernels).
__global__ __launch_bounds__(256) void knn_wave(const float4* __restrict__ P4,
                                                int* __restrict__ idxg)
{
    __shared__ float4 pts[2048];               // 32 KB -> 5 blocks/CU
    const int t = threadIdx.x, lane = t & 63, w = t >> 6;
    const int qid = blockIdx.x * 4 + w;        // 0..16383
    const int b = qid >> 13;
    const float4 q = P4[qid];                  // wave-uniform broadcast
    const float4* C0 = P4 + (size_t)b * NPTS;

    float dd[9]; int ii[9];                    // sorted ascending (d, idx)
#pragma unroll
    for (int k = 0; k < 9; ++k) { dd[k] = __builtin_inff(); ii[k] = k; }

    for (int cb = 0; cb < NPTS; cb += 2048) {
        __syncthreads();
        for (int i = t; i < 2048; i += 256) pts[i] = C0[cb + i];
        __syncthreads();
        for (int i = 0; i < 2048; i += 64) {
            float4 c = pts[i + lane];
            float d = (q.w + c.w) - 2.0f * (q.x * c.x + q.y * c.y + q.z * c.z);
            unsigned long long mask = __ballot(d <= dd[8]);  // conservative
            while (mask) {                      // wave-uniform loop
                int L = __builtin_ctzll(mask);
                mask &= mask - 1;
                float dL = __shfl(d, L);        // uniform broadcast
                int   mL = cb + i + L;
                if (dL < dd[8] || (dL == dd[8] && mL < ii[8])) {
                    dd[8] = dL; ii[8] = mL;
#pragma unroll
                    for (int k = 8; k > 0; --k) {
                        float a0 = dd[k - 1], a1 = dd[k];
                        int   b0v = ii[k - 1], b1v = ii[k];
                        bool sw = (a1 < a0) || (a1 == a0 && b1v < b0v);
                        dd[k - 1] = sw ? a1 : a0;  dd[k] = sw ? a0 : a1;
                        ii[k - 1] = sw ? b1v : b0v; ii[k] = sw ? b0v : b1v;
                    }
                }
            }
        }
    }
    if (lane < 9) {
        int m = ii[lane];
        m = ((unsigned)m < (unsigned)NPTS) ? m : 0;   // fault-proof
        idxg[qid * 9 + lane] = b * NPTS + m;
    }
}

// --------------------------------------------------------------- pack ------
// f32 [B][C][N] channel-major -> bf16 point-major [M][ldd] at column offset,
// zero-pad c>=Csrc.
__global__ __launch_bounds__(256) void pack_t(const float* __restrict__ src, int Csrc,
                                              bf16* __restrict__ dst, int ldd, int colOfs)
{
    __shared__ bf16 tile[32][68];
    const int t  = threadIdx.x;
    const int nb = blockIdx.x * 64;
    const int cb = blockIdx.y * 32;
    const int b  = blockIdx.z;
#pragma unroll
    for (int i = 0; i < 8; ++i) {
        int id = t + i * 256;
        int c = id >> 6, n = id & 63;
        int cc = cb + c;
        bf16 v = (bf16)0.0f;
        if (cc < Csrc) v = f2b(src[(size_t)(b * Csrc + cc) * NPTS + nb + n]);
        tile[c][n] = v;
    }
    __syncthreads();
#pragma unroll
    for (int i = 0; i < 8; ++i) {
        int id = t + i * 256;
        int n = id >> 5, c = id & 31;
        dst[(size_t)(b * NPTS + nb + n) * ldd + colOfs + cb + c] = tile[c][n];
    }
}

// pad w0 f32 [128][67] -> bf16 [128][96] zeros beyond 67
__global__ __launch_bounds__(256) void w0_pad(const float* __restrict__ w0,
                                              bf16* __restrict__ w0p)
{
    int id = blockIdx.x * 256 + threadIdx.x;
    if (id < 128 * 96) {
        int o = id / 96, c = id - o * 96;
        w0p[id] = (c < 67) ? f2b(w0[o * 67 + c]) : (bf16)0.0f;
    }
}

// stage all dense GEMM weights f32 -> bf16 contiguous in ws
__global__ __launch_bounds__(256) void cvt_weights(
    const float* __restrict__ w1, const float* __restrict__ wz,
    const float* __restrict__ wr, const float* __restrict__ wq,
    const float* __restrict__ w2a, const float* __restrict__ w2b,
    const float* __restrict__ rw0, const float* __restrict__ rw1,
    const float* __restrict__ cw0, const float* __restrict__ cw1,
    bf16* __restrict__ dst)
{
    int id = blockIdx.x * 256 + threadIdx.x;
    if (id >= 163840) return;
    const float* s; int off;
    if (id < 16384)       { s = w1;  off = 0; }
    else if (id < 49152)  { s = wz;  off = 16384; }
    else if (id < 81920)  { s = wr;  off = 49152; }
    else if (id < 114688) { s = wq;  off = 81920; }
    else if (id < 139264) { s = w2a; off = 114688; }
    else if (id < 147456) { s = w2b; off = 139264; }
    else if (id < 151552) { s = rw0; off = 147456; }
    else if (id < 155648) { s = rw1; off = 151552; }
    else if (id < 159744) { s = cw0; off = 155648; }
    else                  { s = cw1; off = 159744; }
    dst[id] = f2b(s[id - off]);
}

// --------------------------------------------------------------- GEMM ------
// out[j][o] = epi( sum_c A[j][c] * W[o][c] ). A bf16 point-major [M][lda],
// W bf16 [O][ldw] (staged). MFMA 16x16x32 bf16 NT:
// A-frag lane(q=lane>>4,r=lane&15): A[pt=r][k=q*8+j]; B-frag: W[o=r][k=q*8+j];
// C/D: col(lane&15)=o, row=q*4+reg=pt (m89 mapping).
// Wave tile 64pt x 32o; block = 2x2 waves = 128pt x 64o.
template <int EPI>
__global__ __launch_bounds__(256) void gemm_k(
    const bf16* __restrict__ A, int lda,
    const bf16* __restrict__ W, int ldw, int K, int Otot,
    const float* __restrict__ bias, const float* __restrict__ bnp,
    const bf16* __restrict__ aux1, const bf16* __restrict__ aux2,
    bf16* __restrict__ dst, int ldo, int dofs,
    float* __restrict__ out2)
{
    const int w = threadIdx.x >> 6, lane = threadIdx.x & 63;
    const int q = lane >> 4, r = lane & 15;
    const int ptb = blockIdx.x * 128 + (w & 1) * 64;
    const int ob  = blockIdx.y * 64 + (w >> 1) * 32;
    const bf16* Ap = A + (size_t)(ptb + r) * lda + q * 8;
    const bf16* Wp = W + (size_t)(ob + r) * ldw + q * 8;
    f32x4 zero = {0.f, 0.f, 0.f, 0.f};
    f32x4 acc[4][2];
#pragma unroll
    for (int i = 0; i < 4; ++i) { acc[i][0] = zero; acc[i][1] = zero; }
    for (int k = 0; k < K; k += 32) {
        bf16x8 bv0 = *(const bf16x8*)(Wp + k);
        bf16x8 bv1 = *(const bf16x8*)(Wp + 16 * ldw + k);
        bf16x8 a0 = *(const bf16x8*)(Ap + k);
        bf16x8 a1 = *(const bf16x8*)(Ap + 16 * lda + k);
        bf16x8 a2 = *(const bf16x8*)(Ap + 32 * lda + k);
        bf16x8 a3 = *(const bf16x8*)(Ap + 48 * lda + k);
        acc[0][0] = __builtin_amdgcn_mfma_f32_16x16x32_bf16(a0, bv0, acc[0][0], 0, 0, 0);
        acc[1][0] = __builtin_amdgcn_mfma_f32_16x16x32_bf16(a1, bv0, acc[1][0], 0, 0, 0);
        acc[2][0] = __builtin_amdgcn_mfma_f32_16x16x32_bf16(a2, bv0, acc[2][0], 0, 0, 0);
        acc[3][0] = __builtin_amdgcn_mfma_f32_16x16x32_bf16(a3, bv0, acc[3][0], 0, 0, 0);
        acc[0][1] = __builtin_amdgcn_mfma_f32_16x16x32_bf16(a0, bv1, acc[0][1], 0, 0, 0);
        acc[1][1] = __builtin_amdgcn_mfma_f32_16x16x32_bf16(a1, bv1, acc[1][1], 0, 0, 0);
        acc[2][1] = __builtin_amdgcn_mfma_f32_16x16x32_bf16(a2, bv1, acc[2][1], 0, 0, 0);
        acc[3][1] = __builtin_amdgcn_mfma_f32_16x16x32_bf16(a3, bv1, acc[3][1], 0, 0, 0);
    }
#pragma unroll
    for (int to = 0; to < 2; ++to) {
        const int o = ob + to * 16 + r;
        float bs = 0.f, gg = 0.f, be = 0.f, mm = 0.f, rs = 0.f;
        if (EPI != 5) bs = bias[o];
        if (EPI == 1 || EPI == 5) {
            gg = bnp[o]; be = bnp[Otot + o]; mm = bnp[2 * Otot + o];
            float vv = bnp[3 * Otot + o];
            rs = 1.0f / sqrtf(vv + 1e-5f);
        }
#pragma unroll
        for (int tm = 0; tm < 4; ++tm) {
#pragma unroll
            for (int rr = 0; rr < 4; ++rr) {
                const int j = ptb + tm * 16 + q * 4 + rr;
                float v = acc[tm][to][rr];
                if (EPI == 0) { v += bs; v = v > 0.f ? v : 0.1f * v; }
                else if (EPI == 1) { v += bs; v = (v - mm) * rs * gg + be; v = v > 0.f ? v : 0.1f * v; }
                else if (EPI == 2) { v += bs; v = 1.0f / (1.0f + expf(-v)); }
                else if (EPI == 3) { v += bs; v = 1.0f / (1.0f + expf(-v));
                                     v *= b2f(aux1[(size_t)j * 256 + o]); }
                else if (EPI == 4) {
                    v += bs; float qv = tanhf(v);
                    float z = b2f(aux2[(size_t)j * 128 + o]);
                    float h = b2f(aux1[(size_t)j * 256 + o]);
                    v = (1.0f - z) * h + z * qv;
                }
                else if (EPI == 5) { v = (v - mm) * rs * gg + be; v = fmaxf(v, 0.f); }
                else if (EPI == 6) { v += bs; v = v > 0.f ? v : 0.1f * v; }
                dst[(size_t)j * ldo + dofs + o] = f2b(v);
                if (EPI == 6) {
                    int bb = j >> 13, n = j & (NPTS - 1);
                    out2[(size_t)bb * 64 * NPTS + (size_t)o * NPTS + n] = v;
                }
            }
        }
    }
}

// ---------------------------------------------------------- gather-max -----
__global__ __launch_bounds__(256) void gather_max(const int* __restrict__ idxg,
                                                  const bf16* __restrict__ P2,
                                                  bf16* __restrict__ HF)
{
    const int id = blockIdx.x * 256 + threadIdx.x;
    const int j = id >> 7, o = id & 127;
    const int* ip = idxg + j * 9;
    float v = -__builtin_inff();
#pragma unroll
    for (int k = 0; k < 9; ++k) {
        int m = ip[k];
        m = ((unsigned)m < (unsigned)MTOT) ? m : 0;   // fault-proof
        v = fmaxf(v, b2f(P2[(size_t)m * 128 + o]));
    }
    HF[(size_t)j * 256 + o] = f2b(v);
}

// --------------------------------------------------------------- head ------
__global__ __launch_bounds__(256) void head_k(
    const bf16* __restrict__ X2, const bf16* __restrict__ R2v, const bf16* __restrict__ C2v,
    const float* __restrict__ rw2, const float* __restrict__ rbn2,
    const float* __restrict__ cw2, const float* __restrict__ cbn2,
    const float* __restrict__ wfc, const float* __restrict__ bfc,
    const float* __restrict__ flow, float* __restrict__ out)
{
    const int j = blockIdx.x * 256 + threadIdx.x;
    const int b = j >> 13, n = j & (NPTS - 1);
    const bf16x8* xr = (const bf16x8*)(X2 + (size_t)j * 64);
    const bf16x8* rr = (const bf16x8*)(R2v + (size_t)j * 64);
    const bf16x8* cr = (const bf16x8*)(C2v + (size_t)j * 64);
    float dr = 0.f, dc = 0.f, p0 = 0.f, p1 = 0.f, p2 = 0.f;
#pragma unroll
    for (int bk = 0; bk < 8; ++bk) {
        bf16x8 xv = xr[bk], rv = rr[bk], cv = cr[bk];
#pragma unroll
        for (int i = 0; i < 8; ++i) {
            const int c = bk * 8 + i;
            float x = (float)xv[i];
            dr += rw2[c] * (float)rv[i];
            dc += cw2[c] * (float)cv[i];
            p0 += wfc[c] * x;
            p1 += wfc[64 + c] * x;
            p2 += wfc[128 + c] * x;
        }
    }
    float refine = (dr - rbn2[2]) / sqrtf(rbn2[3] + 1e-5f) * rbn2[0] + rbn2[1];
    refine = fmaxf(refine, 0.f);
    float coarse = (dc - cbn2[2]) / sqrtf(cbn2[3] + 1e-5f) * cbn2[0] + cbn2[1];
    coarse = fmaxf(coarse, 0.f);
    p0 += bfc[0]; p1 += bfc[1]; p2 += bfc[2];
    const float f0 = flow[(size_t)b * 3 * NPTS + n];
    const float f1 = flow[(size_t)b * 3 * NPTS + NPTS + n];
    const float f2v = flow[(size_t)b * 3 * NPTS + 2 * NPTS + n];
    float o0 = fminf(fmaxf(coarse * f0 + refine * p0, -20.f), 20.f);
    float o1 = fminf(fmaxf(coarse * f1 + refine * p1, -20.f), 20.f);
    float o2 = fminf(fmaxf(coarse * f2v + refine * p2, -20.f), 20.f);
    float* ro = out + 1048576; // x section = 2*64*8192 f32 elements
    ro[(size_t)b * 3 * NPTS + n] = o0;
    ro[(size_t)b * 3 * NPTS + NPTS + n] = o1;
    ro[(size_t)b * 3 * NPTS + 2 * NPTS + n] = o2;
}

// -------------------------------------------------------------- launch -----
// Workspace (27,590,656 B), lifetime-aliased; steps = launch order.
//   region XA  @0          6,291,456  XA [14->15]
//     A0 @0 3,145,728 [4->7] | idxg @3,145,728 589,824 [2->9]
//     P4 @3,735,552 262,144 [1->2] | W0p @3,735,552 24,576 [3->7]  (sequential)
//   region HF  @6,291,456  8,388,608  HF [6->14]
//     X1 @6,291,456 [15->16] | X2 @10,485,760 [16->22] | R1 @12,582,912 [17->18]
//   region QIN @14,680,064 8,388,608  QIN [11->14]
//     P1 @14,680,064 [7->8] | P2 @18,874,368 [8->9]
//     C1 @14,680,064 [20->21] | C2 @16,777,216 [21->22]
//   region Z   @23,068,672 4,194,304  Z [12->14]
//     R2 @23,068,672 [18->22] | CV @25,165,824 [19->20]
//   region WTS @27,262,976 327,680  staged bf16 weights [3c->21]
extern "C" void kernel_launch(void* const* d_in, const int* in_sizes, int n_in,
                              void* d_out, int out_size, void* d_ws, size_t ws_size,
                              hipStream_t stream)
{
    static const int EXP[35] = {
        49152, 1048576, 1048576, 2097152, 49152,
        8576, 128, 512, 16384, 128, 512,
        32768, 128, 32768, 128, 32768, 128,
        24576, 128, 8192, 64, 192, 3,
        4096, 256, 4096, 256, 64, 4,
        4096, 256, 4096, 256, 64, 4 };
    float code = 0.f;
    if (n_in != 35) code = 900.f;
    else if (out_size != 1097728) code = 950.f;
    else if (ws_size < 27590656u) code = 980.f;
    else { for (int i = 0; i < 35; ++i) if (in_sizes[i] != EXP[i]) { code = 1000.f + 4.f * i; break; } }
    if (code != 0.f) { diag_k<<<dim3(1), dim3(64), 0, stream>>>((float*)d_out, code); return; }

    const float* xyz    = (const float*)d_in[0];
    const float* points = (const float*)d_in[1];
    const float* cost   = (const float*)d_in[2];
    const float* feats  = (const float*)d_in[3];
    const float* flow   = (const float*)d_in[4];
    const float* w0     = (const float*)d_in[5];
    const float* b0     = (const float*)d_in[6];
    const float* bn0    = (const float*)d_in[7];
    const float* w1     = (const float*)d_in[8];
    const float* b1     = (const float*)d_in[9];
    const float* bn1    = (const float*)d_in[10];
    const float* wz     = (const float*)d_in[11];
    const float* bz     = (const float*)d_in[12];
    const float* wr     = (const float*)d_in[13];
    const float* br     = (const float*)d_in[14];
    const float* wq     = (const float*)d_in[15];
    const float* bq     = (const float*)d_in[16];
    const float* w2a    = (const float*)d_in[17];
    const float* b2a    = (const float*)d_in[18];
    const float* w2b    = (const float*)d_in[19];
    const float* b2b    = (const float*)d_in[20];
    const float* wfc    = (const float*)d_in[21];
    const float* bfc    = (const float*)d_in[22];
    const float* rw0    = (const float*)d_in[23];
    const float* rbn0   = (const float*)d_in[24];
    const float* rw1    = (const float*)d_in[25];
    const float* rbn1   = (const float*)d_in[26];
    const float* rw2    = (const float*)d_in[27];
    const float* rbn2   = (const float*)d_in[28];
    const float* cw0    = (const float*)d_in[29];
    const float* cbn0   = (const float*)d_in[30];
    const float* cw1    = (const float*)d_in[31];
    const float* cbn1   = (const float*)d_in[32];
    const float* cw2    = (const float*)d_in[33];
    const float* cbn2   = (const float*)d_in[34];

    char* ws = (char*)d_ws;
    bf16*   XA   = (bf16*)  (ws + 0);
    bf16*   A0   = (bf16*)  (ws + 0);
    int*    idxg = (int*)   (ws + 3145728);
    float4* P4   = (float4*)(ws + 3735552);
    bf16*   W0p  = (bf16*)  (ws + 3735552);
    bf16*   HF   = (bf16*)  (ws + 6291456);
    bf16*   X1   = (bf16*)  (ws + 6291456);
    bf16*   X2   = (bf16*)  (ws + 10485760);
    bf16*   R1   = (bf16*)  (ws + 12582912);
    bf16*   QIN  = (bf16*)  (ws + 14680064);
    bf16*   P1   = (bf16*)  (ws + 14680064);
    bf16*   P2   = (bf16*)  (ws + 18874368);
    bf16*   C1   = (bf16*)  (ws + 14680064);
    bf16*   C2   = (bf16*)  (ws + 16777216);
    bf16*   Z    = (bf16*)  (ws + 23068672);
    bf16*   R2   = (bf16*)  (ws + 23068672);
    bf16*   CV   = (bf16*)  (ws + 25165824);
    bf16*   WTS  = (bf16*)  (ws + 27262976);  // staged bf16 weights

    bf16* W1  = WTS;
    bf16* WZ  = WTS + 16384;
    bf16* WR  = WTS + 49152;
    bf16* WQ  = WTS + 81920;
    bf16* W2A = WTS + 114688;
    bf16* W2B = WTS + 139264;
    bf16* RW0 = WTS + 147456;
    bf16* RW1 = WTS + 151552;
    bf16* CW0 = WTS + 155648;
    bf16* CW1 = WTS + 159744;

    float* out = (float*)d_out;
    dim3 blk(256);

    /*1*/  knn_prep<<<dim3(64), blk, 0, stream>>>(xyz, P4);
    /*2*/  knn_wave<<<dim3(4096), blk, 0, stream>>>(P4, idxg);
    /*3*/  w0_pad<<<dim3(48), blk, 0, stream>>>(w0, W0p);
    /*3c*/ cvt_weights<<<dim3(640), blk, 0, stream>>>(w1, wz, wr, wq, w2a, w2b, rw0, rw1, cw0, cw1, WTS);
    /*4*/  pack_t<<<dim3(128, 2, 2), blk, 0, stream>>>(cost,   64, A0,  96,   0);
    /*5*/  pack_t<<<dim3(128, 1, 2), blk, 0, stream>>>(flow,    3, A0,  96,  64);
    /*6*/  pack_t<<<dim3(128, 4, 2), blk, 0, stream>>>(feats, 128, HF,  256, 128);
    /*7*/  gemm_k<1><<<dim3(128, 2), blk, 0, stream>>>(A0,  96, W0p, 96,  96, 128, b0, bn0, nullptr, nullptr, P1, 128, 0, nullptr);
    /*8*/  gemm_k<1><<<dim3(128, 2), blk, 0, stream>>>(P1, 128, W1, 128, 128, 128, b1, bn1, nullptr, nullptr, P2, 128, 0, nullptr);
    /*9*/  gather_max<<<dim3(8192), blk, 0, stream>>>(idxg, P2, HF);
    /*10*/ pack_t<<<dim3(128, 2, 2), blk, 0, stream>>>(points, 64, XA,  192,   0);
    /*11*/ pack_t<<<dim3(128, 4, 2), blk, 0, stream>>>(feats, 128, QIN, 256, 128);
    /*12*/ gemm_k<2><<<dim3(128, 2), blk, 0, stream>>>(HF, 256, WZ, 256, 256, 128, bz, nullptr, nullptr, nullptr, Z,   128, 0, nullptr);
    /*13*/ gemm_k<3><<<dim3(128, 2), blk, 0, stream>>>(HF, 256, WR, 256, 256, 128, br, nullptr, HF,      nullptr, QIN, 256, 0, nullptr);
    /*14*/ gemm_k<4><<<dim3(128, 2), blk, 0, stream>>>(QIN,256, WQ, 256, 256, 128, bq, nullptr, HF,      Z,       XA,  192, 64, nullptr);
    /*15*/ gemm_k<0><<<dim3(128, 2), blk, 0, stream>>>(XA, 192, W2A,192, 192, 128, b2a, nullptr, nullptr, nullptr, X1, 128, 0, nullptr);
    /*16*/ gemm_k<6><<<dim3(128, 1), blk, 0, stream>>>(X1, 128, W2B,128, 128,  64, b2b, nullptr, nullptr, nullptr, X2,  64, 0, out);
    /*17*/ gemm_k<5><<<dim3(128, 1), blk, 0, stream>>>(X2,  64, RW0, 64,  64,  64, nullptr, rbn0, nullptr, nullptr, R1, 64, 0, nullptr);
    /*18*/ gemm_k<5><<<dim3(128, 1), blk, 0, stream>>>(R1,  64, RW1, 64,  64,  64, nullptr, rbn1, nullptr, nullptr, R2, 64, 0, nullptr);
    /*19*/ pack_t<<<dim3(128, 2, 2), blk, 0, stream>>>(cost,   64, CV,  64,   0);
    /*20*/ gemm_k<5><<<dim3(128, 1), blk, 0, stream>>>(CV,  64, CW0, 64,  64,  64, nullptr, cbn0, nullptr, nullptr, C1, 64, 0, nullptr);
    /*21*/ gemm_k<5><<<dim3(128, 1), blk, 0, stream>>>(C1,  64, CW1, 64,  64,  64, nullptr, cbn1, nullptr, nullptr, C2, 64, 0, nullptr);
    /*22*/ head_k<<<dim3(64), blk, 0, stream>>>(X2, R2, C2, rw2, rbn2, cw2, cbn2, wfc, bfc, flow, out);

    (void)n_in;
}

// Round 7
// 418.585 us; speedup vs baseline: 2.1661x; 1.2193x over previous
//
#include <hip/hip_runtime.h>
#include <math.h>

typedef __bf16 bf16;
typedef __bf16 bf16x8 __attribute__((ext_vector_type(8)));
typedef float f32x4 __attribute__((ext_vector_type(4)));

#define NPTS 8192
#define MTOT 16384

static __device__ __forceinline__ float b2f(bf16 x) { return (float)x; }
static __device__ __forceinline__ bf16  f2b(float x) { return (bf16)x; }

// ------------------------------------------------------------ diagnostics --
__global__ void diag_k(float* out, float code)
{
    if (threadIdx.x == 0 && blockIdx.x == 0) out[0] = code;
}

// ------------------------------------------------------------- prep_all ----
// fuses: knn_prep (P4 table) + w0_pad + cvt_weights. Branch is block-uniform.
__global__ __launch_bounds__(256) void prep_all(
    const float* __restrict__ xyz, const float* __restrict__ w0,
    const float* __restrict__ w1, const float* __restrict__ wz,
    const float* __restrict__ wr, const float* __restrict__ wq,
    const float* __restrict__ w2a, const float* __restrict__ w2b,
    const float* __restrict__ rw0, const float* __restrict__ rw1,
    const float* __restrict__ cw0, const float* __restrict__ cw1,
    float4* __restrict__ P4, bf16* __restrict__ w0p, bf16* __restrict__ wts)
{
    const int bx = blockIdx.x;
    if (bx < 64) {                      // P4[j] = (x,y,z,|p|^2)
        int id = bx * 256 + threadIdx.x;
        int b = id >> 13, n = id & (NPTS - 1);
        const float* X = xyz + b * 3 * NPTS;
        float x = X[n], y = X[NPTS + n], z = X[2 * NPTS + n];
        P4[id] = make_float4(x, y, z, x * x + y * y + z * z);
    } else if (bx < 112) {              // w0 [128][67] -> bf16 [128][96]
        int id = (bx - 64) * 256 + threadIdx.x;
        if (id < 128 * 96) {
            int o = id / 96, c = id - o * 96;
            w0p[id] = (c < 67) ? f2b(w0[o * 67 + c]) : (bf16)0.0f;
        }
    } else {                            // stage dense weights f32 -> bf16
        int id = (bx - 112) * 256 + threadIdx.x;
        if (id < 163840) {
            const float* s; int off;
            if (id < 16384)       { s = w1;  off = 0; }
            else if (id < 49152)  { s = wz;  off = 16384; }
            else if (id < 81920)  { s = wr;  off = 49152; }
            else if (id < 114688) { s = wq;  off = 81920; }
            else if (id < 139264) { s = w2a; off = 114688; }
            else if (id < 147456) { s = w2b; off = 139264; }
            else if (id < 151552) { s = rw0; off = 147456; }
            else if (id < 155648) { s = rw1; off = 151552; }
            else if (id < 159744) { s = cw0; off = 155648; }
            else                  { s = cw1; off = 159744; }
            wts[id] = f2b(s[id - off]);
        }
    }
}

// ---------------------------------------------------------------- KNN ------
// v3: one wave per (query, candidate-half). u64 lex key = (mono32(d)<<32)|idx
// so lex (d, idx) = single u64 compare (top_k first-occurrence semantics; d is
// never -0.0 since a-a rounds to +0). Init: 9-round butterfly min-reduce over
// the first 64 candidates (exact top-9-of-64, wave-uniform, branch-free).
// Main loop: ballot(key < kk[8]) gates extraction; extraction via v_readlane
// (uniform lane index) - no LDS-pipe shfl in the serial chain. Halves merged
// through LDS. Distance expression textually identical to rounds 4-6.
__global__ __launch_bounds__(512) void knn_wave2(const float4* __restrict__ P4,
                                                 int* __restrict__ idxg)
{
    __shared__ float4 pts[2][1024];                  // 32 KB
    __shared__ unsigned long long mg[4][9];
    const int t = threadIdx.x, lane = t & 63, w = t >> 6;
    const int qw = w & 3, h = w >> 2;
    const int qid = blockIdx.x * 4 + qw, b = qid >> 13;
    const float4 q = P4[qid];
    const float4* C0 = P4 + (size_t)b * NPTS;
    const float4* pbase = &pts[h][0];

    unsigned long long kk[9];
#pragma unroll
    for (int k = 0; k < 9; ++k) kk[k] = ~0ull;

    for (int ch = 0; ch < 4; ++ch) {
        __syncthreads();
#pragma unroll
        for (int r2 = 0; r2 < 4; ++r2) {
            int idx2 = t + r2 * 512;
            pts[idx2 >> 10][idx2 & 1023] =
                C0[(idx2 >> 10) * 4096 + ch * 1024 + (idx2 & 1023)];
        }
        __syncthreads();
        int i0 = 0;
        if (ch == 0) {
            // init from this wave's first 64 candidates
            float4 c = pbase[lane];
            float d = (q.w + c.w) - 2.0f * (q.x * c.x + q.y * c.y + q.z * c.z);
            unsigned kd = __float_as_uint(d);
            kd ^= ((unsigned)((int)kd >> 31)) | 0x80000000u;
            unsigned long long key = ((unsigned long long)kd << 32)
                                   | (unsigned)(h * 4096 + lane);
#pragma unroll
            for (int r = 0; r < 9; ++r) {
                unsigned long long m = key;
#pragma unroll
                for (int s = 1; s < 64; s <<= 1) {
                    unsigned long long o = __shfl_xor(m, s);
                    if (o < m) m = o;
                }
                kk[r] = m;                       // wave-uniform
                if (key == m) key = ~0ull;       // knockout (keys unique)
            }
            i0 = 1;
        }
        for (int i = i0; i < 16; ++i) {
            float4 c = pbase[i * 64 + lane];
            float d = (q.w + c.w) - 2.0f * (q.x * c.x + q.y * c.y + q.z * c.z);
            unsigned kd = __float_as_uint(d);
            kd ^= ((unsigned)((int)kd >> 31)) | 0x80000000u;
            unsigned long long key = ((unsigned long long)kd << 32)
                                   | (unsigned)(h * 4096 + ch * 1024 + i * 64 + lane);
            unsigned long long mask = __ballot(key < kk[8]);
            while (mask) {                       // wave-uniform extraction
                int L = __builtin_ctzll(mask);
                mask &= mask - 1;
                unsigned lo = (unsigned)__builtin_amdgcn_readlane((int)key, L);
                unsigned hi = (unsigned)__builtin_amdgcn_readlane((int)(key >> 32), L);
                unsigned long long K = ((unsigned long long)hi << 32) | lo;
                if (K < kk[8]) {
                    bool lt[9];
#pragma unroll
                    for (int j2 = 0; j2 < 9; ++j2) lt[j2] = K < kk[j2];
#pragma unroll
                    for (int j2 = 8; j2 > 0; --j2)
                        kk[j2] = lt[j2] ? (lt[j2 - 1] ? kk[j2 - 1] : K) : kk[j2];
                    kk[0] = lt[0] ? K : kk[0];
                }
            }
        }
    }
    // merge the two candidate-halves of each query
    if (h == 1 && lane == 0) {
#pragma unroll
        for (int k = 0; k < 9; ++k) mg[qw][k] = kk[k];
    }
    __syncthreads();
    if (h == 0) {
#pragma unroll
        for (int k = 0; k < 9; ++k) {
            unsigned long long K = mg[qw][k];
            if (K < kk[8]) {
                bool lt[9];
#pragma unroll
                for (int j2 = 0; j2 < 9; ++j2) lt[j2] = K < kk[j2];
#pragma unroll
                for (int j2 = 8; j2 > 0; --j2)
                    kk[j2] = lt[j2] ? (lt[j2 - 1] ? kk[j2 - 1] : K) : kk[j2];
                kk[0] = lt[0] ? K : kk[0];
            }
        }
        if (lane == 0) {
#pragma unroll
            for (int k = 0; k < 9; ++k) {
                int m = (int)(unsigned)(kk[k] & 0xffffffffu);
                m = ((unsigned)m < (unsigned)NPTS) ? m : 0;   // fault-proof
                idxg[qid * 9 + k] = b * NPTS + m;
            }
        }
    }
}

// --------------------------------------------------------------- pack ------
// f32 [B][C][N] channel-major -> bf16 point-major [M][ldd] tile (zero-pad).
__device__ __forceinline__ void pack_body(bf16 (*tile)[68],
                                          const float* __restrict__ src, int Csrc,
                                          bf16* __restrict__ dst, int ldd, int colOfs,
                                          int nb, int cb, int b)
{
    const int t = threadIdx.x;
#pragma unroll
    for (int i = 0; i < 8; ++i) {
        int id = t + i * 256;
        int c = id >> 6, n = id & 63;
        int cc = cb + c;
        bf16 v = (bf16)0.0f;
        if (cc < Csrc) v = f2b(src[(size_t)(b * Csrc + cc) * NPTS + nb + n]);
        tile[c][n] = v;
    }
    __syncthreads();
#pragma unroll
    for (int i = 0; i < 8; ++i) {
        int id = t + i * 256;
        int n = id >> 5, c = id & 31;
        dst[(size_t)(b * NPTS + nb + n) * ldd + colOfs + cb + c] = tile[c][n];
    }
}

// early: cost->A0 (y<2), flow->A0 cols64+ (y==2), feats->HF cols128+ (y>=3)
__global__ __launch_bounds__(256) void pack_early(const float* __restrict__ cost,
                                                  const float* __restrict__ flow,
                                                  const float* __restrict__ feats,
                                                  bf16* __restrict__ A0,
                                                  bf16* __restrict__ HF)
{
    __shared__ bf16 tile[32][68];
    const int nb = blockIdx.x * 64, b = blockIdx.z, y = blockIdx.y;
    if (y < 2)      pack_body(tile, cost,  64, A0, 96,   0, nb, y * 32, b);
    else if (y == 2) pack_body(tile, flow,   3, A0, 96,  64, nb, 0,      b);
    else            pack_body(tile, feats, 128, HF, 256, 128, nb, (y - 3) * 32, b);
}

// mid: points->XA (y<2), feats->QIN cols128+ (y>=2)   [after gather: A0/idxg dead]
__global__ __launch_bounds__(256) void pack_mid(const float* __restrict__ points,
                                                const float* __restrict__ feats,
                                                bf16* __restrict__ XA,
                                                bf16* __restrict__ QIN)
{
    __shared__ bf16 tile[32][68];
    const int nb = blockIdx.x * 64, b = blockIdx.z, y = blockIdx.y;
    if (y < 2) pack_body(tile, points, 64, XA, 192, 0, nb, y * 32, b);
    else       pack_body(tile, feats, 128, QIN, 256, 128, nb, (y - 2) * 32, b);
}

// cv: cost -> CV (ld 64)   [after gemmQ: QIN region dead]
__global__ __launch_bounds__(256) void pack_cv(const float* __restrict__ cost,
                                               bf16* __restrict__ CV)
{
    __shared__ bf16 tile[32][68];
    pack_body(tile, cost, 64, CV, 64, 0, blockIdx.x * 64, blockIdx.y * 32, blockIdx.z);
}

// --------------------------------------------------------------- GEMM ------
// out[j][o] = epi( sum_c A[j][c] * W[o][c] ). MFMA 16x16x32 bf16 NT (m89 C/D
// mapping). Wave tile 64pt x 32o; block = 2x2 waves = 128pt x 64o.
template <int EPI>
__global__ __launch_bounds__(256) void gemm_k(
    const bf16* __restrict__ A, int lda,
    const bf16* __restrict__ W, int ldw, int K, int Otot,
    const float* __restrict__ bias, const float* __restrict__ bnp,
    const bf16* __restrict__ aux1, const bf16* __restrict__ aux2,
    bf16* __restrict__ dst, int ldo, int dofs,
    float* __restrict__ out2)
{
    const int w = threadIdx.x >> 6, lane = threadIdx.x & 63;
    const int q = lane >> 4, r = lane & 15;
    const int ptb = blockIdx.x * 128 + (w & 1) * 64;
    const int ob  = blockIdx.y * 64 + (w >> 1) * 32;
    const bf16* Ap = A + (size_t)(ptb + r) * lda + q * 8;
    const bf16* Wp = W + (size_t)(ob + r) * ldw + q * 8;
    f32x4 zero = {0.f, 0.f, 0.f, 0.f};
    f32x4 acc[4][2];
#pragma unroll
    for (int i = 0; i < 4; ++i) { acc[i][0] = zero; acc[i][1] = zero; }
    for (int k = 0; k < K; k += 32) {
        bf16x8 bv0 = *(const bf16x8*)(Wp + k);
        bf16x8 bv1 = *(const bf16x8*)(Wp + 16 * ldw + k);
        bf16x8 a0 = *(const bf16x8*)(Ap + k);
        bf16x8 a1 = *(const bf16x8*)(Ap + 16 * lda + k);
        bf16x8 a2 = *(const bf16x8*)(Ap + 32 * lda + k);
        bf16x8 a3 = *(const bf16x8*)(Ap + 48 * lda + k);
        acc[0][0] = __builtin_amdgcn_mfma_f32_16x16x32_bf16(a0, bv0, acc[0][0], 0, 0, 0);
        acc[1][0] = __builtin_amdgcn_mfma_f32_16x16x32_bf16(a1, bv0, acc[1][0], 0, 0, 0);
        acc[2][0] = __builtin_amdgcn_mfma_f32_16x16x32_bf16(a2, bv0, acc[2][0], 0, 0, 0);
        acc[3][0] = __builtin_amdgcn_mfma_f32_16x16x32_bf16(a3, bv0, acc[3][0], 0, 0, 0);
        acc[0][1] = __builtin_amdgcn_mfma_f32_16x16x32_bf16(a0, bv1, acc[0][1], 0, 0, 0);
        acc[1][1] = __builtin_amdgcn_mfma_f32_16x16x32_bf16(a1, bv1, acc[1][1], 0, 0, 0);
        acc[2][1] = __builtin_amdgcn_mfma_f32_16x16x32_bf16(a2, bv1, acc[2][1], 0, 0, 0);
        acc[3][1] = __builtin_amdgcn_mfma_f32_16x16x32_bf16(a3, bv1, acc[3][1], 0, 0, 0);
    }
#pragma unroll
    for (int to = 0; to < 2; ++to) {
        const int o = ob + to * 16 + r;
        float bs = 0.f, gg = 0.f, be = 0.f, mm = 0.f, rs = 0.f;
        if (EPI != 5) bs = bias[o];
        if (EPI == 1 || EPI == 5) {
            gg = bnp[o]; be = bnp[Otot + o]; mm = bnp[2 * Otot + o];
            float vv = bnp[3 * Otot + o];
            rs = 1.0f / sqrtf(vv + 1e-5f);
        }
#pragma unroll
        for (int tm = 0; tm < 4; ++tm) {
#pragma unroll
            for (int rr = 0; rr < 4; ++rr) {
                const int j = ptb + tm * 16 + q * 4 + rr;
                float v = acc[tm][to][rr];
                if (EPI == 0) { v += bs; v = v > 0.f ? v : 0.1f * v; }
                else if (EPI == 1) { v += bs; v = (v - mm) * rs * gg + be; v = v > 0.f ? v : 0.1f * v; }
                else if (EPI == 2) { v += bs; v = 1.0f / (1.0f + expf(-v)); }
                else if (EPI == 3) { v += bs; v = 1.0f / (1.0f + expf(-v));
                                     v *= b2f(aux1[(size_t)j * 256 + o]); }
                else if (EPI == 4) {
                    v += bs; float qv = tanhf(v);
                    float z = b2f(aux2[(size_t)j * 128 + o]);
                    float h = b2f(aux1[(size_t)j * 256 + o]);
                    v = (1.0f - z) * h + z * qv;
                }
                else if (EPI == 5) { v = (v - mm) * rs * gg + be; v = fmaxf(v, 0.f); }
                else if (EPI == 6) { v += bs; v = v > 0.f ? v : 0.1f * v; }
                dst[(size_t)j * ldo + dofs + o] = f2b(v);
                if (EPI == 6) {
                    int bb = j >> 13, n = j & (NPTS - 1);
                    out2[(size_t)bb * 64 * NPTS + (size_t)o * NPTS + n] = v;
                }
            }
        }
    }
}

// dual EPI5 reg-net layer: blockIdx.y selects (refine | coarse) path.
// lda = ldw = ldo = K = Otot = 64; grid (128, 2).
__global__ __launch_bounds__(256) void gemm5_dual(
    const bf16* __restrict__ A1s, const bf16* __restrict__ W1s,
    const float* __restrict__ bnp1, bf16* __restrict__ d1,
    const bf16* __restrict__ A2s, const bf16* __restrict__ W2s,
    const float* __restrict__ bnp2, bf16* __restrict__ d2)
{
    const bf16* A = blockIdx.y ? A2s : A1s;
    const bf16* W = blockIdx.y ? W2s : W1s;
    const float* bnp = blockIdx.y ? bnp2 : bnp1;
    bf16* dst = blockIdx.y ? d2 : d1;
    const int w = threadIdx.x >> 6, lane = threadIdx.x & 63;
    const int q = lane >> 4, r = lane & 15;
    const int ptb = blockIdx.x * 128 + (w & 1) * 64;
    const int ob  = (w >> 1) * 32;
    const bf16* Ap = A + (size_t)(ptb + r) * 64 + q * 8;
    const bf16* Wp = W + (size_t)(ob + r) * 64 + q * 8;
    f32x4 zero = {0.f, 0.f, 0.f, 0.f};
    f32x4 acc[4][2];
#pragma unroll
    for (int i = 0; i < 4; ++i) { acc[i][0] = zero; acc[i][1] = zero; }
#pragma unroll
    for (int k = 0; k < 64; k += 32) {
        bf16x8 bv0 = *(const bf16x8*)(Wp + k);
        bf16x8 bv1 = *(const bf16x8*)(Wp + 16 * 64 + k);
        bf16x8 a0 = *(const bf16x8*)(Ap + k);
        bf16x8 a1 = *(const bf16x8*)(Ap + 16 * 64 + k);
        bf16x8 a2 = *(const bf16x8*)(Ap + 32 * 64 + k);
        bf16x8 a3 = *(const bf16x8*)(Ap + 48 * 64 + k);
        acc[0][0] = __builtin_amdgcn_mfma_f32_16x16x32_bf16(a0, bv0, acc[0][0], 0, 0, 0);
        acc[1][0] = __builtin_amdgcn_mfma_f32_16x16x32_bf16(a1, bv0, acc[1][0], 0, 0, 0);
        acc[2][0] = __builtin_amdgcn_mfma_f32_16x16x32_bf16(a2, bv0, acc[2][0], 0, 0, 0);
        acc[3][0] = __builtin_amdgcn_mfma_f32_16x16x32_bf16(a3, bv0, acc[3][0], 0, 0, 0);
        acc[0][1] = __builtin_amdgcn_mfma_f32_16x16x32_bf16(a0, bv1, acc[0][1], 0, 0, 0);
        acc[1][1] = __builtin_amdgcn_mfma_f32_16x16x32_bf16(a1, bv1, acc[1][1], 0, 0, 0);
        acc[2][1] = __builtin_amdgcn_mfma_f32_16x16x32_bf16(a2, bv1, acc[2][1], 0, 0, 0);
        acc[3][1] = __builtin_amdgcn_mfma_f32_16x16x32_bf16(a3, bv1, acc[3][1], 0, 0, 0);
    }
#pragma unroll
    for (int to = 0; to < 2; ++to) {
        const int o = ob + to * 16 + r;
        float gg = bnp[o], be = bnp[64 + o], mm = bnp[128 + o];
        float rs = 1.0f / sqrtf(bnp[192 + o] + 1e-5f);
#pragma unroll
        for (int tm = 0; tm < 4; ++tm) {
#pragma unroll
            for (int rr = 0; rr < 4; ++rr) {
                const int j = ptb + tm * 16 + q * 4 + rr;
                float v = acc[tm][to][rr];
                v = (v - mm) * rs * gg + be; v = fmaxf(v, 0.f);
                dst[(size_t)j * 64 + o] = f2b(v);
            }
        }
    }
}

// ---------------------------------------------------------- gather-max -----
__global__ __launch_bounds__(256) void gather_max(const int* __restrict__ idxg,
                                                  const bf16* __restrict__ P2,
                                                  bf16* __restrict__ HF)
{
    const int id = blockIdx.x * 256 + threadIdx.x;
    const int j = id >> 7, o = id & 127;
    const int* ip = idxg + j * 9;
    float v = -__builtin_inff();
#pragma unroll
    for (int k = 0; k < 9; ++k) {
        int m = ip[k];
        m = ((unsigned)m < (unsigned)MTOT) ? m : 0;   // fault-proof
        v = fmaxf(v, b2f(P2[(size_t)m * 128 + o]));
    }
    HF[(size_t)j * 256 + o] = f2b(v);
}

// --------------------------------------------------------------- head ------
__global__ __launch_bounds__(256) void head_k(
    const bf16* __restrict__ X2, const bf16* __restrict__ R2v, const bf16* __restrict__ C2v,
    const float* __restrict__ rw2, const float* __restrict__ rbn2,
    const float* __restrict__ cw2, const float* __restrict__ cbn2,
    const float* __restrict__ wfc, const float* __restrict__ bfc,
    const float* __restrict__ flow, float* __restrict__ out)
{
    const int j = blockIdx.x * 256 + threadIdx.x;
    const int b = j >> 13, n = j & (NPTS - 1);
    const bf16x8* xr = (const bf16x8*)(X2 + (size_t)j * 64);
    const bf16x8* rr = (const bf16x8*)(R2v + (size_t)j * 64);
    const bf16x8* cr = (const bf16x8*)(C2v + (size_t)j * 64);
    float dr = 0.f, dc = 0.f, p0 = 0.f, p1 = 0.f, p2 = 0.f;
#pragma unroll
    for (int bk = 0; bk < 8; ++bk) {
        bf16x8 xv = xr[bk], rv = rr[bk], cv = cr[bk];
#pragma unroll
        for (int i = 0; i < 8; ++i) {
            const int c = bk * 8 + i;
            float x = (float)xv[i];
            dr += rw2[c] * (float)rv[i];
            dc += cw2[c] * (float)cv[i];
            p0 += wfc[c] * x;
            p1 += wfc[64 + c] * x;
            p2 += wfc[128 + c] * x;
        }
    }
    float refine = (dr - rbn2[2]) / sqrtf(rbn2[3] + 1e-5f) * rbn2[0] + rbn2[1];
    refine = fmaxf(refine, 0.f);
    float coarse = (dc - cbn2[2]) / sqrtf(cbn2[3] + 1e-5f) * cbn2[0] + cbn2[1];
    coarse = fmaxf(coarse, 0.f);
    p0 += bfc[0]; p1 += bfc[1]; p2 += bfc[2];
    const float f0 = flow[(size_t)b * 3 * NPTS + n];
    const float f1 = flow[(size_t)b * 3 * NPTS + NPTS + n];
    const float f2v = flow[(size_t)b * 3 * NPTS + 2 * NPTS + n];
    float o0 = fminf(fmaxf(coarse * f0 + refine * p0, -20.f), 20.f);
    float o1 = fminf(fmaxf(coarse * f1 + refine * p1, -20.f), 20.f);
    float o2 = fminf(fmaxf(coarse * f2v + refine * p2, -20.f), 20.f);
    float* ro = out + 1048576; // x section = 2*64*8192 f32 elements
    ro[(size_t)b * 3 * NPTS + n] = o0;
    ro[(size_t)b * 3 * NPTS + NPTS + n] = o1;
    ro[(size_t)b * 3 * NPTS + 2 * NPTS + n] = o2;
}

// -------------------------------------------------------------- launch -----
// Workspace (27,590,656 B), lifetime-aliased; steps = launch order (1..16).
//   region XA @0 6,291,456            XA [7->10,11]
//     A0 @0 3,145,728 [3->4] | idxg @3,145,728 [2->6]
//     W0p @3,735,552 24,576 [1->4] | P4 @3,760,128 262,144 [1->2]
//   region HF @6,291,456 8,388,608    HF [3->10]
//     X1 @6,291,456 [11->13] | X2 @10,485,760 [13->16] | R1 @12,582,912 [14->15]
//   region QIN @14,680,064 8,388,608  QIN [7->10]
//     P1 @14,680,064 [4->5] | P2 @18,874,368 [5->6]
//     C1 @14,680,064 [14->15] | C2 @16,777,216 [15->16] | CV @18,874,368 [12->14]
//   region Z @23,068,672 4,194,304    Z [8->10]
//     R2 @23,068,672 [15->16]
//   WTS @27,262,976 327,680 [1->15]
extern "C" void kernel_launch(void* const* d_in, const int* in_sizes, int n_in,
                              void* d_out, int out_size, void* d_ws, size_t ws_size,
                              hipStream_t stream)
{
    static const int EXP[35] = {
        49152, 1048576, 1048576, 2097152, 49152,
        8576, 128, 512, 16384, 128, 512,
        32768, 128, 32768, 128, 32768, 128,
        24576, 128, 8192, 64, 192, 3,
        4096, 256, 4096, 256, 64, 4,
        4096, 256, 4096, 256, 64, 4 };
    float code = 0.f;
    if (n_in != 35) code = 900.f;
    else if (out_size != 1097728) code = 950.f;
    else if (ws_size < 27590656u) code = 980.f;
    else { for (int i = 0; i < 35; ++i) if (in_sizes[i] != EXP[i]) { code = 1000.f + 4.f * i; break; } }
    if (code != 0.f) { diag_k<<<dim3(1), dim3(64), 0, stream>>>((float*)d_out, code); return; }

    const float* xyz    = (const float*)d_in[0];
    const float* points = (const float*)d_in[1];
    const float* cost   = (const float*)d_in[2];
    const float* feats  = (const float*)d_in[3];
    const float* flow   = (const float*)d_in[4];
    const float* w0     = (const float*)d_in[5];
    const float* b0     = (const float*)d_in[6];
    const float* bn0    = (const float*)d_in[7];
    const float* w1     = (const float*)d_in[8];
    const float* b1     = (const float*)d_in[9];
    const float* bn1    = (const float*)d_in[10];
    const float* wz     = (const float*)d_in[11];
    const float* bz     = (const float*)d_in[12];
    const float* wr     = (const float*)d_in[13];
    const float* br     = (const float*)d_in[14];
    const float* wq     = (const float*)d_in[15];
    const float* bq     = (const float*)d_in[16];
    const float* w2a    = (const float*)d_in[17];
    const float* b2a    = (const float*)d_in[18];
    const float* w2b    = (const float*)d_in[19];
    const float* b2b    = (const float*)d_in[20];
    const float* wfc    = (const float*)d_in[21];
    const float* bfc    = (const float*)d_in[22];
    const float* rw0    = (const float*)d_in[23];
    const float* rbn0   = (const float*)d_in[24];
    const float* rw1    = (const float*)d_in[25];
    const float* rbn1   = (const float*)d_in[26];
    const float* rw2    = (const float*)d_in[27];
    const float* rbn2   = (const float*)d_in[28];
    const float* cw0    = (const float*)d_in[29];
    const float* cbn0   = (const float*)d_in[30];
    const float* cw1    = (const float*)d_in[31];
    const float* cbn1   = (const float*)d_in[32];
    const float* cw2    = (const float*)d_in[33];
    const float* cbn2   = (const float*)d_in[34];

    char* ws = (char*)d_ws;
    bf16*   XA   = (bf16*)  (ws + 0);
    bf16*   A0   = (bf16*)  (ws + 0);
    int*    idxg = (int*)   (ws + 3145728);
    bf16*   W0p  = (bf16*)  (ws + 3735552);
    float4* P4   = (float4*)(ws + 3760128);
    bf16*   HF   = (bf16*)  (ws + 6291456);
    bf16*   X1   = (bf16*)  (ws + 6291456);
    bf16*   X2   = (bf16*)  (ws + 10485760);
    bf16*   R1   = (bf16*)  (ws + 12582912);
    bf16*   QIN  = (bf16*)  (ws + 14680064);
    bf16*   P1   = (bf16*)  (ws + 14680064);
    bf16*   P2   = (bf16*)  (ws + 18874368);
    bf16*   C1   = (bf16*)  (ws + 14680064);
    bf16*   C2   = (bf16*)  (ws + 16777216);
    bf16*   CV   = (bf16*)  (ws + 18874368);
    bf16*   Z    = (bf16*)  (ws + 23068672);
    bf16*   R2   = (bf16*)  (ws + 23068672);
    bf16*   WTS  = (bf16*)  (ws + 27262976);

    bf16* W1  = WTS;
    bf16* WZ  = WTS + 16384;
    bf16* WR  = WTS + 49152;
    bf16* WQ  = WTS + 81920;
    bf16* W2A = WTS + 114688;
    bf16* W2B = WTS + 139264;
    bf16* RW0 = WTS + 147456;
    bf16* RW1 = WTS + 151552;
    bf16* CW0 = WTS + 155648;
    bf16* CW1 = WTS + 159744;

    float* out = (float*)d_out;
    dim3 blk(256);

    /*1*/  prep_all<<<dim3(752), blk, 0, stream>>>(xyz, w0, w1, wz, wr, wq,
                w2a, w2b, rw0, rw1, cw0, cw1, P4, W0p, WTS);
    /*2*/  knn_wave2<<<dim3(4096), dim3(512), 0, stream>>>(P4, idxg);
    /*3*/  pack_early<<<dim3(128, 7, 2), blk, 0, stream>>>(cost, flow, feats, A0, HF);
    /*4*/  gemm_k<1><<<dim3(128, 2), blk, 0, stream>>>(A0,  96, W0p, 96,  96, 128, b0, bn0, nullptr, nullptr, P1, 128, 0, nullptr);
    /*5*/  gemm_k<1><<<dim3(128, 2), blk, 0, stream>>>(P1, 128, W1, 128, 128, 128, b1, bn1, nullptr, nullptr, P2, 128, 0, nullptr);
    /*6*/  gather_max<<<dim3(8192), blk, 0, stream>>>(idxg, P2, HF);
    /*7*/  pack_mid<<<dim3(128, 6, 2), blk, 0, stream>>>(points, feats, XA, QIN);
    /*8*/  gemm_k<2><<<dim3(128, 2), blk, 0, stream>>>(HF, 256, WZ, 256, 256, 128, bz, nullptr, nullptr, nullptr, Z,   128, 0, nullptr);
    /*9*/  gemm_k<3><<<dim3(128, 2), blk, 0, stream>>>(HF, 256, WR, 256, 256, 128, br, nullptr, HF,      nullptr, QIN, 256, 0, nullptr);
    /*10*/ gemm_k<4><<<dim3(128, 2), blk, 0, stream>>>(QIN,256, WQ, 256, 256, 128, bq, nullptr, HF,      Z,       XA,  192, 64, nullptr);
    /*11*/ gemm_k<0><<<dim3(128, 2), blk, 0, stream>>>(XA, 192, W2A,192, 192, 128, b2a, nullptr, nullptr, nullptr, X1, 128, 0, nullptr);
    /*12*/ pack_cv<<<dim3(128, 2, 2), blk, 0, stream>>>(cost, CV);
    /*13*/ gemm_k<6><<<dim3(128, 1), blk, 0, stream>>>(X1, 128, W2B,128, 128,  64, b2b, nullptr, nullptr, nullptr, X2,  64, 0, out);
    /*14*/ gemm5_dual<<<dim3(128, 2), blk, 0, stream>>>(X2, RW0, rbn0, R1, CV, CW0, cbn0, C1);
    /*15*/ gemm5_dual<<<dim3(128, 2), blk, 0, stream>>>(R1, RW1, rbn1, R2, C1, CW1, cbn1, C2);
    /*16*/ head_k<<<dim3(64), blk, 0, stream>>>(X2, R2, C2, rw2, rbn2, cw2, cbn2, wfc, bfc, flow, out);

    (void)n_in;
}

// Round 9
// 352.036 us; speedup vs baseline: 2.5756x; 1.1890x over previous
//
#include <hip/hip_runtime.h>
#include <math.h>

typedef __bf16 bf16;
typedef __bf16 bf16x8 __attribute__((ext_vector_type(8)));
typedef float f32x4 __attribute__((ext_vector_type(4)));

#define NPTS 8192
#define MTOT 16384

static __device__ __forceinline__ float b2f(bf16 x) { return (float)x; }
static __device__ __forceinline__ bf16  f2b(float x) { return (bf16)x; }

// ------------------------------------------------------------ diagnostics --
__global__ void diag_k(float* out, float code)
{
    if (threadIdx.x == 0 && blockIdx.x == 0) out[0] = code;
}

// ------------------------------------------------------------- prep_all ----
__global__ __launch_bounds__(256) void prep_all(
    const float* __restrict__ xyz, const float* __restrict__ w0,
    const float* __restrict__ w1, const float* __restrict__ wz,
    const float* __restrict__ wr, const float* __restrict__ wq,
    const float* __restrict__ w2a, const float* __restrict__ w2b,
    const float* __restrict__ rw0, const float* __restrict__ rw1,
    const float* __restrict__ cw0, const float* __restrict__ cw1,
    float4* __restrict__ P4, bf16* __restrict__ w0p, bf16* __restrict__ wts)
{
    const int bx = blockIdx.x;
    if (bx < 64) {                      // P4[j] = (x,y,z,|p|^2)
        int id = bx * 256 + threadIdx.x;
        int b = id >> 13, n = id & (NPTS - 1);
        const float* X = xyz + b * 3 * NPTS;
        float x = X[n], y = X[NPTS + n], z = X[2 * NPTS + n];
        P4[id] = make_float4(x, y, z, x * x + y * y + z * z);
    } else if (bx < 112) {              // w0 [128][67] -> bf16 [128][96]
        int id = (bx - 64) * 256 + threadIdx.x;
        if (id < 128 * 96) {
            int o = id / 96, c = id - o * 96;
            w0p[id] = (c < 67) ? f2b(w0[o * 67 + c]) : (bf16)0.0f;
        }
    } else {                            // stage dense weights f32 -> bf16
        int id = (bx - 112) * 256 + threadIdx.x;
        if (id < 163840) {
            const float* s; int off;
            if (id < 16384)       { s = w1;  off = 0; }
            else if (id < 49152)  { s = wz;  off = 16384; }
            else if (id < 81920)  { s = wr;  off = 49152; }
            else if (id < 114688) { s = wq;  off = 81920; }
            else if (id < 139264) { s = w2a; off = 114688; }
            else if (id < 147456) { s = w2b; off = 139264; }
            else if (id < 151552) { s = rw0; off = 147456; }
            else if (id < 155648) { s = rw1; off = 151552; }
            else if (id < 159744) { s = cw0; off = 155648; }
            else                  { s = cw1; off = 159744; }
            wts[id] = f2b(s[id - off]);
        }
    }
}

// ---------------------------------------------------------------- KNN ------
// v4: ONE wave per query (minimal total insert events ~9+9*ln(N/9) ~ 70),
// no merge pass. u64 lex key = (mono32(d)<<32)|idx -> lex (d,idx) = single
// u64 compare (= top_k first-occurrence; d never -0.0: a-a rounds to +0).
// Init: 9-round butterfly min-knockout over first 64 candidates. Main loop:
// ballot gates extraction; extraction via v_readlane (uniform index).
// 16 KB LDS chunk -> 8 blocks/CU = 32 waves/CU. Distance expr = rounds 4-7.
__global__ __launch_bounds__(256) void knn_wave3(const float4* __restrict__ P4,
                                                 int* __restrict__ idxg)
{
    __shared__ float4 pts[1024];                 // 16 KB
    const int t = threadIdx.x, lane = t & 63, w = t >> 6;
    const int qid = blockIdx.x * 4 + w, b = qid >> 13;   // 4 queries/block, same b
    const float4 q = P4[qid];
    const float4* C0 = P4 + (size_t)b * NPTS;

    unsigned long long kk[9];
#pragma unroll
    for (int k = 0; k < 9; ++k) kk[k] = ~0ull;

    for (int ch = 0; ch < 8; ++ch) {
        __syncthreads();
#pragma unroll
        for (int r2 = 0; r2 < 4; ++r2) {
            int i2 = t + r2 * 256;
            pts[i2] = C0[ch * 1024 + i2];
        }
        __syncthreads();
        int i0 = 0;
        if (ch == 0) {
            // exact top-9 of the first 64 candidates: butterfly min-knockout
            float4 c = pts[lane];
            float d = (q.w + c.w) - 2.0f * (q.x * c.x + q.y * c.y + q.z * c.z);
            unsigned kd = __float_as_uint(d);
            kd ^= ((unsigned)((int)kd >> 31)) | 0x80000000u;
            unsigned long long key = ((unsigned long long)kd << 32) | (unsigned)lane;
#pragma unroll
            for (int r = 0; r < 9; ++r) {
                unsigned long long m = key;
#pragma unroll
                for (int s = 1; s < 64; s <<= 1) {
                    unsigned long long o = __shfl_xor(m, s);
                    if (o < m) m = o;
                }
                kk[r] = m;                       // wave-uniform
                if (key == m) key = ~0ull;       // knockout (keys unique)
            }
            i0 = 1;
        }
        for (int i = i0; i < 16; ++i) {
            float4 c = pts[i * 64 + lane];
            float d = (q.w + c.w) - 2.0f * (q.x * c.x + q.y * c.y + q.z * c.z);
            unsigned kd = __float_as_uint(d);
            kd ^= ((unsigned)((int)kd >> 31)) | 0x80000000u;
            unsigned long long key = ((unsigned long long)kd << 32)
                                   | (unsigned)(ch * 1024 + i * 64 + lane);
            unsigned long long mask = __ballot(key < kk[8]);
            while (mask) {                       // wave-uniform extraction
                int L = __builtin_ctzll(mask);
                mask &= mask - 1;
                unsigned lo = (unsigned)__builtin_amdgcn_readlane((int)key, L);
                unsigned hi = (unsigned)__builtin_amdgcn_readlane((int)(key >> 32), L);
                unsigned long long K = ((unsigned long long)hi << 32) | lo;
                if (K < kk[8]) {
                    bool lt[9];
#pragma unroll
                    for (int j2 = 0; j2 < 9; ++j2) lt[j2] = K < kk[j2];
#pragma unroll
                    for (int j2 = 8; j2 > 0; --j2)
                        kk[j2] = lt[j2] ? (lt[j2 - 1] ? kk[j2 - 1] : K) : kk[j2];
                    kk[0] = lt[0] ? K : kk[0];
                }
            }
        }
    }
    if (lane == 0) {
#pragma unroll
        for (int k = 0; k < 9; ++k) {
            int m = (int)(unsigned)(kk[k] & 0xffffffffu);
            m = ((unsigned)m < (unsigned)NPTS) ? m : 0;   // fault-proof
            idxg[qid * 9 + k] = b * NPTS + m;
        }
    }
}

// --------------------------------------------------------------- pack ------
__device__ __forceinline__ void pack_body(bf16 (*tile)[68],
                                          const float* __restrict__ src, int Csrc,
                                          bf16* __restrict__ dst, int ldd, int colOfs,
                                          int nb, int cb, int b)
{
    const int t = threadIdx.x;
#pragma unroll
    for (int i = 0; i < 8; ++i) {
        int id = t + i * 256;
        int c = id >> 6, n = id & 63;
        int cc = cb + c;
        bf16 v = (bf16)0.0f;
        if (cc < Csrc) v = f2b(src[(size_t)(b * Csrc + cc) * NPTS + nb + n]);
        tile[c][n] = v;
    }
    __syncthreads();
#pragma unroll
    for (int i = 0; i < 8; ++i) {
        int id = t + i * 256;
        int n = id >> 5, c = id & 31;
        dst[(size_t)(b * NPTS + nb + n) * ldd + colOfs + cb + c] = tile[c][n];
    }
}

// early: cost->A0 (y<2), flow->A0 cols64+ (y==2), feats->HF cols128+ (y>=3)
__global__ __launch_bounds__(256) void pack_early(const float* __restrict__ cost,
                                                  const float* __restrict__ flow,
                                                  const float* __restrict__ feats,
                                                  bf16* __restrict__ A0,
                                                  bf16* __restrict__ HF)
{
    __shared__ bf16 tile[32][68];
    const int nb = blockIdx.x * 64, b = blockIdx.z, y = blockIdx.y;
    if (y < 2)       pack_body(tile, cost,  64, A0, 96,   0, nb, y * 32, b);
    else if (y == 2) pack_body(tile, flow,   3, A0, 96,  64, nb, 0,      b);
    else             pack_body(tile, feats, 128, HF, 256, 128, nb, (y - 3) * 32, b);
}

// mid (after gather; A0/idxg dead): points->XA (y<2), feats->QIN cols128+ (y>=2)
__global__ __launch_bounds__(256) void pack_mid(const float* __restrict__ points,
                                                const float* __restrict__ feats,
                                                bf16* __restrict__ XA,
                                                bf16* __restrict__ QIN)
{
    __shared__ bf16 tile[32][68];
    const int nb = blockIdx.x * 64, b = blockIdx.z, y = blockIdx.y;
    if (y < 2) pack_body(tile, points, 64, XA, 192, 0, nb, y * 32, b);
    else       pack_body(tile, feats, 128, QIN, 256, 128, nb, (y - 2) * 32, b);
}

// cv: cost -> CV (ld 64). MUST run after gemm_k<4> (CV @18,874,368 lies inside
// the QIN region 14,680,064..23,068,672 — round-8's failure was packing this
// before QIN's last read; lifetime: QIN dead after step 9).
__global__ __launch_bounds__(256) void pack_cv(const float* __restrict__ cost,
                                               bf16* __restrict__ CV)
{
    __shared__ bf16 tile[32][68];
    pack_body(tile, cost, 64, CV, 64, 0, blockIdx.x * 64, blockIdx.y * 32, blockIdx.z);
}

// --------------------------------------------------------------- GEMM ------
// out[j][o] = epi( sum_c A[j][c] * W[o][c] ). MFMA 16x16x32 bf16 NT (m89 C/D
// mapping). Wave tile 32pt x 32o; block = 2x2 waves = 64pt x 64o ->
// 512+ blocks = 2+ blocks/CU.
template <int EPI>
__global__ __launch_bounds__(256) void gemm_k(
    const bf16* __restrict__ A, int lda,
    const bf16* __restrict__ W, int ldw, int K, int Otot,
    const float* __restrict__ bias, const float* __restrict__ bnp,
    const bf16* __restrict__ aux1, const bf16* __restrict__ aux2,
    bf16* __restrict__ dst, int ldo, int dofs,
    float* __restrict__ out2)
{
    const int w = threadIdx.x >> 6, lane = threadIdx.x & 63;
    const int q = lane >> 4, r = lane & 15;
    const int ptb = blockIdx.x * 64 + (w & 1) * 32;
    const int ob  = blockIdx.y * 64 + (w >> 1) * 32;
    const bf16* Ap = A + (size_t)(ptb + r) * lda + q * 8;
    const bf16* Wp = W + (size_t)(ob + r) * ldw + q * 8;
    f32x4 zero = {0.f, 0.f, 0.f, 0.f};
    f32x4 acc[2][2];
    acc[0][0] = zero; acc[0][1] = zero; acc[1][0] = zero; acc[1][1] = zero;
    for (int k = 0; k < K; k += 32) {
        bf16x8 bv0 = *(const bf16x8*)(Wp + k);
        bf16x8 bv1 = *(const bf16x8*)(Wp + 16 * ldw + k);
        bf16x8 a0 = *(const bf16x8*)(Ap + k);
        bf16x8 a1 = *(const bf16x8*)(Ap + 16 * lda + k);
        acc[0][0] = __builtin_amdgcn_mfma_f32_16x16x32_bf16(a0, bv0, acc[0][0], 0, 0, 0);
        acc[1][0] = __builtin_amdgcn_mfma_f32_16x16x32_bf16(a1, bv0, acc[1][0], 0, 0, 0);
        acc[0][1] = __builtin_amdgcn_mfma_f32_16x16x32_bf16(a0, bv1, acc[0][1], 0, 0, 0);
        acc[1][1] = __builtin_amdgcn_mfma_f32_16x16x32_bf16(a1, bv1, acc[1][1], 0, 0, 0);
    }
#pragma unroll
    for (int to = 0; to < 2; ++to) {
        const int o = ob + to * 16 + r;
        float bs = 0.f, gg = 0.f, be = 0.f, mm = 0.f, rs = 0.f;
        if (EPI != 5) bs = bias[o];
        if (EPI == 1 || EPI == 5) {
            gg = bnp[o]; be = bnp[Otot + o]; mm = bnp[2 * Otot + o];
            float vv = bnp[3 * Otot + o];
            rs = 1.0f / sqrtf(vv + 1e-5f);
        }
#pragma unroll
        for (int tm = 0; tm < 2; ++tm) {
#pragma unroll
            for (int rr = 0; rr < 4; ++rr) {
                const int j = ptb + tm * 16 + q * 4 + rr;
                float v = acc[tm][to][rr];
                if (EPI == 0) { v += bs; v = v > 0.f ? v : 0.1f * v; }
                else if (EPI == 1) { v += bs; v = (v - mm) * rs * gg + be; v = v > 0.f ? v : 0.1f * v; }
                else if (EPI == 4) {
                    v += bs; float qv = tanhf(v);
                    float z = b2f(aux2[(size_t)j * 128 + o]);
                    float h = b2f(aux1[(size_t)j * 256 + o]);
                    v = (1.0f - z) * h + z * qv;
                }
                else if (EPI == 5) { v = (v - mm) * rs * gg + be; v = fmaxf(v, 0.f); }
                else if (EPI == 6) { v += bs; v = v > 0.f ? v : 0.1f * v; }
                dst[(size_t)j * ldo + dofs + o] = f2b(v);
                if (EPI == 6) {
                    int bb = j >> 13, n = j & (NPTS - 1);
                    out2[(size_t)bb * 64 * NPTS + (size_t)o * NPTS + n] = v;
                }
            }
        }
    }
}

// fused GRU z/r gates (independent consumers of HF): grid y in 0..3,
// sel = y>>1 picks z vs r, oy = y&1 picks o-half.
__global__ __launch_bounds__(256) void gemm_zr(
    const bf16* __restrict__ HF, const bf16* __restrict__ WZ,
    const bf16* __restrict__ WR, const float* __restrict__ bz,
    const float* __restrict__ br, bf16* __restrict__ Z, bf16* __restrict__ QIN)
{
    const int sel = blockIdx.y >> 1, oy = blockIdx.y & 1;
    const bf16* W = sel ? WR : WZ;
    const float* bias = sel ? br : bz;
    const int w = threadIdx.x >> 6, lane = threadIdx.x & 63;
    const int q = lane >> 4, r = lane & 15;
    const int ptb = blockIdx.x * 64 + (w & 1) * 32;
    const int ob  = oy * 64 + (w >> 1) * 32;
    const bf16* Ap = HF + (size_t)(ptb + r) * 256 + q * 8;
    const bf16* Wp = W + (size_t)(ob + r) * 256 + q * 8;
    f32x4 zero = {0.f, 0.f, 0.f, 0.f};
    f32x4 acc[2][2];
    acc[0][0] = zero; acc[0][1] = zero; acc[1][0] = zero; acc[1][1] = zero;
#pragma unroll
    for (int k = 0; k < 256; k += 32) {
        bf16x8 bv0 = *(const bf16x8*)(Wp + k);
        bf16x8 bv1 = *(const bf16x8*)(Wp + 16 * 256 + k);
        bf16x8 a0 = *(const bf16x8*)(Ap + k);
        bf16x8 a1 = *(const bf16x8*)(Ap + 16 * 256 + k);
        acc[0][0] = __builtin_amdgcn_mfma_f32_16x16x32_bf16(a0, bv0, acc[0][0], 0, 0, 0);
        acc[1][0] = __builtin_amdgcn_mfma_f32_16x16x32_bf16(a1, bv0, acc[1][0], 0, 0, 0);
        acc[0][1] = __builtin_amdgcn_mfma_f32_16x16x32_bf16(a0, bv1, acc[0][1], 0, 0, 0);
        acc[1][1] = __builtin_amdgcn_mfma_f32_16x16x32_bf16(a1, bv1, acc[1][1], 0, 0, 0);
    }
#pragma unroll
    for (int to = 0; to < 2; ++to) {
        const int o = ob + to * 16 + r;
        const float bs = bias[o];
#pragma unroll
        for (int tm = 0; tm < 2; ++tm) {
#pragma unroll
            for (int rr = 0; rr < 4; ++rr) {
                const int j = ptb + tm * 16 + q * 4 + rr;
                float v = acc[tm][to][rr] + bs;
                v = 1.0f / (1.0f + expf(-v));
                if (sel == 0) Z[(size_t)j * 128 + o] = f2b(v);
                else QIN[(size_t)j * 256 + o] = f2b(v * b2f(HF[(size_t)j * 256 + o]));
            }
        }
    }
}

// dual EPI5 reg-net layer: blockIdx.y selects (refine | coarse); O=K=64.
__global__ __launch_bounds__(256) void gemm5_dual(
    const bf16* __restrict__ A1s, const bf16* __restrict__ W1s,
    const float* __restrict__ bnp1, bf16* __restrict__ d1,
    const bf16* __restrict__ A2s, const bf16* __restrict__ W2s,
    const float* __restrict__ bnp2, bf16* __restrict__ d2)
{
    const bf16* A = blockIdx.y ? A2s : A1s;
    const bf16* W = blockIdx.y ? W2s : W1s;
    const float* bnp = blockIdx.y ? bnp2 : bnp1;
    bf16* dst = blockIdx.y ? d2 : d1;
    const int w = threadIdx.x >> 6, lane = threadIdx.x & 63;
    const int q = lane >> 4, r = lane & 15;
    const int ptb = blockIdx.x * 64 + (w & 1) * 32;
    const int ob  = (w >> 1) * 32;
    const bf16* Ap = A + (size_t)(ptb + r) * 64 + q * 8;
    const bf16* Wp = W + (size_t)(ob + r) * 64 + q * 8;
    f32x4 zero = {0.f, 0.f, 0.f, 0.f};
    f32x4 acc[2][2];
    acc[0][0] = zero; acc[0][1] = zero; acc[1][0] = zero; acc[1][1] = zero;
#pragma unroll
    for (int k = 0; k < 64; k += 32) {
        bf16x8 bv0 = *(const bf16x8*)(Wp + k);
        bf16x8 bv1 = *(const bf16x8*)(Wp + 16 * 64 + k);
        bf16x8 a0 = *(const bf16x8*)(Ap + k);
        bf16x8 a1 = *(const bf16x8*)(Ap + 16 * 64 + k);
        acc[0][0] = __builtin_amdgcn_mfma_f32_16x16x32_bf16(a0, bv0, acc[0][0], 0, 0, 0);
        acc[1][0] = __builtin_amdgcn_mfma_f32_16x16x32_bf16(a1, bv0, acc[1][0], 0, 0, 0);
        acc[0][1] = __builtin_amdgcn_mfma_f32_16x16x32_bf16(a0, bv1, acc[0][1], 0, 0, 0);
        acc[1][1] = __builtin_amdgcn_mfma_f32_16x16x32_bf16(a1, bv1, acc[1][1], 0, 0, 0);
    }
#pragma unroll
    for (int to = 0; to < 2; ++to) {
        const int o = ob + to * 16 + r;
        float gg = bnp[o], be = bnp[64 + o], mm = bnp[128 + o];
        float rs = 1.0f / sqrtf(bnp[192 + o] + 1e-5f);
#pragma unroll
        for (int tm = 0; tm < 2; ++tm) {
#pragma unroll
            for (int rr = 0; rr < 4; ++rr) {
                const int j = ptb + tm * 16 + q * 4 + rr;
                float v = acc[tm][to][rr];
                v = (v - mm) * rs * gg + be; v = fmaxf(v, 0.f);
                dst[(size_t)j * 64 + o] = f2b(v);
            }
        }
    }
}

// ---------------------------------------------------------- gather-max -----
__global__ __launch_bounds__(256) void gather_max(const int* __restrict__ idxg,
                                                  const bf16* __restrict__ P2,
                                                  bf16* __restrict__ HF)
{
    const int id = blockIdx.x * 256 + threadIdx.x;
    const int j = id >> 7, o = id & 127;
    const int* ip = idxg + j * 9;
    float v = -__builtin_inff();
#pragma unroll
    for (int k = 0; k < 9; ++k) {
        int m = ip[k];
        m = ((unsigned)m < (unsigned)MTOT) ? m : 0;   // fault-proof
        v = fmaxf(v, b2f(P2[(size_t)m * 128 + o]));
    }
    HF[(size_t)j * 256 + o] = f2b(v);
}

// --------------------------------------------------------------- head ------
__global__ __launch_bounds__(256) void head_k(
    const bf16* __restrict__ X2, const bf16* __restrict__ R2v, const bf16* __restrict__ C2v,
    const float* __restrict__ rw2, const float* __restrict__ rbn2,
    const float* __restrict__ cw2, const float* __restrict__ cbn2,
    const float* __restrict__ wfc, const float* __restrict__ bfc,
    const float* __restrict__ flow, float* __restrict__ out)
{
    const int j = blockIdx.x * 256 + threadIdx.x;
    const int b = j >> 13, n = j & (NPTS - 1);
    const bf16x8* xr = (const bf16x8*)(X2 + (size_t)j * 64);
    const bf16x8* rr = (const bf16x8*)(R2v + (size_t)j * 64);
    const bf16x8* cr = (const bf16x8*)(C2v + (size_t)j * 64);
    float dr = 0.f, dc = 0.f, p0 = 0.f, p1 = 0.f, p2 = 0.f;
#pragma unroll
    for (int bk = 0; bk < 8; ++bk) {
        bf16x8 xv = xr[bk], rv = rr[bk], cv = cr[bk];
#pragma unroll
        for (int i = 0; i < 8; ++i) {
            const int c = bk * 8 + i;
            float x = (float)xv[i];
            dr += rw2[c] * (float)rv[i];
            dc += cw2[c] * (float)cv[i];
            p0 += wfc[c] * x;
            p1 += wfc[64 + c] * x;
            p2 += wfc[128 + c] * x;
        }
    }
    float refine = (dr - rbn2[2]) / sqrtf(rbn2[3] + 1e-5f) * rbn2[0] + rbn2[1];
    refine = fmaxf(refine, 0.f);
    float coarse = (dc - cbn2[2]) / sqrtf(cbn2[3] + 1e-5f) * cbn2[0] + cbn2[1];
    coarse = fmaxf(coarse, 0.f);
    p0 += bfc[0]; p1 += bfc[1]; p2 += bfc[2];
    const float f0 = flow[(size_t)b * 3 * NPTS + n];
    const float f1 = flow[(size_t)b * 3 * NPTS + NPTS + n];
    const float f2v = flow[(size_t)b * 3 * NPTS + 2 * NPTS + n];
    float o0 = fminf(fmaxf(coarse * f0 + refine * p0, -20.f), 20.f);
    float o1 = fminf(fmaxf(coarse * f1 + refine * p1, -20.f), 20.f);
    float o2 = fminf(fmaxf(coarse * f2v + refine * p2, -20.f), 20.f);
    float* ro = out + 1048576; // x section = 2*64*8192 f32 elements
    ro[(size_t)b * 3 * NPTS + n] = o0;
    ro[(size_t)b * 3 * NPTS + NPTS + n] = o1;
    ro[(size_t)b * 3 * NPTS + 2 * NPTS + n] = o2;
}

// -------------------------------------------------------------- launch -----
// Workspace (27,590,656 B), lifetime-aliased; steps = launch order (1..15).
//   region XA @0 6,291,456            XA [7->9,11]
//     A0 @0 [3->4] | idxg @3,145,728 [2->6]
//     W0p @3,735,552 [1->4] | P4 @3,760,128 [1->2]
//   region HF @6,291,456 8,388,608    HF [3->9]
//     X1 @6,291,456 [11->12] | X2 @10,485,760 [12->15] | R1 @12,582,912 [13->14]
//   region QIN @14,680,064 8,388,608  QIN [7->9]
//     P1 @14,680,064 [4->5] | P2 @18,874,368 [5->6]
//     C1 @14,680,064 [13->14] | C2 @16,777,216 [14->15]
//     CV @18,874,368 [10->13]  (packed AFTER QIN's last read at step 9!)
//   region Z @23,068,672 4,194,304    Z [8->9] | R2 @23,068,672 [14->15]
//   WTS @27,262,976 327,680 [1->14]
extern "C" void kernel_launch(void* const* d_in, const int* in_sizes, int n_in,
                              void* d_out, int out_size, void* d_ws, size_t ws_size,
                              hipStream_t stream)
{
    static const int EXP[35] = {
        49152, 1048576, 1048576, 2097152, 49152,
        8576, 128, 512, 16384, 128, 512,
        32768, 128, 32768, 128, 32768, 128,
        24576, 128, 8192, 64, 192, 3,
        4096, 256, 4096, 256, 64, 4,
        4096, 256, 4096, 256, 64, 4 };
    float code = 0.f;
    if (n_in != 35) code = 900.f;
    else if (out_size != 1097728) code = 950.f;
    else if (ws_size < 27590656u) code = 980.f;
    else { for (int i = 0; i < 35; ++i) if (in_sizes[i] != EXP[i]) { code = 1000.f + 4.f * i; break; } }
    if (code != 0.f) { diag_k<<<dim3(1), dim3(64), 0, stream>>>((float*)d_out, code); return; }

    const float* xyz    = (const float*)d_in[0];
    const float* points = (const float*)d_in[1];
    const float* cost   = (const float*)d_in[2];
    const float* feats  = (const float*)d_in[3];
    const float* flow   = (const float*)d_in[4];
    const float* w0     = (const float*)d_in[5];
    const float* b0     = (const float*)d_in[6];
    const float* bn0    = (const float*)d_in[7];
    const float* w1     = (const float*)d_in[8];
    const float* b1     = (const float*)d_in[9];
    const float* bn1    = (const float*)d_in[10];
    const float* wz     = (const float*)d_in[11];
    const float* bz     = (const float*)d_in[12];
    const float* wr     = (const float*)d_in[13];
    const float* br     = (const float*)d_in[14];
    const float* wq     = (const float*)d_in[15];
    const float* bq     = (const float*)d_in[16];
    const float* w2a    = (const float*)d_in[17];
    const float* b2a    = (const float*)d_in[18];
    const float* w2b    = (const float*)d_in[19];
    const float* b2b    = (const float*)d_in[20];
    const float* wfc    = (const float*)d_in[21];
    const float* bfc    = (const float*)d_in[22];
    const float* rw0    = (const float*)d_in[23];
    const float* rbn0   = (const float*)d_in[24];
    const float* rw1    = (const float*)d_in[25];
    const float* rbn1   = (const float*)d_in[26];
    const float* rw2    = (const float*)d_in[27];
    const float* rbn2   = (const float*)d_in[28];
    const float* cw0    = (const float*)d_in[29];
    const float* cbn0   = (const float*)d_in[30];
    const float* cw1    = (const float*)d_in[31];
    const float* cbn1   = (const float*)d_in[32];
    const float* cw2    = (const float*)d_in[33];
    const float* cbn2   = (const float*)d_in[34];

    char* ws = (char*)d_ws;
    bf16*   XA   = (bf16*)  (ws + 0);
    bf16*   A0   = (bf16*)  (ws + 0);
    int*    idxg = (int*)   (ws + 3145728);
    bf16*   W0p  = (bf16*)  (ws + 3735552);
    float4* P4   = (float4*)(ws + 3760128);
    bf16*   HF   = (bf16*)  (ws + 6291456);
    bf16*   X1   = (bf16*)  (ws + 6291456);
    bf16*   X2   = (bf16*)  (ws + 10485760);
    bf16*   R1   = (bf16*)  (ws + 12582912);
    bf16*   QIN  = (bf16*)  (ws + 14680064);
    bf16*   P1   = (bf16*)  (ws + 14680064);
    bf16*   P2   = (bf16*)  (ws + 18874368);
    bf16*   C1   = (bf16*)  (ws + 14680064);
    bf16*   C2   = (bf16*)  (ws + 16777216);
    bf16*   CV   = (bf16*)  (ws + 18874368);
    bf16*   Z    = (bf16*)  (ws + 23068672);
    bf16*   R2   = (bf16*)  (ws + 23068672);
    bf16*   WTS  = (bf16*)  (ws + 27262976);

    bf16* W1  = WTS;
    bf16* WZ  = WTS + 16384;
    bf16* WR  = WTS + 49152;
    bf16* WQ  = WTS + 81920;
    bf16* W2A = WTS + 114688;
    bf16* W2B = WTS + 139264;
    bf16* RW0 = WTS + 147456;
    bf16* RW1 = WTS + 151552;
    bf16* CW0 = WTS + 155648;
    bf16* CW1 = WTS + 159744;

    float* out = (float*)d_out;
    dim3 blk(256);

    /*1*/  prep_all<<<dim3(752), blk, 0, stream>>>(xyz, w0, w1, wz, wr, wq,
                w2a, w2b, rw0, rw1, cw0, cw1, P4, W0p, WTS);
    /*2*/  knn_wave3<<<dim3(4096), blk, 0, stream>>>(P4, idxg);
    /*3*/  pack_early<<<dim3(128, 7, 2), blk, 0, stream>>>(cost, flow, feats, A0, HF);
    /*4*/  gemm_k<1><<<dim3(256, 2), blk, 0, stream>>>(A0,  96, W0p, 96,  96, 128, b0, bn0, nullptr, nullptr, P1, 128, 0, nullptr);
    /*5*/  gemm_k<1><<<dim3(256, 2), blk, 0, stream>>>(P1, 128, W1, 128, 128, 128, b1, bn1, nullptr, nullptr, P2, 128, 0, nullptr);
    /*6*/  gather_max<<<dim3(8192), blk, 0, stream>>>(idxg, P2, HF);
    /*7*/  pack_mid<<<dim3(128, 6, 2), blk, 0, stream>>>(points, feats, XA, QIN);
    /*8*/  gemm_zr<<<dim3(256, 4), blk, 0, stream>>>(HF, WZ, WR, bz, br, Z, QIN);
    /*9*/  gemm_k<4><<<dim3(256, 2), blk, 0, stream>>>(QIN,256, WQ, 256, 256, 128, bq, nullptr, HF,      Z,       XA,  192, 64, nullptr);
    /*10*/ pack_cv<<<dim3(128, 2, 2), blk, 0, stream>>>(cost, CV);
    /*11*/ gemm_k<0><<<dim3(256, 2), blk, 0, stream>>>(XA, 192, W2A,192, 192, 128, b2a, nullptr, nullptr, nullptr, X1, 128, 0, nullptr);
    /*12*/ gemm_k<6><<<dim3(256, 1), blk, 0, stream>>>(X1, 128, W2B,128, 128,  64, b2b, nullptr, nullptr, nullptr, X2,  64, 0, out);
    /*13*/ gemm5_dual<<<dim3(256, 2), blk, 0, stream>>>(X2, RW0, rbn0, R1, CV, CW0, cbn0, C1);
    /*14*/ gemm5_dual<<<dim3(256, 2), blk, 0, stream>>>(R1, RW1, rbn1, R2, C1, CW1, cbn1, C2);
    /*15*/ head_k<<<dim3(64), blk, 0, stream>>>(X2, R2, C2, rw2, rbn2, cw2, cbn2, wfc, bfc, flow, out);

    (void)n_in;
}

// Round 10
// 334.568 us; speedup vs baseline: 2.7101x; 1.0522x over previous
//
#include <hip/hip_runtime.h>
#include <math.h>

typedef __bf16 bf16;
typedef __bf16 bf16x8 __attribute__((ext_vector_type(8)));
typedef float f32x4 __attribute__((ext_vector_type(4)));

#define NPTS 8192
#define MTOT 16384

static __device__ __forceinline__ float b2f(bf16 x) { return (float)x; }
static __device__ __forceinline__ bf16  f2b(float x) { return (bf16)x; }

// ------------------------------------------------------------ diagnostics --
__global__ void diag_k(float* out, float code)
{
    if (threadIdx.x == 0 && blockIdx.x == 0) out[0] = code;
}

// --------------------------------------------------------------- pack ------
// f32 [B][C][N] channel-major -> bf16 point-major [M][ldd] tile (zero-pad).
__device__ __forceinline__ void pack_body(bf16 (*tile)[68],
                                          const float* __restrict__ src, int Csrc,
                                          bf16* __restrict__ dst, int ldd,
                                          int nb, int cb, int b)
{
    const int t = threadIdx.x;
#pragma unroll
    for (int i = 0; i < 8; ++i) {
        int id = t + i * 256;
        int c = id >> 6, n = id & 63;
        int cc = cb + c;
        bf16 v = (bf16)0.0f;
        if (cc < Csrc) v = f2b(src[(size_t)(b * Csrc + cc) * NPTS + nb + n]);
        tile[c][n] = v;
    }
    __syncthreads();
#pragma unroll
    for (int i = 0; i < 8; ++i) {
        int id = t + i * 256;
        int n = id >> 5, c = id & 31;
        dst[(size_t)(b * NPTS + nb + n) * ldd + cb + c] = tile[c][n];
    }
}

// ------------------------------------------------------------- prep_all ----
// fuses: P4 table + w0 pad + weight staging + ALL primitive packs
// (cost->CV ld64, flow->FL ld32, feats->FE ld128, points->PT ld64).
// Concats are never materialized: GEMMs read two buffers via split-K.
__global__ __launch_bounds__(256) void prep_all(
    const float* __restrict__ xyz, const float* __restrict__ w0,
    const float* __restrict__ w1, const float* __restrict__ wz,
    const float* __restrict__ wr, const float* __restrict__ wq,
    const float* __restrict__ w2a, const float* __restrict__ w2b,
    const float* __restrict__ rw0, const float* __restrict__ rw1,
    const float* __restrict__ cw0, const float* __restrict__ cw1,
    const float* __restrict__ cost, const float* __restrict__ flow,
    const float* __restrict__ feats, const float* __restrict__ points,
    float4* __restrict__ P4, bf16* __restrict__ w0p, bf16* __restrict__ wts,
    bf16* __restrict__ CV, bf16* __restrict__ FL,
    bf16* __restrict__ FE, bf16* __restrict__ PT)
{
    __shared__ bf16 tile[32][68];
    const int bx = blockIdx.x;
    if (bx < 64) {                      // P4[j] = (x,y,z,|p|^2)
        int id = bx * 256 + threadIdx.x;
        int b = id >> 13, n = id & (NPTS - 1);
        const float* X = xyz + b * 3 * NPTS;
        float x = X[n], y = X[NPTS + n], z = X[2 * NPTS + n];
        P4[id] = make_float4(x, y, z, x * x + y * y + z * z);
    } else if (bx < 112) {              // w0 [128][67] -> bf16 [128][96]
        int id = (bx - 64) * 256 + threadIdx.x;
        if (id < 128 * 96) {
            int o = id / 96, c = id - o * 96;
            w0p[id] = (c < 67) ? f2b(w0[o * 67 + c]) : (bf16)0.0f;
        }
    } else if (bx < 752) {              // stage dense weights f32 -> bf16
        int id = (bx - 112) * 256 + threadIdx.x;
        if (id < 163840) {
            const float* s; int off;
            if (id < 16384)       { s = w1;  off = 0; }
            else if (id < 49152)  { s = wz;  off = 16384; }
            else if (id < 81920)  { s = wr;  off = 49152; }
            else if (id < 114688) { s = wq;  off = 81920; }
            else if (id < 139264) { s = w2a; off = 114688; }
            else if (id < 147456) { s = w2b; off = 139264; }
            else if (id < 151552) { s = rw0; off = 147456; }
            else if (id < 155648) { s = rw1; off = 151552; }
            else if (id < 159744) { s = cw0; off = 155648; }
            else                  { s = cw1; off = 159744; }
            wts[id] = f2b(s[id - off]);
        }
    } else if (bx < 1264) {             // cost -> CV ld 64 (512 blocks)
        int l = bx - 752, x = l & 127, r2 = l >> 7;
        pack_body(tile, cost, 64, CV, 64, x * 64, (r2 & 1) * 32, r2 >> 1);
    } else if (bx < 1520) {             // flow -> FL ld 32 (256 blocks)
        int l = bx - 1264, x = l & 127, b = l >> 7;
        pack_body(tile, flow, 3, FL, 32, x * 64, 0, b);
    } else if (bx < 2544) {             // feats -> FE ld 128 (1024 blocks)
        int l = bx - 1520, x = l & 127, r2 = l >> 7;
        pack_body(tile, feats, 128, FE, 128, x * 64, (r2 & 3) * 32, r2 >> 2);
    } else {                            // points -> PT ld 64 (512 blocks)
        int l = bx - 2544, x = l & 127, r2 = l >> 7;
        pack_body(tile, points, 64, PT, 64, x * 64, (r2 & 1) * 32, r2 >> 1);
    }
}

// ---------------------------------------------------------------- KNN ------
// v5: one wave per query. Ballot gate on raw float d <= tau (conservative:
// includes ties; tau decoded from kk[8] only when it changes). Event path
// builds the u64 lex key (mono32(d)<<32)|idx from ONE readlane -> exact
// (d, idx) lex order = top_k first-occurrence. Init: butterfly min-knockout
// over first 64 candidates. Distance expression identical to rounds 4-9.
static __device__ __forceinline__ float tau_decode(unsigned long long k8)
{
    unsigned u = (unsigned)(k8 >> 32);
    unsigned m = 0x80000000u | (unsigned)(~((int)u >> 31));
    return __uint_as_float(u ^ m);
}

__global__ __launch_bounds__(256) void knn_wave4(const float4* __restrict__ P4,
                                                 int* __restrict__ idxg)
{
    __shared__ float4 pts[1024];                 // 16 KB
    const int t = threadIdx.x, lane = t & 63, w = t >> 6;
    const int qid = blockIdx.x * 4 + w, b = qid >> 13;
    const float4 q = P4[qid];
    const float4* C0 = P4 + (size_t)b * NPTS;

    unsigned long long kk[9];
#pragma unroll
    for (int k = 0; k < 9; ++k) kk[k] = ~0ull;
    float tau = __builtin_inff();

    for (int ch = 0; ch < 8; ++ch) {
        __syncthreads();
#pragma unroll
        for (int r2 = 0; r2 < 4; ++r2) {
            int i2 = t + r2 * 256;
            pts[i2] = C0[ch * 1024 + i2];
        }
        __syncthreads();
        int i0 = 0;
        if (ch == 0) {
            float4 c = pts[lane];
            float d = (q.w + c.w) - 2.0f * (q.x * c.x + q.y * c.y + q.z * c.z);
            unsigned kd = __float_as_uint(d);
            kd ^= ((unsigned)((int)kd >> 31)) | 0x80000000u;
            unsigned long long key = ((unsigned long long)kd << 32) | (unsigned)lane;
#pragma unroll
            for (int r = 0; r < 9; ++r) {
                unsigned long long m = key;
#pragma unroll
                for (int s = 1; s < 64; s <<= 1) {
                    unsigned long long o = __shfl_xor(m, s);
                    if (o < m) m = o;
                }
                kk[r] = m;
                if (key == m) key = ~0ull;
            }
            tau = tau_decode(kk[8]);
            i0 = 1;
        }
        for (int i = i0; i < 16; ++i) {
            float4 c = pts[i * 64 + lane];
            float d = (q.w + c.w) - 2.0f * (q.x * c.x + q.y * c.y + q.z * c.z);
            unsigned long long mask = __ballot(d <= tau);
            if (mask) {
                const int base = ch * 1024 + i * 64;
                do {                              // wave-uniform extraction
                    int L = __builtin_ctzll(mask);
                    mask &= mask - 1;
                    float dL = __uint_as_float(
                        (unsigned)__builtin_amdgcn_readlane(__float_as_int(d), L));
                    unsigned kd = __float_as_uint(dL);
                    kd ^= ((unsigned)((int)kd >> 31)) | 0x80000000u;
                    unsigned long long K = ((unsigned long long)kd << 32)
                                         | (unsigned)(base + L);
                    if (K < kk[8]) {
                        bool lt[9];
#pragma unroll
                        for (int j2 = 0; j2 < 9; ++j2) lt[j2] = K < kk[j2];
#pragma unroll
                        for (int j2 = 8; j2 > 0; --j2)
                            kk[j2] = lt[j2] ? (lt[j2 - 1] ? kk[j2 - 1] : K) : kk[j2];
                        kk[0] = lt[0] ? K : kk[0];
                        tau = tau_decode(kk[8]);
                    }
                } while (mask);
            }
        }
    }
    if (lane == 0) {
#pragma unroll
        for (int k = 0; k < 9; ++k) {
            int m = (int)(unsigned)(kk[k] & 0xffffffffu);
            m = ((unsigned)m < (unsigned)NPTS) ? m : 0;   // fault-proof
            idxg[qid * 9 + k] = b * NPTS + m;
        }
    }
}

// --------------------------------------------------------------- GEMM ------
// out[j][o] = epi( sum_c A[j][c] * W[o][c] ) with SPLIT-K A: cols [0,K1) from
// A1 (lda1), cols [K1,K) from A2 (lda2) — concatenation never materialized.
// MFMA 16x16x32 bf16 NT (m89 C/D mapping). Wave 32pt x 32o; block 64pt x 64o.
template <int EPI>
__global__ __launch_bounds__(256) void gemm2(
    const bf16* __restrict__ A1, int lda1, int K1,
    const bf16* __restrict__ A2, int lda2,
    const bf16* __restrict__ W, int ldw, int K, int Otot,
    const float* __restrict__ bias, const float* __restrict__ bnp,
    const bf16* __restrict__ aux1, const bf16* __restrict__ aux2,
    bf16* __restrict__ dst, int ldo, float* __restrict__ out2)
{
    const int w = threadIdx.x >> 6, lane = threadIdx.x & 63;
    const int q = lane >> 4, r = lane & 15;
    const int ptb = blockIdx.x * 64 + (w & 1) * 32;
    const int ob  = blockIdx.y * 64 + (w >> 1) * 32;
    const bf16* Wp = W + (size_t)(ob + r) * ldw + q * 8;
    f32x4 zero = {0.f, 0.f, 0.f, 0.f};
    f32x4 acc[2][2];
    acc[0][0] = zero; acc[0][1] = zero; acc[1][0] = zero; acc[1][1] = zero;
    for (int k = 0; k < K; k += 32) {
        const bf16* Ab; int kb, ld;
        if (k < K1) { Ab = A1; kb = k; ld = lda1; }
        else        { Ab = A2; kb = k - K1; ld = lda2; }
        const bf16* Ap = Ab + (size_t)(ptb + r) * ld + q * 8 + kb;
        bf16x8 bv0 = *(const bf16x8*)(Wp + k);
        bf16x8 bv1 = *(const bf16x8*)(Wp + 16 * ldw + k);
        bf16x8 a0 = *(const bf16x8*)(Ap);
        bf16x8 a1 = *(const bf16x8*)(Ap + 16 * ld);
        acc[0][0] = __builtin_amdgcn_mfma_f32_16x16x32_bf16(a0, bv0, acc[0][0], 0, 0, 0);
        acc[1][0] = __builtin_amdgcn_mfma_f32_16x16x32_bf16(a1, bv0, acc[1][0], 0, 0, 0);
        acc[0][1] = __builtin_amdgcn_mfma_f32_16x16x32_bf16(a0, bv1, acc[0][1], 0, 0, 0);
        acc[1][1] = __builtin_amdgcn_mfma_f32_16x16x32_bf16(a1, bv1, acc[1][1], 0, 0, 0);
    }
#pragma unroll
    for (int to = 0; to < 2; ++to) {
        const int o = ob + to * 16 + r;
        float bs = 0.f, gg = 0.f, be = 0.f, mm = 0.f, rs = 0.f;
        if (EPI != 5) bs = bias[o];
        if (EPI == 1) {
            gg = bnp[o]; be = bnp[Otot + o]; mm = bnp[2 * Otot + o];
            rs = 1.0f / sqrtf(bnp[3 * Otot + o] + 1e-5f);
        }
#pragma unroll
        for (int tm = 0; tm < 2; ++tm) {
#pragma unroll
            for (int rr = 0; rr < 4; ++rr) {
                const int j = ptb + tm * 16 + q * 4 + rr;
                float v = acc[tm][to][rr];
                if (EPI == 0) { v += bs; v = v > 0.f ? v : 0.1f * v; }
                else if (EPI == 1) { v += bs; v = (v - mm) * rs * gg + be; v = v > 0.f ? v : 0.1f * v; }
                else if (EPI == 4) {
                    v += bs; float qv = tanhf(v);
                    float z = b2f(aux2[(size_t)j * 128 + o]);
                    float h = b2f(aux1[(size_t)j * 128 + o]);
                    v = (1.0f - z) * h + z * qv;
                }
                else if (EPI == 6) { v += bs; v = v > 0.f ? v : 0.1f * v; }
                dst[(size_t)j * ldo + o] = f2b(v);
                if (EPI == 6) {
                    int bb = j >> 13, n = j & (NPTS - 1);
                    out2[(size_t)bb * 64 * NPTS + (size_t)o * NPTS + n] = v;
                }
            }
        }
    }
}

// fused GRU z/r gates; A = [h | feats] via split-K (H ld128, FE ld128).
// grid y in 0..3: sel=y>>1 picks z vs r, oy=y&1 picks o-half.
__global__ __launch_bounds__(256) void gemm_zr(
    const bf16* __restrict__ H, const bf16* __restrict__ FE,
    const bf16* __restrict__ WZ, const bf16* __restrict__ WR,
    const float* __restrict__ bz, const float* __restrict__ br,
    bf16* __restrict__ Z, bf16* __restrict__ RH)
{
    const int sel = blockIdx.y >> 1, oy = blockIdx.y & 1;
    const bf16* W = sel ? WR : WZ;
    const float* bias = sel ? br : bz;
    const int w = threadIdx.x >> 6, lane = threadIdx.x & 63;
    const int q = lane >> 4, r = lane & 15;
    const int ptb = blockIdx.x * 64 + (w & 1) * 32;
    const int ob  = oy * 64 + (w >> 1) * 32;
    const bf16* Wp = W + (size_t)(ob + r) * 256 + q * 8;
    f32x4 zero = {0.f, 0.f, 0.f, 0.f};
    f32x4 acc[2][2];
    acc[0][0] = zero; acc[0][1] = zero; acc[1][0] = zero; acc[1][1] = zero;
#pragma unroll
    for (int k = 0; k < 256; k += 32) {
        const bf16* Ab = (k < 128) ? H : FE;
        const int kb = k & 127;
        const bf16* Ap = Ab + (size_t)(ptb + r) * 128 + q * 8 + kb;
        bf16x8 bv0 = *(const bf16x8*)(Wp + k);
        bf16x8 bv1 = *(const bf16x8*)(Wp + 16 * 256 + k);
        bf16x8 a0 = *(const bf16x8*)(Ap);
        bf16x8 a1 = *(const bf16x8*)(Ap + 16 * 128);
        acc[0][0] = __builtin_amdgcn_mfma_f32_16x16x32_bf16(a0, bv0, acc[0][0], 0, 0, 0);
        acc[1][0] = __builtin_amdgcn_mfma_f32_16x16x32_bf16(a1, bv0, acc[1][0], 0, 0, 0);
        acc[0][1] = __builtin_amdgcn_mfma_f32_16x16x32_bf16(a0, bv1, acc[0][1], 0, 0, 0);
        acc[1][1] = __builtin_amdgcn_mfma_f32_16x16x32_bf16(a1, bv1, acc[1][1], 0, 0, 0);
    }
#pragma unroll
    for (int to = 0; to < 2; ++to) {
        const int o = ob + to * 16 + r;
        const float bs = bias[o];
#pragma unroll
        for (int tm = 0; tm < 2; ++tm) {
#pragma unroll
            for (int rr = 0; rr < 4; ++rr) {
                const int j = ptb + tm * 16 + q * 4 + rr;
                float v = acc[tm][to][rr] + bs;
                v = 1.0f / (1.0f + expf(-v));
                if (sel == 0) Z[(size_t)j * 128 + o] = f2b(v);
                else RH[(size_t)j * 128 + o] = f2b(v * b2f(H[(size_t)j * 128 + o]));
            }
        }
    }
}

// dual EPI5 reg-net layer: blockIdx.y selects (refine | coarse); O=K=64.
__global__ __launch_bounds__(256) void gemm5_dual(
    const bf16* __restrict__ A1s, const bf16* __restrict__ W1s,
    const float* __restrict__ bnp1, bf16* __restrict__ d1,
    const bf16* __restrict__ A2s, const bf16* __restrict__ W2s,
    const float* __restrict__ bnp2, bf16* __restrict__ d2)
{
    const bf16* A = blockIdx.y ? A2s : A1s;
    const bf16* W = blockIdx.y ? W2s : W1s;
    const float* bnp = blockIdx.y ? bnp2 : bnp1;
    bf16* dst = blockIdx.y ? d2 : d1;
    const int w = threadIdx.x >> 6, lane = threadIdx.x & 63;
    const int q = lane >> 4, r = lane & 15;
    const int ptb = blockIdx.x * 64 + (w & 1) * 32;
    const int ob  = (w >> 1) * 32;
    const bf16* Ap = A + (size_t)(ptb + r) * 64 + q * 8;
    const bf16* Wp = W + (size_t)(ob + r) * 64 + q * 8;
    f32x4 zero = {0.f, 0.f, 0.f, 0.f};
    f32x4 acc[2][2];
    acc[0][0] = zero; acc[0][1] = zero; acc[1][0] = zero; acc[1][1] = zero;
#pragma unroll
    for (int k = 0; k < 64; k += 32) {
        bf16x8 bv0 = *(const bf16x8*)(Wp + k);
        bf16x8 bv1 = *(const bf16x8*)(Wp + 16 * 64 + k);
        bf16x8 a0 = *(const bf16x8*)(Ap + k);
        bf16x8 a1 = *(const bf16x8*)(Ap + 16 * 64 + k);
        acc[0][0] = __builtin_amdgcn_mfma_f32_16x16x32_bf16(a0, bv0, acc[0][0], 0, 0, 0);
        acc[1][0] = __builtin_amdgcn_mfma_f32_16x16x32_bf16(a1, bv0, acc[1][0], 0, 0, 0);
        acc[0][1] = __builtin_amdgcn_mfma_f32_16x16x32_bf16(a0, bv1, acc[0][1], 0, 0, 0);
        acc[1][1] = __builtin_amdgcn_mfma_f32_16x16x32_bf16(a1, bv1, acc[1][1], 0, 0, 0);
    }
#pragma unroll
    for (int to = 0; to < 2; ++to) {
        const int o = ob + to * 16 + r;
        float gg = bnp[o], be = bnp[64 + o], mm = bnp[128 + o];
        float rs = 1.0f / sqrtf(bnp[192 + o] + 1e-5f);
#pragma unroll
        for (int tm = 0; tm < 2; ++tm) {
#pragma unroll
            for (int rr = 0; rr < 4; ++rr) {
                const int j = ptb + tm * 16 + q * 4 + rr;
                float v = acc[tm][to][rr];
                v = (v - mm) * rs * gg + be; v = fmaxf(v, 0.f);
                dst[(size_t)j * 64 + o] = f2b(v);
            }
        }
    }
}

// ---------------------------------------------------------- gather-max -----
__global__ __launch_bounds__(256) void gather_max(const int* __restrict__ idxg,
                                                  const bf16* __restrict__ P2,
                                                  bf16* __restrict__ H)
{
    const int id = blockIdx.x * 256 + threadIdx.x;
    const int j = id >> 7, o = id & 127;
    const int* ip = idxg + j * 9;
    float v = -__builtin_inff();
#pragma unroll
    for (int k = 0; k < 9; ++k) {
        int m = ip[k];
        m = ((unsigned)m < (unsigned)MTOT) ? m : 0;   // fault-proof
        v = fmaxf(v, b2f(P2[(size_t)m * 128 + o]));
    }
    H[(size_t)j * 128 + o] = f2b(v);
}

// --------------------------------------------------------------- head ------
__global__ __launch_bounds__(256) void head_k(
    const bf16* __restrict__ X2, const bf16* __restrict__ R2v, const bf16* __restrict__ C2v,
    const float* __restrict__ rw2, const float* __restrict__ rbn2,
    const float* __restrict__ cw2, const float* __restrict__ cbn2,
    const float* __restrict__ wfc, const float* __restrict__ bfc,
    const float* __restrict__ flow, float* __restrict__ out)
{
    const int j = blockIdx.x * 256 + threadIdx.x;
    const int b = j >> 13, n = j & (NPTS - 1);
    const bf16x8* xr = (const bf16x8*)(X2 + (size_t)j * 64);
    const bf16x8* rr = (const bf16x8*)(R2v + (size_t)j * 64);
    const bf16x8* cr = (const bf16x8*)(C2v + (size_t)j * 64);
    float dr = 0.f, dc = 0.f, p0 = 0.f, p1 = 0.f, p2 = 0.f;
#pragma unroll
    for (int bk = 0; bk < 8; ++bk) {
        bf16x8 xv = xr[bk], rv = rr[bk], cv = cr[bk];
#pragma unroll
        for (int i = 0; i < 8; ++i) {
            const int c = bk * 8 + i;
            float x = (float)xv[i];
            dr += rw2[c] * (float)rv[i];
            dc += cw2[c] * (float)cv[i];
            p0 += wfc[c] * x;
            p1 += wfc[64 + c] * x;
            p2 += wfc[128 + c] * x;
        }
    }
    float refine = (dr - rbn2[2]) / sqrtf(rbn2[3] + 1e-5f) * rbn2[0] + rbn2[1];
    refine = fmaxf(refine, 0.f);
    float coarse = (dc - cbn2[2]) / sqrtf(cbn2[3] + 1e-5f) * cbn2[0] + cbn2[1];
    coarse = fmaxf(coarse, 0.f);
    p0 += bfc[0]; p1 += bfc[1]; p2 += bfc[2];
    const float f0 = flow[(size_t)b * 3 * NPTS + n];
    const float f1 = flow[(size_t)b * 3 * NPTS + NPTS + n];
    const float f2v = flow[(size_t)b * 3 * NPTS + 2 * NPTS + n];
    float o0 = fminf(fmaxf(coarse * f0 + refine * p0, -20.f), 20.f);
    float o1 = fminf(fmaxf(coarse * f1 + refine * p1, -20.f), 20.f);
    float o2 = fminf(fmaxf(coarse * f2v + refine * p2, -20.f), 20.f);
    float* ro = out + 1048576;
    ro[(size_t)b * 3 * NPTS + n] = o0;
    ro[(size_t)b * 3 * NPTS + NPTS + n] = o1;
    ro[(size_t)b * 3 * NPTS + 2 * NPTS + n] = o2;
}

// -------------------------------------------------------------- launch -----
// Workspace (27,590,656 B), lifetime-aliased; steps = launch order (1..12):
//  1 prep  2 knn  3 g1(CV|FL->P1)  4 g2(P1->P2)  5 gather(P2->H)
//  6 zr(H|FE->Z,RH)  7 gq(RH|FE->HP; aux H,Z)  8 g2a(PT|HP->X1)
//  9 g2b(X1->X2,out) 10 reg1(X2->R1, CV->C1) 11 reg2(R1->R2, C1->C2) 12 head
//   P4  @0          262,144 [1->2]   | W0p @262,144  24,576 [1->3]
//   WTS @286,720    327,680 [1->11]  | idxg @614,400 589,824 [2->5]
//   CV  @1,204,224  2,097,152 [1->10]| FL @3,301,376 1,048,576 [1->3]
//   FE  @4,349,952  4,194,304 [1->7] | PT @8,544,256 2,097,152 [1->8]
//   H   @10,641,408 4,194,304 [5->7] | X1 = H slot [8->9]
//   P1  @14,835,712 4,194,304 [3->4] | RH = P1 slot [6->7] | X2 @14,835,712 [9->12]
//     R1 @16,932,864 2,097,152 [10->11]
//   P2  @19,030,016 4,194,304 [4->5] | HP = P2 slot [7->8] | C1 @19,030,016 [10->11]
//     R2 @21,127,168 2,097,152 [11->12]
//   Z   @23,224,320 4,194,304 [6->7] | C2 @23,224,320 [11->12]
// max end 27,418,624 <= 27,590,656
extern "C" void kernel_launch(void* const* d_in, const int* in_sizes, int n_in,
                              void* d_out, int out_size, void* d_ws, size_t ws_size,
                              hipStream_t stream)
{
    static const int EXP[35] = {
        49152, 1048576, 1048576, 2097152, 49152,
        8576, 128, 512, 16384, 128, 512,
        32768, 128, 32768, 128, 32768, 128,
        24576, 128, 8192, 64, 192, 3,
        4096, 256, 4096, 256, 64, 4,
        4096, 256, 4096, 256, 64, 4 };
    float code = 0.f;
    if (n_in != 35) code = 900.f;
    else if (out_size != 1097728) code = 950.f;
    else if (ws_size < 27590656u) code = 980.f;
    else { for (int i = 0; i < 35; ++i) if (in_sizes[i] != EXP[i]) { code = 1000.f + 4.f * i; break; } }
    if (code != 0.f) { diag_k<<<dim3(1), dim3(64), 0, stream>>>((float*)d_out, code); return; }

    const float* xyz    = (const float*)d_in[0];
    const float* points = (const float*)d_in[1];
    const float* cost   = (const float*)d_in[2];
    const float* feats  = (const float*)d_in[3];
    const float* flow   = (const float*)d_in[4];
    const float* w0     = (const float*)d_in[5];
    const float* b0     = (const float*)d_in[6];
    const float* bn0    = (const float*)d_in[7];
    const float* w1     = (const float*)d_in[8];
    const float* b1     = (const float*)d_in[9];
    const float* bn1    = (const float*)d_in[10];
    const float* wz     = (const float*)d_in[11];
    const float* bz     = (const float*)d_in[12];
    const float* wr     = (const float*)d_in[13];
    const float* br     = (const float*)d_in[14];
    const float* wq     = (const float*)d_in[15];
    const float* bq     = (const float*)d_in[16];
    const float* w2a    = (const float*)d_in[17];
    const float* b2a    = (const float*)d_in[18];
    const float* w2b    = (const float*)d_in[19];
    const float* b2b    = (const float*)d_in[20];
    const float* wfc    = (const float*)d_in[21];
    const float* bfc    = (const float*)d_in[22];
    const float* rw0    = (const float*)d_in[23];
    const float* rbn0   = (const float*)d_in[24];
    const float* rw1    = (const float*)d_in[25];
    const float* rbn1   = (const float*)d_in[26];
    const float* rw2    = (const float*)d_in[27];
    const float* rbn2   = (const float*)d_in[28];
    const float* cw0    = (const float*)d_in[29];
    const float* cbn0   = (const float*)d_in[30];
    const float* cw1    = (const float*)d_in[31];
    const float* cbn1   = (const float*)d_in[32];
    const float* cw2    = (const float*)d_in[33];
    const float* cbn2   = (const float*)d_in[34];

    char* ws = (char*)d_ws;
    float4* P4   = (float4*)(ws + 0);
    bf16*   W0p  = (bf16*)  (ws + 262144);
    bf16*   WTS  = (bf16*)  (ws + 286720);
    int*    idxg = (int*)   (ws + 614400);
    bf16*   CV   = (bf16*)  (ws + 1204224);
    bf16*   FL   = (bf16*)  (ws + 3301376);
    bf16*   FE   = (bf16*)  (ws + 4349952);
    bf16*   PT   = (bf16*)  (ws + 8544256);
    bf16*   H    = (bf16*)  (ws + 10641408);
    bf16*   X1   = (bf16*)  (ws + 10641408);
    bf16*   P1   = (bf16*)  (ws + 14835712);
    bf16*   RH   = (bf16*)  (ws + 14835712);
    bf16*   X2   = (bf16*)  (ws + 14835712);
    bf16*   R1   = (bf16*)  (ws + 16932864);
    bf16*   P2   = (bf16*)  (ws + 19030016);
    bf16*   HP   = (bf16*)  (ws + 19030016);
    bf16*   C1   = (bf16*)  (ws + 19030016);
    bf16*   R2   = (bf16*)  (ws + 21127168);
    bf16*   Z    = (bf16*)  (ws + 23224320);
    bf16*   C2   = (bf16*)  (ws + 23224320);

    bf16* W1  = WTS;
    bf16* WZ  = WTS + 16384;
    bf16* WR  = WTS + 49152;
    bf16* WQ  = WTS + 81920;
    bf16* W2A = WTS + 114688;
    bf16* W2B = WTS + 139264;
    bf16* RW0 = WTS + 147456;
    bf16* RW1 = WTS + 151552;
    bf16* CW0 = WTS + 155648;
    bf16* CW1 = WTS + 159744;

    float* out = (float*)d_out;
    dim3 blk(256);

    /*1*/  prep_all<<<dim3(3056), blk, 0, stream>>>(xyz, w0, w1, wz, wr, wq,
                w2a, w2b, rw0, rw1, cw0, cw1, cost, flow, feats, points,
                P4, W0p, WTS, CV, FL, FE, PT);
    /*2*/  knn_wave4<<<dim3(4096), blk, 0, stream>>>(P4, idxg);
    /*3*/  gemm2<1><<<dim3(256, 2), blk, 0, stream>>>(CV, 64, 64, FL, 32,
                W0p, 96, 96, 128, b0, bn0, nullptr, nullptr, P1, 128, nullptr);
    /*4*/  gemm2<1><<<dim3(256, 2), blk, 0, stream>>>(P1, 128, 128, P1, 128,
                W1, 128, 128, 128, b1, bn1, nullptr, nullptr, P2, 128, nullptr);
    /*5*/  gather_max<<<dim3(8192), blk, 0, stream>>>(idxg, P2, H);
    /*6*/  gemm_zr<<<dim3(256, 4), blk, 0, stream>>>(H, FE, WZ, WR, bz, br, Z, RH);
    /*7*/  gemm2<4><<<dim3(256, 2), blk, 0, stream>>>(RH, 128, 128, FE, 128,
                WQ, 256, 256, 128, bq, nullptr, H, Z, HP, 128, nullptr);
    /*8*/  gemm2<0><<<dim3(256, 2), blk, 0, stream>>>(PT, 64, 64, HP, 128,
                W2A, 192, 192, 128, b2a, nullptr, nullptr, nullptr, X1, 128, nullptr);
    /*9*/  gemm2<6><<<dim3(256, 1), blk, 0, stream>>>(X1, 128, 128, X1, 128,
                W2B, 128, 128, 64, b2b, nullptr, nullptr, nullptr, X2, 64, out);
    /*10*/ gemm5_dual<<<dim3(256, 2), blk, 0, stream>>>(X2, RW0, rbn0, R1, CV, CW0, cbn0, C1);
    /*11*/ gemm5_dual<<<dim3(256, 2), blk, 0, stream>>>(R1, RW1, rbn1, R2, C1, CW1, cbn1, C2);
    /*12*/ head_k<<<dim3(64), blk, 0, stream>>>(X2, R2, C2, rw2, rbn2, cw2, cbn2, wfc, bfc, flow, out);

    (void)n_in;
}

// Round 12
// 298.497 us; speedup vs baseline: 3.0376x; 1.1208x over previous
//
#include <hip/hip_runtime.h>
#include <math.h>

typedef __bf16 bf16;
typedef __bf16 bf16x8 __attribute__((ext_vector_type(8)));
typedef float f32x4 __attribute__((ext_vector_type(4)));

#define NPTS 8192
#define MTOT 16384

static __device__ __forceinline__ float b2f(bf16 x) { return (float)x; }
static __device__ __forceinline__ bf16  f2b(float x) { return (bf16)x; }

// ------------------------------------------------------------ diagnostics --
__global__ void diag_k(float* out, float code)
{
    if (threadIdx.x == 0 && blockIdx.x == 0) out[0] = code;
}

// --------------------------------------------------------------- pack ------
static __device__ __forceinline__ void pack_body(bf16 (*tile)[68],
                                                 const float* __restrict__ src, int Csrc,
                                                 bf16* __restrict__ dst, int ldd,
                                                 int nb, int cb, int b)
{
    const int t = threadIdx.x;
#pragma unroll
    for (int i = 0; i < 8; ++i) {
        int id = t + i * 256;
        int c = id >> 6, n = id & 63;
        int cc = cb + c;
        bf16 v = (bf16)0.0f;
        if (cc < Csrc) v = f2b(src[(size_t)(b * Csrc + cc) * NPTS + nb + n]);
        tile[c][n] = v;
    }
    __syncthreads();
#pragma unroll
    for (int i = 0; i < 8; ++i) {
        int id = t + i * 256;
        int n = id >> 5, c = id & 31;
        dst[(size_t)(b * NPTS + nb + n) * ldd + cb + c] = tile[c][n];
    }
}

static __device__ __forceinline__ float tau_decode(unsigned long long k8)
{
    unsigned u = (unsigned)(k8 >> 32);
    unsigned m = 0x80000000u | (unsigned)(~((int)u >> 31));
    return __uint_as_float(u ^ m);
}

// ------------------------------------------- L1: fused prep + knn ----------
// prep (blocks 0..2991) and knn (blocks 2992..7087) are mutually independent.
// knn = round-10 knn_wave4 algorithm, reading xyz directly (bit-identical
// arithmetic to the old P4 prep).
__global__ __launch_bounds__(256) void prep_knn(
    const float* __restrict__ xyz, const float* __restrict__ w0,
    const float* __restrict__ w1, const float* __restrict__ wz,
    const float* __restrict__ wr, const float* __restrict__ wq,
    const float* __restrict__ w2a, const float* __restrict__ w2b,
    const float* __restrict__ rw0, const float* __restrict__ rw1,
    const float* __restrict__ cw0, const float* __restrict__ cw1,
    const float* __restrict__ cost, const float* __restrict__ flow,
    const float* __restrict__ feats, const float* __restrict__ points,
    bf16* __restrict__ w0p, bf16* __restrict__ wts,
    bf16* __restrict__ CV, bf16* __restrict__ FL,
    bf16* __restrict__ FE, bf16* __restrict__ PT,
    int* __restrict__ idxg)
{
    __shared__ __align__(16) char smem[16384];
    const int bx = blockIdx.x;
    if (bx < 2992) {
        bf16 (*tile)[68] = (bf16 (*)[68])smem;
        if (bx < 48) {
            int id = bx * 256 + threadIdx.x;
            if (id < 128 * 96) {
                int o = id / 96, c = id - o * 96;
                w0p[id] = (c < 67) ? f2b(w0[o * 67 + c]) : (bf16)0.0f;
            }
        } else if (bx < 688) {
            int id = (bx - 48) * 256 + threadIdx.x;
            if (id < 163840) {
                const float* s; int off;
                if (id < 16384)       { s = w1;  off = 0; }
                else if (id < 49152)  { s = wz;  off = 16384; }
                else if (id < 81920)  { s = wr;  off = 49152; }
                else if (id < 114688) { s = wq;  off = 81920; }
                else if (id < 139264) { s = w2a; off = 114688; }
                else if (id < 147456) { s = w2b; off = 139264; }
                else if (id < 151552) { s = rw0; off = 147456; }
                else if (id < 155648) { s = rw1; off = 151552; }
                else if (id < 159744) { s = cw0; off = 155648; }
                else                  { s = cw1; off = 159744; }
                wts[id] = f2b(s[id - off]);
            }
        } else if (bx < 1200) {
            int l = bx - 688, x = l & 127, r2 = l >> 7;
            pack_body(tile, cost, 64, CV, 64, x * 64, (r2 & 1) * 32, r2 >> 1);
        } else if (bx < 1456) {
            int l = bx - 1200, x = l & 127, b = l >> 7;
            pack_body(tile, flow, 3, FL, 32, x * 64, 0, b);
        } else if (bx < 2480) {
            int l = bx - 1456, x = l & 127, r2 = l >> 7;
            pack_body(tile, feats, 128, FE, 128, x * 64, (r2 & 3) * 32, r2 >> 2);
        } else {
            int l = bx - 2480, x = l & 127, r2 = l >> 7;
            pack_body(tile, points, 64, PT, 64, x * 64, (r2 & 1) * 32, r2 >> 1);
        }
        return;
    }
    // ------------------------------ knn -----------------------------------
    float4* pts = (float4*)smem;
    const int t = threadIdx.x, lane = t & 63, w = t >> 6;
    const int qid = (bx - 2992) * 4 + w, b = qid >> 13;
    const float* X = xyz + b * 3 * NPTS;
    const int n = qid & (NPTS - 1);
    const float qx = X[n], qy = X[NPTS + n], qz = X[2 * NPTS + n];
    const float qsq = qx * qx + qy * qy + qz * qz;

    unsigned long long kk[9];
#pragma unroll
    for (int k = 0; k < 9; ++k) kk[k] = ~0ull;
    float tau = __builtin_inff();

    for (int ch = 0; ch < 8; ++ch) {
        __syncthreads();
#pragma unroll
        for (int r2 = 0; r2 < 4; ++r2) {
            int i2 = t + r2 * 256;
            int ci = ch * 1024 + i2;
            float x = X[ci], y = X[NPTS + ci], z = X[2 * NPTS + ci];
            pts[i2] = make_float4(x, y, z, x * x + y * y + z * z);
        }
        __syncthreads();
        int i0 = 0;
        if (ch == 0) {
            float4 c = pts[lane];
            float d = (qsq + c.w) - 2.0f * (qx * c.x + qy * c.y + qz * c.z);
            unsigned kd = __float_as_uint(d);
            kd ^= ((unsigned)((int)kd >> 31)) | 0x80000000u;
            unsigned long long key = ((unsigned long long)kd << 32) | (unsigned)lane;
#pragma unroll
            for (int r = 0; r < 9; ++r) {
                unsigned long long m = key;
#pragma unroll
                for (int s = 1; s < 64; s <<= 1) {
                    unsigned long long o = __shfl_xor(m, s);
                    if (o < m) m = o;
                }
                kk[r] = m;
                if (key == m) key = ~0ull;
            }
            tau = tau_decode(kk[8]);
            i0 = 1;
        }
        for (int i = i0; i < 16; ++i) {
            float4 c = pts[i * 64 + lane];
            float d = (qsq + c.w) - 2.0f * (qx * c.x + qy * c.y + qz * c.z);
            unsigned long long mask = __ballot(d <= tau);
            if (mask) {
                const int base = ch * 1024 + i * 64;
                do {
                    int L = __builtin_ctzll(mask);
                    mask &= mask - 1;
                    float dL = __uint_as_float(
                        (unsigned)__builtin_amdgcn_readlane(__float_as_int(d), L));
                    unsigned kd = __float_as_uint(dL);
                    kd ^= ((unsigned)((int)kd >> 31)) | 0x80000000u;
                    unsigned long long K = ((unsigned long long)kd << 32)
                                         | (unsigned)(base + L);
                    if (K < kk[8]) {
                        bool lt[9];
#pragma unroll
                        for (int j2 = 0; j2 < 9; ++j2) lt[j2] = K < kk[j2];
#pragma unroll
                        for (int j2 = 8; j2 > 0; --j2)
                            kk[j2] = lt[j2] ? (lt[j2 - 1] ? kk[j2 - 1] : K) : kk[j2];
                        kk[0] = lt[0] ? K : kk[0];
                        tau = tau_decode(kk[8]);
                    }
                } while (mask);
            }
        }
    }
    if (lane == 0) {
#pragma unroll
        for (int k = 0; k < 9; ++k) {
            int m = (int)(unsigned)(kk[k] & 0xffffffffu);
            m = ((unsigned)m < (unsigned)NPTS) ? m : 0;
            idxg[qid * 9 + k] = b * NPTS + m;
        }
    }
}

// --------------------------------------------------- 32x32 wave-tile MM ----
// acc += A[rows...][k] * W[o][k]; A split-K across (A1,lda1,row01,K1) then
// (A2,lda2,row02). Pointers may be LDS or global (generic AS, inlined).
static __device__ __forceinline__ void mm32(
    f32x4 (&acc)[2][2],
    const bf16* A1, int lda1, int row01, int K1,
    const bf16* A2, int lda2, int row02,
    const bf16* W, int ldw, int K, int ob)
{
    const int lane = threadIdx.x & 63;
    const int q = lane >> 4, r = lane & 15;
    const bf16* Wp = W + (size_t)(ob + r) * ldw + q * 8;
    for (int k = 0; k < K; k += 32) {
        const bf16* Ap; int ld;
        if (k < K1) { ld = lda1; Ap = A1 + (size_t)(row01 + r) * lda1 + q * 8 + k; }
        else        { ld = lda2; Ap = A2 + (size_t)(row02 + r) * lda2 + q * 8 + (k - K1); }
        bf16x8 bv0 = *(const bf16x8*)(Wp + k);
        bf16x8 bv1 = *(const bf16x8*)(Wp + 16 * ldw + k);
        bf16x8 a0 = *(const bf16x8*)(Ap);
        bf16x8 a1 = *(const bf16x8*)(Ap + 16 * ld);
        acc[0][0] = __builtin_amdgcn_mfma_f32_16x16x32_bf16(a0, bv0, acc[0][0], 0, 0, 0);
        acc[1][0] = __builtin_amdgcn_mfma_f32_16x16x32_bf16(a1, bv0, acc[1][0], 0, 0, 0);
        acc[0][1] = __builtin_amdgcn_mfma_f32_16x16x32_bf16(a0, bv1, acc[0][1], 0, 0, 0);
        acc[1][1] = __builtin_amdgcn_mfma_f32_16x16x32_bf16(a1, bv1, acc[1][1], 0, 0, 0);
    }
}

static __device__ __forceinline__ void zacc(f32x4 (&acc)[2][2])
{
    f32x4 z = {0.f, 0.f, 0.f, 0.f};
    acc[0][0] = z; acc[0][1] = z; acc[1][0] = z; acc[1][1] = z;
}

// ------------------------------------- L2: conv1+conv2 fused (row-local) ---
// block = 32 points; conv1 (K=96, CV|FL split) -> P1 tile in LDS;
// conv2 (K=128, A from LDS) -> P2 global. Arithmetic identical to R10.
__global__ __launch_bounds__(256) void conv12(
    const bf16* __restrict__ CV, const bf16* __restrict__ FL,
    const bf16* __restrict__ W0p, const bf16* __restrict__ W1,
    const float* __restrict__ b0, const float* __restrict__ bn0,
    const float* __restrict__ b1, const float* __restrict__ bn1,
    bf16* __restrict__ P2)
{
    __shared__ __align__(16) bf16 P1t[32][136];
    const int w = threadIdx.x >> 6, lane = threadIdx.x & 63;
    const int q = lane >> 4, r = lane & 15;
    const int ptb = blockIdx.x * 32;
    {
        f32x4 acc[2][2]; zacc(acc);
        const int ob = w * 32;
        mm32(acc, CV, 64, ptb, 64, FL, 32, ptb, W0p, 96, 96, ob);
#pragma unroll
        for (int to = 0; to < 2; ++to) {
            const int o = ob + to * 16 + r;
            float bs = b0[o];
            float gg = bn0[o], be = bn0[128 + o], mm = bn0[256 + o];
            float rs = 1.0f / sqrtf(bn0[384 + o] + 1e-5f);
#pragma unroll
            for (int tm = 0; tm < 2; ++tm) {
#pragma unroll
                for (int rr = 0; rr < 4; ++rr) {
                    const int jl = tm * 16 + q * 4 + rr;
                    float v = acc[tm][to][rr] + bs;
                    v = (v - mm) * rs * gg + be;
                    v = v > 0.f ? v : 0.1f * v;
                    P1t[jl][o] = f2b(v);
                }
            }
        }
    }
    __syncthreads();
    {
        f32x4 acc[2][2]; zacc(acc);
        const int ob = w * 32;
        mm32(acc, &P1t[0][0], 136, 0, 128, &P1t[0][0], 136, 0, W1, 128, 128, ob);
#pragma unroll
        for (int to = 0; to < 2; ++to) {
            const int o = ob + to * 16 + r;
            float bs = b1[o];
            float gg = bn1[o], be = bn1[128 + o], mm = bn1[256 + o];
            float rs = 1.0f / sqrtf(bn1[384 + o] + 1e-5f);
#pragma unroll
            for (int tm = 0; tm < 2; ++tm) {
#pragma unroll
                for (int rr = 0; rr < 4; ++rr) {
                    const int jl = tm * 16 + q * 4 + rr;
                    float v = acc[tm][to][rr] + bs;
                    v = (v - mm) * rs * gg + be;
                    v = v > 0.f ? v : 0.1f * v;
                    P2[(size_t)(ptb + jl) * 128 + o] = f2b(v);
                }
            }
        }
    }
}

// --------------------------------------------------- L3: gather-max --------
__global__ __launch_bounds__(256) void gather_max(const int* __restrict__ idxg,
                                                  const bf16* __restrict__ P2,
                                                  bf16* __restrict__ H)
{
    const int id = blockIdx.x * 256 + threadIdx.x;
    const int j = id >> 7, o = id & 127;
    const int* ip = idxg + j * 9;
    float v = -__builtin_inff();
#pragma unroll
    for (int k = 0; k < 9; ++k) {
        int m = ip[k];
        m = ((unsigned)m < (unsigned)MTOT) ? m : 0;
        v = fmaxf(v, b2f(P2[(size_t)m * 128 + o]));
    }
    H[(size_t)j * 128 + o] = f2b(v);
}

// ------------------------------ L4: fused row-local tail (megarow) ---------
struct MRP {
    const bf16 *H, *FE, *PT, *CV;
    const bf16 *WZ, *WR, *WQ, *W2A, *W2B, *RW0, *RW1, *CW0, *CW1;
    const float *bz, *br, *bq, *b2a, *b2b;
    const float *rbn0, *rbn1, *cbn0, *cbn1;
    const float *rw2, *rbn2, *cw2, *cbn2, *wfc, *bfc, *flow;
    float* out;
};

// block = 32 points (512 blocks). Stages: zr -> gq -> g2a -> g2b||C1 ->
// R1||C2 -> R2 -> head, all intermediates in LDS, __syncthreads between.
// Epilogue arithmetic identical to R10 kernels.
__global__ __launch_bounds__(256) void megarow(MRP p)
{
    __shared__ __align__(16) bf16 Zt[32][136], RHt[32][136], HPt[32][136], X1t[32][136];
    __shared__ __align__(16) bf16 X2t[32][72], R1t[32][72], R2t[32][72],
                                  C1t[32][72], C2t[32][72];
    const int w = threadIdx.x >> 6, lane = threadIdx.x & 63;
    const int q = lane >> 4, r = lane & 15;
    const int ptb = blockIdx.x * 32;

    // D: GRU gates z, r.h
    {
        const int ob = w * 32;
        f32x4 acc[2][2]; zacc(acc);
        mm32(acc, p.H, 128, ptb, 128, p.FE, 128, ptb, p.WZ, 256, 256, ob);
#pragma unroll
        for (int to = 0; to < 2; ++to) {
            const int o = ob + to * 16 + r;
            const float bs = p.bz[o];
#pragma unroll
            for (int tm = 0; tm < 2; ++tm)
#pragma unroll
                for (int rr = 0; rr < 4; ++rr) {
                    const int jl = tm * 16 + q * 4 + rr;
                    float v = acc[tm][to][rr] + bs;
                    Zt[jl][o] = f2b(1.0f / (1.0f + expf(-v)));
                }
        }
        f32x4 acc2[2][2]; zacc(acc2);
        mm32(acc2, p.H, 128, ptb, 128, p.FE, 128, ptb, p.WR, 256, 256, ob);
#pragma unroll
        for (int to = 0; to < 2; ++to) {
            const int o = ob + to * 16 + r;
            const float bs = p.br[o];
#pragma unroll
            for (int tm = 0; tm < 2; ++tm)
#pragma unroll
                for (int rr = 0; rr < 4; ++rr) {
                    const int jl = tm * 16 + q * 4 + rr;
                    float v = acc2[tm][to][rr] + bs;
                    v = 1.0f / (1.0f + expf(-v));
                    RHt[jl][o] = f2b(v * b2f(p.H[(size_t)(ptb + jl) * 128 + o]));
                }
        }
    }
    __syncthreads();
    // E: q = tanh(...); h' = (1-z)h + z q  -> HPt
    {
        const int ob = w * 32;
        f32x4 acc[2][2]; zacc(acc);
        mm32(acc, &RHt[0][0], 136, 0, 128, p.FE, 128, ptb, p.WQ, 256, 256, ob);
#pragma unroll
        for (int to = 0; to < 2; ++to) {
            const int o = ob + to * 16 + r;
            const float bs = p.bq[o];
#pragma unroll
            for (int tm = 0; tm < 2; ++tm)
#pragma unroll
                for (int rr = 0; rr < 4; ++rr) {
                    const int jl = tm * 16 + q * 4 + rr;
                    float v = acc[tm][to][rr] + bs;
                    float qv = tanhf(v);
                    float z = b2f(Zt[jl][o]);
                    float h = b2f(p.H[(size_t)(ptb + jl) * 128 + o]);
                    HPt[jl][o] = f2b((1.0f - z) * h + z * qv);
                }
        }
    }
    __syncthreads();
    // F: x1 = lrelu(w2a . [points | h'])
    {
        const int ob = w * 32;
        f32x4 acc[2][2]; zacc(acc);
        mm32(acc, p.PT, 64, ptb, 64, &HPt[0][0], 136, 0, p.W2A, 192, 192, ob);
#pragma unroll
        for (int to = 0; to < 2; ++to) {
            const int o = ob + to * 16 + r;
            const float bs = p.b2a[o];
#pragma unroll
            for (int tm = 0; tm < 2; ++tm)
#pragma unroll
                for (int rr = 0; rr < 4; ++rr) {
                    const int jl = tm * 16 + q * 4 + rr;
                    float v = acc[tm][to][rr] + bs;
                    X1t[jl][o] = f2b(v > 0.f ? v : 0.1f * v);
                }
        }
    }
    __syncthreads();
    // G: waves 0-1: x2 = lrelu(w2b . x1) (+ out x-section); waves 2-3: C1
    if (w < 2) {
        const int ob = w * 32;
        f32x4 acc[2][2]; zacc(acc);
        mm32(acc, &X1t[0][0], 136, 0, 128, &X1t[0][0], 136, 0, p.W2B, 128, 128, ob);
#pragma unroll
        for (int to = 0; to < 2; ++to) {
            const int o = ob + to * 16 + r;
            const float bs = p.b2b[o];
#pragma unroll
            for (int tm = 0; tm < 2; ++tm)
#pragma unroll
                for (int rr = 0; rr < 4; ++rr) {
                    const int jl = tm * 16 + q * 4 + rr;
                    float v = acc[tm][to][rr] + bs;
                    v = v > 0.f ? v : 0.1f * v;
                    X2t[jl][o] = f2b(v);
                    const int j = ptb + jl, bb = j >> 13, nn = j & (NPTS - 1);
                    p.out[(size_t)bb * 64 * NPTS + (size_t)o * NPTS + nn] = v;
                }
        }
    } else {
        const int ob = (w - 2) * 32;
        f32x4 acc[2][2]; zacc(acc);
        mm32(acc, p.CV, 64, ptb, 64, p.CV, 64, ptb, p.CW0, 64, 64, ob);
#pragma unroll
        for (int to = 0; to < 2; ++to) {
            const int o = ob + to * 16 + r;
            float gg = p.cbn0[o], be = p.cbn0[64 + o], mm = p.cbn0[128 + o];
            float rs = 1.0f / sqrtf(p.cbn0[192 + o] + 1e-5f);
#pragma unroll
            for (int tm = 0; tm < 2; ++tm)
#pragma unroll
                for (int rr = 0; rr < 4; ++rr) {
                    const int jl = tm * 16 + q * 4 + rr;
                    float v = acc[tm][to][rr];
                    v = (v - mm) * rs * gg + be;
                    C1t[jl][o] = f2b(fmaxf(v, 0.f));
                }
        }
    }
    __syncthreads();
    // H: waves 0-1: R1 = reg(x2); waves 2-3: C2 = reg(C1)
    if (w < 2) {
        const int ob = w * 32;
        f32x4 acc[2][2]; zacc(acc);
        mm32(acc, &X2t[0][0], 72, 0, 64, &X2t[0][0], 72, 0, p.RW0, 64, 64, ob);
#pragma unroll
        for (int to = 0; to < 2; ++to) {
            const int o = ob + to * 16 + r;
            float gg = p.rbn0[o], be = p.rbn0[64 + o], mm = p.rbn0[128 + o];
            float rs = 1.0f / sqrtf(p.rbn0[192 + o] + 1e-5f);
#pragma unroll
            for (int tm = 0; tm < 2; ++tm)
#pragma unroll
                for (int rr = 0; rr < 4; ++rr) {
                    const int jl = tm * 16 + q * 4 + rr;
                    float v = acc[tm][to][rr];
                    v = (v - mm) * rs * gg + be;
                    R1t[jl][o] = f2b(fmaxf(v, 0.f));
                }
        }
    } else {
        const int ob = (w - 2) * 32;
        f32x4 acc[2][2]; zacc(acc);
        mm32(acc, &C1t[0][0], 72, 0, 64, &C1t[0][0], 72, 0, p.CW1, 64, 64, ob);
#pragma unroll
        for (int to = 0; to < 2; ++to) {
            const int o = ob + to * 16 + r;
            float gg = p.cbn1[o], be = p.cbn1[64 + o], mm = p.cbn1[128 + o];
            float rs = 1.0f / sqrtf(p.cbn1[192 + o] + 1e-5f);
#pragma unroll
            for (int tm = 0; tm < 2; ++tm)
#pragma unroll
                for (int rr = 0; rr < 4; ++rr) {
                    const int jl = tm * 16 + q * 4 + rr;
                    float v = acc[tm][to][rr];
                    v = (v - mm) * rs * gg + be;
                    C2t[jl][o] = f2b(fmaxf(v, 0.f));
                }
        }
    }
    __syncthreads();
    // I: waves 0-1: R2 = reg(R1)
    if (w < 2) {
        const int ob = w * 32;
        f32x4 acc[2][2]; zacc(acc);
        mm32(acc, &R1t[0][0], 72, 0, 64, &R1t[0][0], 72, 0, p.RW1, 64, 64, ob);
#pragma unroll
        for (int to = 0; to < 2; ++to) {
            const int o = ob + to * 16 + r;
            float gg = p.rbn1[o], be = p.rbn1[64 + o], mm = p.rbn1[128 + o];
            float rs = 1.0f / sqrtf(p.rbn1[192 + o] + 1e-5f);
#pragma unroll
            for (int tm = 0; tm < 2; ++tm)
#pragma unroll
                for (int rr = 0; rr < 4; ++rr) {
                    const int jl = tm * 16 + q * 4 + rr;
                    float v = acc[tm][to][rr];
                    v = (v - mm) * rs * gg + be;
                    R2t[jl][o] = f2b(fmaxf(v, 0.f));
                }
        }
    }
    __syncthreads();
    // J: head fuse (threads 0..31, one point each)
    if (threadIdx.x < 32) {
        const int jl = threadIdx.x, j = ptb + jl;
        const int b = j >> 13, n = j & (NPTS - 1);
        float dr = 0.f, dc = 0.f, p0 = 0.f, p1 = 0.f, p2 = 0.f;
#pragma unroll
        for (int c = 0; c < 64; ++c) {
            float x = b2f(X2t[jl][c]);
            dr += p.rw2[c] * b2f(R2t[jl][c]);
            dc += p.cw2[c] * b2f(C2t[jl][c]);
            p0 += p.wfc[c] * x;
            p1 += p.wfc[64 + c] * x;
            p2 += p.wfc[128 + c] * x;
        }
        float refine = (dr - p.rbn2[2]) / sqrtf(p.rbn2[3] + 1e-5f) * p.rbn2[0] + p.rbn2[1];
        refine = fmaxf(refine, 0.f);
        float coarse = (dc - p.cbn2[2]) / sqrtf(p.cbn2[3] + 1e-5f) * p.cbn2[0] + p.cbn2[1];
        coarse = fmaxf(coarse, 0.f);
        p0 += p.bfc[0]; p1 += p.bfc[1]; p2 += p.bfc[2];
        const float f0 = p.flow[(size_t)b * 3 * NPTS + n];
        const float f1 = p.flow[(size_t)b * 3 * NPTS + NPTS + n];
        const float f2v = p.flow[(size_t)b * 3 * NPTS + 2 * NPTS + n];
        float o0 = fminf(fmaxf(coarse * f0 + refine * p0, -20.f), 20.f);
        float o1 = fminf(fmaxf(coarse * f1 + refine * p1, -20.f), 20.f);
        float o2 = fminf(fmaxf(coarse * f2v + refine * p2, -20.f), 20.f);
        float* ro = p.out + 1048576;
        ro[(size_t)b * 3 * NPTS + n] = o0;
        ro[(size_t)b * 3 * NPTS + NPTS + n] = o1;
        ro[(size_t)b * 3 * NPTS + 2 * NPTS + n] = o2;
    }
}

// -------------------------------------------------------------- launch -----
// Workspace (18,767,872 B), NO aliasing (all tail intermediates are LDS):
//   W0p @0 | WTS @24,576 | idxg @352,256 | CV @942,080 | FL @3,039,232
//   FE @4,087,808 | PT @8,282,112 | P2 @10,379,264 | H @14,573,568
extern "C" void kernel_launch(void* const* d_in, const int* in_sizes, int n_in,
                              void* d_out, int out_size, void* d_ws, size_t ws_size,
                              hipStream_t stream)
{
    static const int EXP[35] = {
        49152, 1048576, 1048576, 2097152, 49152,
        8576, 128, 512, 16384, 128, 512,
        32768, 128, 32768, 128, 32768, 128,
        24576, 128, 8192, 64, 192, 3,
        4096, 256, 4096, 256, 64, 4,
        4096, 256, 4096, 256, 64, 4 };
    float code = 0.f;
    if (n_in != 35) code = 900.f;
    else if (out_size != 1097728) code = 950.f;
    else if (ws_size < 18767872u) code = 980.f;
    else { for (int i = 0; i < 35; ++i) if (in_sizes[i] != EXP[i]) { code = 1000.f + 4.f * i; break; } }
    if (code != 0.f) { diag_k<<<dim3(1), dim3(64), 0, stream>>>((float*)d_out, code); return; }

    const float* xyz    = (const float*)d_in[0];
    const float* points = (const float*)d_in[1];
    const float* cost   = (const float*)d_in[2];
    const float* feats  = (const float*)d_in[3];
    const float* flow   = (const float*)d_in[4];
    const float* w0     = (const float*)d_in[5];
    const float* b0     = (const float*)d_in[6];
    const float* bn0    = (const float*)d_in[7];
    const float* w1     = (const float*)d_in[8];
    const float* b1     = (const float*)d_in[9];
    const float* bn1    = (const float*)d_in[10];
    const float* wz     = (const float*)d_in[11];
    const float* bz     = (const float*)d_in[12];
    const float* wr     = (const float*)d_in[13];
    const float* br     = (const float*)d_in[14];
    const float* wq     = (const float*)d_in[15];
    const float* bq     = (const float*)d_in[16];
    const float* w2a    = (const float*)d_in[17];
    const float* b2a    = (const float*)d_in[18];
    const float* w2b    = (const float*)d_in[19];
    const float* b2b    = (const float*)d_in[20];
    const float* wfc    = (const float*)d_in[21];
    const float* bfc    = (const float*)d_in[22];
    const float* rw0    = (const float*)d_in[23];
    const float* rbn0   = (const float*)d_in[24];
    const float* rw1    = (const float*)d_in[25];
    const float* rbn1   = (const float*)d_in[26];
    const float* rw2    = (const float*)d_in[27];
    const float* rbn2   = (const float*)d_in[28];
    const float* cw0    = (const float*)d_in[29];
    const float* cbn0   = (const float*)d_in[30];
    const float* cw1    = (const float*)d_in[31];
    const float* cbn1   = (const float*)d_in[32];
    const float* cw2    = (const float*)d_in[33];
    const float* cbn2   = (const float*)d_in[34];

    char* ws = (char*)d_ws;
    bf16* W0p  = (bf16*)(ws + 0);
    bf16* WTS  = (bf16*)(ws + 24576);
    int*  idxg = (int*) (ws + 352256);
    bf16* CV   = (bf16*)(ws + 942080);
    bf16* FL   = (bf16*)(ws + 3039232);
    bf16* FE   = (bf16*)(ws + 4087808);
    bf16* PT   = (bf16*)(ws + 8282112);
    bf16* P2   = (bf16*)(ws + 10379264);
    bf16* H    = (bf16*)(ws + 14573568);

    bf16* W1  = WTS;
    bf16* WZ  = WTS + 16384;
    bf16* WR  = WTS + 49152;
    bf16* WQ  = WTS + 81920;
    bf16* W2A = WTS + 114688;
    bf16* W2B = WTS + 139264;
    bf16* RW0 = WTS + 147456;
    bf16* RW1 = WTS + 151552;
    bf16* CW0 = WTS + 155648;
    bf16* CW1 = WTS + 159744;

    float* out = (float*)d_out;

    /*1*/ prep_knn<<<dim3(7088), dim3(256), 0, stream>>>(
              xyz, w0, w1, wz, wr, wq, w2a, w2b, rw0, rw1, cw0, cw1,
              cost, flow, feats, points, W0p, WTS, CV, FL, FE, PT, idxg);
    /*2*/ conv12<<<dim3(512), dim3(256), 0, stream>>>(
              CV, FL, W0p, W1, b0, bn0, b1, bn1, P2);
    /*3*/ gather_max<<<dim3(8192), dim3(256), 0, stream>>>(idxg, P2, H);
    /*4*/ MRP mp;
          mp.H = H; mp.FE = FE; mp.PT = PT; mp.CV = CV;
          mp.WZ = WZ; mp.WR = WR; mp.WQ = WQ; mp.W2A = W2A; mp.W2B = W2B;
          mp.RW0 = RW0; mp.RW1 = RW1; mp.CW0 = CW0; mp.CW1 = CW1;
          mp.bz = bz; mp.br = br; mp.bq = bq; mp.b2a = b2a; mp.b2b = b2b;
          mp.rbn0 = rbn0; mp.rbn1 = rbn1; mp.cbn0 = cbn0; mp.cbn1 = cbn1;
          mp.rw2 = rw2; mp.rbn2 = rbn2; mp.cw2 = cw2; mp.cbn2 = cbn2;
          mp.wfc = wfc; mp.bfc = bfc; mp.flow = flow; mp.out = out;
          megarow<<<dim3(512), dim3(256), 0, stream>>>(mp);

    (void)n_in;
}